// Round 1
// 544.810 us; speedup vs baseline: 1.1013x; 1.1013x over previous
//
#include <hip/hip_runtime.h>
#include <hip/hip_bf16.h>

#define N_USERS   100000
#define N_ITEMS   50000
#define N_ENT     150000
#define N_EDGES   2000000
#define NNZ       1000000
#define CH        64

#define CB_SHIFT  9
#define CB_SIZE   512
#define NB_E      ((N_ENT   + CB_SIZE - 1) >> CB_SHIFT)   // 293
#define NB_U      ((N_USERS + CB_SIZE - 1) >> CB_SHIFT)   // 196
#define A_CHUNK   4096
#define UCACHE    32   // LDS-cached rows per user (P(deg>32 | lambda=10) ~ 3e-9; fallback reloads)

#define NBLK_CNT   512
#define NBLK_CONV  ((N_ENT * 16 + 255) / 256)             // 9375
#define NBLK_BS_E  ((N_EDGES + A_CHUNK - 1) / A_CHUNK)    // 489
#define NBLK_BS_U  ((NNZ + A_CHUNK - 1) / A_CHUNK)        // 245
#define GB_GATHER  (N_ENT / 4)                            // 37500 blocks (1 wave = 1 row)
#define GB_USER    (N_USERS / 4)                          // 25000 blocks

// ---- bf16 pack/unpack helpers (fp32 accumulate everywhere) ----
__device__ __forceinline__ float bflo(unsigned int u) { return __uint_as_float(u << 16); }
__device__ __forceinline__ float bfhi(unsigned int u) { return __uint_as_float(u & 0xffff0000u); }
__device__ __forceinline__ unsigned int pack_bf(float a, float b) {   // RNE
    unsigned int ua = __float_as_uint(a), ub = __float_as_uint(b);
    ua += 0x7fffu + ((ua >> 16) & 1u);
    ub += 0x7fffu + ((ub >> 16) & 1u);
    return (ua >> 16) | (ub & 0xffff0000u);
}

// =================== build phase, device bodies ===================

__device__ __forceinline__ void coarse_count_f(const int* __restrict__ key, int n,
                                               unsigned int* __restrict__ gcnt, int nb,
                                               unsigned int* h, int bid, int nblk) {
    for (int i = threadIdx.x; i < nb; i += blockDim.x) h[i] = 0;
    __syncthreads();
    for (int e = bid * blockDim.x + threadIdx.x; e < n; e += nblk * blockDim.x)
        atomicAdd(&h[key[e] >> CB_SHIFT], 1u);
    __syncthreads();
    for (int i = threadIdx.x; i < nb; i += blockDim.x)
        if (h[i]) atomicAdd(&gcnt[i], h[i]);
}

// p1: coarse counts (E and U) + fp32->bf16 convert of entity_emb, one dispatch
__global__ void build_p1(const int* __restrict__ head, const int* __restrict__ iu,
                         const float* __restrict__ entity_emb, uint2* __restrict__ E0,
                         unsigned int* __restrict__ cntE, unsigned int* __restrict__ cntU) {
    __shared__ unsigned int h[CB_SIZE];
    int bid = blockIdx.x;
    if (bid < NBLK_CNT) {
        coarse_count_f(head, N_EDGES, cntE, NB_E, h, bid, NBLK_CNT);
    } else if (bid < 2 * NBLK_CNT) {
        coarse_count_f(iu, NNZ, cntU, NB_U, h, bid - NBLK_CNT, NBLK_CNT);
    } else {
        int i = (bid - 2 * NBLK_CNT) * 256 + threadIdx.x;
        if (i < N_ENT * 16) {
            float4 a = ((const float4*)entity_emb)[i];
            E0[i] = make_uint2(pack_bf(a.x, a.y), pack_bf(a.z, a.w));
        }
    }
}

__device__ __forceinline__ void coarse_scan_f(const unsigned int* __restrict__ gcnt,
                                              unsigned int* __restrict__ base,
                                              unsigned int* __restrict__ cursor, int nb,
                                              unsigned int* s) {
    int t = threadIdx.x;
    unsigned int v = (t < nb) ? gcnt[t] : 0u;
    s[t] = v;
    __syncthreads();
    for (int off = 1; off < 512; off <<= 1) {
        unsigned int u = 0;
        if (t >= off) u = s[t - off];
        __syncthreads();
        if (t >= off) s[t] += u;
        __syncthreads();
    }
    if (t < nb) { base[t] = s[t] - v; cursor[t] = s[t] - v; }
    if (t == nb) base[t] = s[nb - 1];   // total
}

// p2: both exclusive scans in one dispatch (2 blocks)
__global__ void build_p2(const unsigned int* __restrict__ cntE, unsigned int* __restrict__ baseE,
                         unsigned int* __restrict__ curE,
                         const unsigned int* __restrict__ cntU, unsigned int* __restrict__ baseU,
                         unsigned int* __restrict__ curU) {
    __shared__ unsigned int s[512];
    if (blockIdx.x == 0) coarse_scan_f(cntE, baseE, curE, NB_E, s);
    else                 coarse_scan_f(cntU, baseU, curU, NB_U, s);
}

__device__ __forceinline__ void binscat_ent_f(const int* __restrict__ head,
                                              const int* __restrict__ tail,
                                              unsigned int* __restrict__ cursor,
                                              unsigned int* __restrict__ binned,
                                              unsigned int* h, unsigned int* bb, int bid) {
    int lo = bid * A_CHUNK;
    int hi = min(lo + A_CHUNK, N_EDGES);
    for (int i = threadIdx.x; i < NB_E; i += blockDim.x) h[i] = 0;
    __syncthreads();
    for (int e = lo + threadIdx.x; e < hi; e += blockDim.x)
        atomicAdd(&h[head[e] >> CB_SHIFT], 1u);
    __syncthreads();
    for (int i = threadIdx.x; i < NB_E; i += blockDim.x) {
        unsigned int c = h[i];
        bb[i] = c ? atomicAdd(&cursor[i], c) : 0u;
        h[i] = 0;
    }
    __syncthreads();
    for (int e = lo + threadIdx.x; e < hi; e += blockDim.x) {
        int hd = head[e];
        int b = hd >> CB_SHIFT;
        unsigned int r = atomicAdd(&h[b], 1u);
        unsigned int local = (unsigned int)hd & (CB_SIZE - 1);
        binned[bb[b] + r] = (local << 18) | (unsigned int)tail[e];   // tail < 2^18
    }
}

__device__ __forceinline__ void binscat_user_f(const int* __restrict__ iu,
                                               const int* __restrict__ ii,
                                               const float* __restrict__ iv,
                                               unsigned int* __restrict__ cursor,
                                               unsigned int* __restrict__ binned,
                                               float* __restrict__ binnedv,
                                               unsigned int* h, unsigned int* bb, int bid) {
    int lo = bid * A_CHUNK;
    int hi = min(lo + A_CHUNK, NNZ);
    for (int i = threadIdx.x; i < NB_U; i += blockDim.x) h[i] = 0;
    __syncthreads();
    for (int e = lo + threadIdx.x; e < hi; e += blockDim.x)
        atomicAdd(&h[iu[e] >> CB_SHIFT], 1u);
    __syncthreads();
    for (int i = threadIdx.x; i < NB_U; i += blockDim.x) {
        unsigned int c = h[i];
        bb[i] = c ? atomicAdd(&cursor[i], c) : 0u;
        h[i] = 0;
    }
    __syncthreads();
    for (int e = lo + threadIdx.x; e < hi; e += blockDim.x) {
        int u = iu[e];
        int b = u >> CB_SHIFT;
        unsigned int r = atomicAdd(&h[b], 1u);
        unsigned int slot = bb[b] + r;
        unsigned int local = (unsigned int)u & (CB_SIZE - 1);
        binned[slot] = (local << 16) | (unsigned int)ii[e];          // item < 2^16
        binnedv[slot] = iv[e];
    }
}

// p3: both bin scatters in one dispatch
__global__ void build_p3(const int* __restrict__ head, const int* __restrict__ tail,
                         unsigned int* __restrict__ curE, unsigned int* __restrict__ binnedE,
                         const int* __restrict__ iu, const int* __restrict__ ii,
                         const float* __restrict__ iv, unsigned int* __restrict__ curU,
                         unsigned int* __restrict__ binnedU, float* __restrict__ binnedUV) {
    __shared__ unsigned int h[NB_E];    // NB_E >= NB_U, covers both
    __shared__ unsigned int bb[NB_E];
    if (blockIdx.x < NBLK_BS_E)
        binscat_ent_f(head, tail, curE, binnedE, h, bb, blockIdx.x);
    else
        binscat_user_f(iu, ii, iv, curU, binnedU, binnedUV, h, bb, blockIdx.x - NBLK_BS_E);
}

__device__ __forceinline__ void build_ent_f(const unsigned int* __restrict__ base,
                                            const unsigned int* __restrict__ binned,
                                            int* __restrict__ col,
                                            unsigned int* __restrict__ row_start,
                                            unsigned int* h, unsigned int* ex,
                                            unsigned int* pairs, int b) {
    unsigned int s0 = base[b], s1 = base[b + 1];
    int t = threadIdx.x;
    h[2 * t] = 0; h[2 * t + 1] = 0;
    __syncthreads();
    for (unsigned int j = s0 + t; j < s1; j += 256)
        atomicAdd(&h[binned[j] >> 18], 1u);
    __syncthreads();
    unsigned int a0 = h[2 * t], a1 = h[2 * t + 1];
    pairs[t] = a0 + a1;
    __syncthreads();
    for (int off = 1; off < 256; off <<= 1) {
        unsigned int u = 0;
        if (t >= off) u = pairs[t - off];
        __syncthreads();
        if (t >= off) pairs[t] += u;
        __syncthreads();
    }
    unsigned int pe = pairs[t] - (a0 + a1);
    ex[2 * t] = pe;
    ex[2 * t + 1] = pe + a0;
    __syncthreads();
    int keybase = b << CB_SHIFT;
    #pragma unroll
    for (int k = 0; k < 2; ++k) {
        int i = 2 * t + k;
        int key = keybase + i;
        if (key < N_ENT) row_start[key] = s0 + ex[i];
    }
    if (b == 0 && t == 0) row_start[N_ENT] = base[NB_E];
    __syncthreads();
    h[2 * t] = 0; h[2 * t + 1] = 0;
    __syncthreads();
    for (unsigned int j = s0 + t; j < s1; j += 256) {
        unsigned int p = binned[j];
        unsigned int local = p >> 18;
        unsigned int r = atomicAdd(&h[local], 1u);
        col[s0 + ex[local] + r] = (int)(p & 0x3FFFFu);
    }
}

__device__ __forceinline__ void build_user_f(const unsigned int* __restrict__ base,
                                             const unsigned int* __restrict__ binned,
                                             const float* __restrict__ binnedv,
                                             int2* __restrict__ upair,
                                             unsigned int* __restrict__ u_row_start,
                                             unsigned int* h, unsigned int* ex,
                                             unsigned int* pairs, int b) {
    unsigned int s0 = base[b], s1 = base[b + 1];
    int t = threadIdx.x;
    h[2 * t] = 0; h[2 * t + 1] = 0;
    __syncthreads();
    for (unsigned int j = s0 + t; j < s1; j += 256)
        atomicAdd(&h[binned[j] >> 16], 1u);
    __syncthreads();
    unsigned int a0 = h[2 * t], a1 = h[2 * t + 1];
    pairs[t] = a0 + a1;
    __syncthreads();
    for (int off = 1; off < 256; off <<= 1) {
        unsigned int u = 0;
        if (t >= off) u = pairs[t - off];
        __syncthreads();
        if (t >= off) pairs[t] += u;
        __syncthreads();
    }
    unsigned int pe = pairs[t] - (a0 + a1);
    ex[2 * t] = pe;
    ex[2 * t + 1] = pe + a0;
    __syncthreads();
    int keybase = b << CB_SHIFT;
    #pragma unroll
    for (int k = 0; k < 2; ++k) {
        int i = 2 * t + k;
        int key = keybase + i;
        if (key < N_USERS) u_row_start[key] = s0 + ex[i];
    }
    if (b == 0 && t == 0) u_row_start[N_USERS] = base[NB_U];
    __syncthreads();
    h[2 * t] = 0; h[2 * t + 1] = 0;
    __syncthreads();
    for (unsigned int j = s0 + t; j < s1; j += 256) {
        unsigned int p = binned[j];
        float v = binnedv[j];
        unsigned int local = p >> 16;
        unsigned int r = atomicAdd(&h[local], 1u);
        upair[s0 + ex[local] + r] = make_int2((int)(p & 0xFFFFu), __float_as_int(v));
    }
}

// p4: both per-bucket counting sorts in one dispatch
__global__ void build_p4(const unsigned int* __restrict__ baseE, const unsigned int* __restrict__ binnedE,
                         int* __restrict__ col, unsigned int* __restrict__ row_start,
                         const unsigned int* __restrict__ baseU, const unsigned int* __restrict__ binnedU,
                         const float* __restrict__ binnedUV, int2* __restrict__ upair,
                         unsigned int* __restrict__ u_row_start) {
    __shared__ unsigned int h[CB_SIZE];
    __shared__ unsigned int ex[CB_SIZE];
    __shared__ unsigned int pairs[256];
    if (blockIdx.x < NB_E)
        build_ent_f(baseE, binnedE, col, row_start, h, ex, pairs, blockIdx.x);
    else
        build_user_f(baseU, binnedU, binnedUV, upair, u_row_start, h, ex, pairs, blockIdx.x - NB_E);
}

// =================== hop kernels, device bodies ===================

// CSR gather (bf16 in, fp32 acc) + fused finalize: mean -> items_bf16 (pre-norm),
// l2norm -> ent_out (bf16, optional) and out_ent = base + norm.
__device__ __forceinline__ void gather_fin_row(int row, int lane,
        const uint2* __restrict__ entb, const unsigned int* __restrict__ row_start,
        const int* __restrict__ col,
        uint2* __restrict__ ent_out, uint2* __restrict__ items_out,
        const float* __restrict__ base_ent, float* __restrict__ out_ent,
        int write_ent) {
    int grp = lane >> 4;
    int t   = lane & 15;
    unsigned int s0 = row_start[row];
    unsigned int s1 = row_start[row + 1];

    float4 acc = make_float4(0.f, 0.f, 0.f, 0.f);
    unsigned int j = s0 + grp;
    for (; j + 4 < s1; j += 8) {
        uint2 a = entb[(size_t)col[j]     * 16 + t];
        uint2 b = entb[(size_t)col[j + 4] * 16 + t];
        acc.x += bflo(a.x) + bflo(b.x); acc.y += bfhi(a.x) + bfhi(b.x);
        acc.z += bflo(a.y) + bflo(b.y); acc.w += bfhi(a.y) + bfhi(b.y);
    }
    if (j < s1) {
        uint2 a = entb[(size_t)col[j] * 16 + t];
        acc.x += bflo(a.x); acc.y += bfhi(a.x);
        acc.z += bflo(a.y); acc.w += bfhi(a.y);
    }
    #pragma unroll
    for (int m = 16; m <= 32; m <<= 1) {
        acc.x += __shfl_xor(acc.x, m, 64);
        acc.y += __shfl_xor(acc.y, m, 64);
        acc.z += __shfl_xor(acc.z, m, 64);
        acc.w += __shfl_xor(acc.w, m, 64);
    }
    float inv = 1.0f / fmaxf((float)(s1 - s0), 1.0f);
    float4 mean = make_float4(acc.x * inv, acc.y * inv, acc.z * inv, acc.w * inv);

    // l2 norm over 64 channels: per-lane partial, reduce across the 16-lane group
    float sq = mean.x * mean.x + mean.y * mean.y + mean.z * mean.z + mean.w * mean.w;
    #pragma unroll
    for (int m = 1; m <= 8; m <<= 1) sq += __shfl_xor(sq, m, 64);
    float invn = 1.0f / fmaxf(sqrtf(sq), 1e-12f);

    if (grp == 0) {
        size_t o = (size_t)row * 16 + t;
        if (row < N_ITEMS)
            items_out[o] = make_uint2(pack_bf(mean.x, mean.y), pack_bf(mean.z, mean.w));
        float4 v = make_float4(mean.x * invn, mean.y * invn, mean.z * invn, mean.w * invn);
        if (write_ent)
            ent_out[o] = make_uint2(pack_bf(v.x, v.y), pack_bf(v.z, v.w));
        float4 c = ((const float4*)base_ent)[o];
        c.x += v.x; c.y += v.y; c.z += v.z; c.w += v.w;
        ((float4*)out_ent)[o] = c;
    }
}

// fused user pipeline: one wave per user, 4x16-lane groups, LDS row cache
__device__ __forceinline__ void fused_user_row(int row, int lane, uint2 (*cw)[16],
        const uint2* __restrict__ itemsb, const unsigned int* __restrict__ u_row_start,
        const int2* __restrict__ up, const float* __restrict__ base_user,
        float* __restrict__ out_user) {
    int grp = lane >> 4;
    int t   = lane & 15;
    unsigned int s0 = u_row_start[row];
    unsigned int s1 = u_row_start[row + 1];

    // ---- pass 1: gather once, cache, weighted sum ----
    float4 um = make_float4(0.f, 0.f, 0.f, 0.f);
    for (unsigned int j = s0 + grp; j < s1; j += 4) {
        int2 p = up[j];
        uint2 r = itemsb[(size_t)p.x * 16 + t];
        int slot = (int)(j - s0);
        if (slot < UCACHE) cw[slot][t] = r;
        float v = __int_as_float(p.y);
        um.x += v * bflo(r.x); um.y += v * bfhi(r.x);
        um.z += v * bflo(r.y); um.w += v * bfhi(r.y);
    }
    #pragma unroll
    for (int m = 16; m <= 32; m <<= 1) {
        um.x += __shfl_xor(um.x, m, 64);
        um.y += __shfl_xor(um.y, m, 64);
        um.z += __shfl_xor(um.z, m, 64);
        um.w += __shfl_xor(um.w, m, 64);
    }
    float4 umm = make_float4(um.x - 1e-6f, um.y - 1e-6f, um.z - 1e-6f, um.w - 1e-6f);

    // ---- pass 2: per-group online softmax from LDS (same-wave RAW, no barrier) ----
    float m_run = -1e30f, l = 0.0f;
    float4 acc = make_float4(0.f, 0.f, 0.f, 0.f);
    for (unsigned int j = s0 + grp; j < s1; j += 4) {
        int slot = (int)(j - s0);
        uint2 r = (slot < UCACHE) ? cw[slot][t]
                                  : itemsb[(size_t)up[j].x * 16 + t];
        float gx = bflo(r.x), gy = bfhi(r.x), gz = bflo(r.y), gw = bfhi(r.y);
        float dx = gx - umm.x, dy = gy - umm.y, dz = gz - umm.z, dw = gw - umm.w;
        float sq = dx * dx + dy * dy + dz * dz + dw * dw;
        #pragma unroll
        for (int m = 1; m <= 8; m <<= 1) sq += __shfl_xor(sq, m, 64);
        float sc = sqrtf(sq) * 5.0f;          // / TEMPERATURE (0.2)
        if (sc > m_run) {                      // no shfl inside: exec-mask safe
            float s = __expf(m_run - sc);
            l *= s;
            acc.x *= s; acc.y *= s; acc.z *= s; acc.w *= s;
            m_run = sc;
        }
        float e = __expf(sc - m_run);
        l += e;
        acc.x += e * gx; acc.y += e * gy; acc.z += e * gz; acc.w += e * gw;
    }

    // ---- merge the 4 group softmax states ----
    float M = fmaxf(m_run, __shfl_xor(m_run, 16, 64));
    M = fmaxf(M, __shfl_xor(M, 32, 64));
    float wgt = (l > 0.0f) ? __expf(m_run - M) : 0.0f;
    l *= wgt;
    acc.x *= wgt; acc.y *= wgt; acc.z *= wgt; acc.w *= wgt;
    #pragma unroll
    for (int m = 16; m <= 32; m <<= 1) {
        l     += __shfl_xor(l, m, 64);
        acc.x += __shfl_xor(acc.x, m, 64);
        acc.y += __shfl_xor(acc.y, m, 64);
        acc.z += __shfl_xor(acc.z, m, 64);
        acc.w += __shfl_xor(acc.w, m, 64);
    }
    float invl = (l > 0.0f) ? (1.0f / l) : 0.0f;
    float4 ua = make_float4(acc.x * invl, acc.y * invl, acc.z * invl, acc.w * invl);

    float sq2 = ua.x * ua.x + ua.y * ua.y + ua.z * ua.z + ua.w * ua.w;
    #pragma unroll
    for (int m = 1; m <= 8; m <<= 1) sq2 += __shfl_xor(sq2, m, 64);
    float inv = 1.0f / fmaxf(sqrtf(sq2), 1e-12f);
    if (grp == 0) {
        size_t o = (size_t)row * 16 + t;
        float4 c = ((const float4*)base_user)[o];
        c.x += ua.x * inv; c.y += ua.y * inv; c.z += ua.z * inv; c.w += ua.w * inv;
        ((float4*)out_user)[o] = c;
    }
}

// =================== hop kernel wrappers ===================

// hop-1 gather + finalize (writes next-hop bf16 table)
__global__ void gather_fin_k(const uint2* __restrict__ entb,
                             const unsigned int* __restrict__ row_start,
                             const int* __restrict__ col,
                             uint2* __restrict__ ent_out, uint2* __restrict__ items_out,
                             const float* __restrict__ base_ent, float* __restrict__ out_ent) {
    int wave = (blockIdx.x * blockDim.x + threadIdx.x) >> 6;
    int lane = threadIdx.x & 63;
    if (wave >= N_ENT) return;
    gather_fin_row(wave, lane, entb, row_start, col, ent_out, items_out, base_ent, out_ent, 1);
}

// combined: hop-2 gather+finalize (no ent_out needed) co-scheduled with hop-1 fused_user.
// Blocks interleaved 3 gather : 2 user so both populations stay co-resident on every CU:
// gather is cache-latency-bound (VALU idle), user is VALU-bound (memory idle).
__global__ void g2_u1_k(const uint2* __restrict__ entb,           // E1 (hop-1 normalized)
                        const unsigned int* __restrict__ row_start,
                        const int* __restrict__ col,
                        uint2* __restrict__ items_out,            // itemsB (hop-2 means)
                        const float* __restrict__ base_ent,       // out_ent (hop-1 result)
                        float* __restrict__ out_ent,
                        const uint2* __restrict__ itemsb1,        // itemsA (hop-1 means)
                        const unsigned int* __restrict__ u_row_start,
                        const int2* __restrict__ up,
                        const float* __restrict__ base_user,      // user_emb
                        float* __restrict__ out_user) {
    __shared__ uint2 cache[4][UCACHE][16];   // 16 KB (only user blocks use it)
    int bid = blockIdx.x;
    int g5 = bid / 5, r5 = bid - g5 * 5;     // 62500 = 12500 * 5 exactly
    int w    = threadIdx.x >> 6;
    int lane = threadIdx.x & 63;
    if (r5 < 3) {
        int row = (g5 * 3 + r5) * 4 + w;     // < 37500*4 = N_ENT exactly
        gather_fin_row(row, lane, entb, row_start, col, nullptr, items_out,
                       base_ent, out_ent, 0);
    } else {
        int row = (g5 * 2 + (r5 - 3)) * 4 + w;   // < 25000*4 = N_USERS exactly
        fused_user_row(row, lane, cache[w], itemsb1, u_row_start, up,
                       base_user, out_user);
    }
}

// hop-2 user pipeline (nothing left to overlap with)
__global__ void fused_user_k(const uint2* __restrict__ itemsb,
                             const unsigned int* __restrict__ u_row_start,
                             const int2* __restrict__ up,
                             const float* __restrict__ base_user,
                             float* __restrict__ out_user) {
    __shared__ uint2 cache[4][UCACHE][16];
    int wave = (blockIdx.x * blockDim.x + threadIdx.x) >> 6;
    int w    = threadIdx.x >> 6;
    int lane = threadIdx.x & 63;
    if (wave >= N_USERS) return;
    fused_user_row(wave, lane, cache[w], itemsb, u_row_start, up, base_user, out_user);
}

extern "C" void kernel_launch(void* const* d_in, const int* in_sizes, int n_in,
                              void* d_out, int out_size, void* d_ws, size_t ws_size,
                              hipStream_t stream) {
    const float* user_emb   = (const float*)d_in[0];
    const float* entity_emb = (const float*)d_in[1];
    const int*   edge_index = (const int*)d_in[3];
    const int*   iu = (const int*)d_in[5];
    const int*   ii = (const int*)d_in[6];
    const float* iv = (const float*)d_in[7];

    float* out_user = (float*)d_out;
    float* out_ent  = out_user + (size_t)N_USERS * CH;

    // ---- workspace layout (~68.3 MB) ----
    uint2* E0     = (uint2*)d_ws;                        // N_ENT*16  (19.2 MB)
    uint2* E1     = E0 + (size_t)N_ENT * 16;             // N_ENT*16  (19.2 MB)
    uint2* itemsA = E1 + (size_t)N_ENT * 16;             // N_ITEMS*16 (6.4 MB)
    uint2* itemsB = itemsA + (size_t)N_ITEMS * 16;       // N_ITEMS*16 (6.4 MB)
    int2*  upair  = (int2*)(itemsB + (size_t)N_ITEMS * 16);      // NNZ (8 MB)
    int*   col    = (int*)(upair + NNZ);                 // N_EDGES (8 MB)
    unsigned int* row_start   = (unsigned int*)(col + N_EDGES);  // N_ENT+1
    unsigned int* u_row_start = row_start + N_ENT + 1;           // N_USERS+1
    unsigned int* cntE  = u_row_start + N_USERS + 1;             // NB_E
    unsigned int* cntU  = cntE + NB_E;                           // NB_U
    unsigned int* baseE = cntU + NB_U;                           // NB_E+1
    unsigned int* curE  = baseE + NB_E + 1;                      // NB_E
    unsigned int* baseU = curE + NB_E;                           // NB_U+1
    unsigned int* curU  = baseU + NB_U + 1;                      // NB_U

    // build-time scratch ALIASED over E1 (16 MB < 19.2 MB; E1 first written by
    // gather_fin_k, which runs after build_p4 has consumed all scratch):
    unsigned int* binnedE  = (unsigned int*)E1;                  // N_EDGES
    unsigned int* binnedU  = binnedE + N_EDGES;                  // NNZ
    float*        binnedUV = (float*)(binnedU + NNZ);            // NNZ

    const int* head = edge_index;
    const int* tail = edge_index + N_EDGES;

    // ---- CSR builds (structure constant across hops), 4 dispatches ----
    hipMemsetAsync(cntE, 0, (size_t)(NB_E + NB_U) * 4, stream);
    build_p1<<<2 * NBLK_CNT + NBLK_CONV, 256, 0, stream>>>(head, iu, entity_emb, E0, cntE, cntU);
    build_p2<<<2, 512, 0, stream>>>(cntE, baseE, curE, cntU, baseU, curU);
    build_p3<<<NBLK_BS_E + NBLK_BS_U, 256, 0, stream>>>(head, tail, curE, binnedE,
                                                        iu, ii, iv, curU, binnedU, binnedUV);
    build_p4<<<NB_E + NB_U, 256, 0, stream>>>(baseE, binnedE, col, row_start,
                                              baseU, binnedU, binnedUV, upair, u_row_start);

    // ---- hop 1 gather+finalize: E0 -> E1, itemsA, out_ent = entity_emb + v1 ----
    gather_fin_k<<<GB_GATHER, 256, 0, stream>>>(E0, row_start, col, E1, itemsA,
                                                entity_emb, out_ent);

    // ---- hop-2 gather+finalize co-scheduled with hop-1 user pipeline ----
    g2_u1_k<<<GB_GATHER + GB_USER, 256, 0, stream>>>(E1, row_start, col, itemsB,
                                                     out_ent, out_ent,
                                                     itemsA, u_row_start, upair,
                                                     user_emb, out_user);

    // ---- hop 2 user pipeline: out_user += u2 ----
    fused_user_k<<<GB_USER, 256, 0, stream>>>(itemsB, u_row_start, upair,
                                              out_user, out_user);
}

// Round 3
// 537.712 us; speedup vs baseline: 1.1158x; 1.0132x over previous
//
#include <hip/hip_runtime.h>

#define N_USERS   100000
#define N_ITEMS   50000
#define N_ENT     150000
#define N_EDGES   2000000
#define NNZ       1000000
#define CH        64

#define CB_SHIFT  9
#define CB_SIZE   512
#define NB_E      ((N_ENT   + CB_SIZE - 1) >> CB_SHIFT)   // 293
#define NB_U      ((N_USERS + CB_SIZE - 1) >> CB_SHIFT)   // 196
#define A_CHUNK   4096
#define UCACHE    32   // LDS-cached rows per user (P(deg>32 | lambda=10) ~ 3e-9; fallback reloads)

#define NBLK_CNT   512
#define NBLK_CONV  ((N_ENT * 16 + 255) / 256)             // 9375
#define NBLK_BS_E  ((N_EDGES + A_CHUNK - 1) / A_CHUNK)    // 489
#define NBLK_BS_U  ((NNZ + A_CHUNK - 1) / A_CHUNK)        // 245
#define GB_GATHER  (N_ENT / 4)                            // 37500 blocks (1 wave = 1 row)
#define GB_USER    (N_USERS / 4)                          // 25000 blocks

// ---- packed fp16 helpers: tables are fp16 pairs in uint2; math is v_pk_* ----
typedef __fp16 h2v __attribute__((ext_vector_type(2)));

__device__ __forceinline__ h2v h2z() { h2v z = {(__fp16)0.f, (__fp16)0.f}; return z; }
__device__ __forceinline__ h2v pk(float a, float b) { return __builtin_amdgcn_cvt_pkrtz(a, b); }
__device__ __forceinline__ unsigned int h2u(h2v h) { return __builtin_bit_cast(unsigned int, h); }
__device__ __forceinline__ h2v u2h(unsigned int u) { return __builtin_bit_cast(h2v, u); }
__device__ __forceinline__ float fdot2f(h2v a, h2v b, float c) {
    return __builtin_amdgcn_fdot2(a, b, c, false);   // f32 accumulate of packed f16 dot
}

// =================== build phase, device bodies ===================

__device__ __forceinline__ void coarse_count_f(const int* __restrict__ key, int n,
                                               unsigned int* __restrict__ gcnt, int nb,
                                               unsigned int* h, int bid, int nblk) {
    for (int i = threadIdx.x; i < nb; i += blockDim.x) h[i] = 0;
    __syncthreads();
    for (int e = bid * blockDim.x + threadIdx.x; e < n; e += nblk * blockDim.x)
        atomicAdd(&h[key[e] >> CB_SHIFT], 1u);
    __syncthreads();
    for (int i = threadIdx.x; i < nb; i += blockDim.x)
        if (h[i]) atomicAdd(&gcnt[i], h[i]);
}

// p1: coarse counts (E and U) + fp32->fp16 convert of entity_emb, one dispatch
__global__ void build_p1(const int* __restrict__ head, const int* __restrict__ iu,
                         const float* __restrict__ entity_emb, uint2* __restrict__ E0,
                         unsigned int* __restrict__ cntE, unsigned int* __restrict__ cntU) {
    __shared__ unsigned int h[CB_SIZE];
    int bid = blockIdx.x;
    if (bid < NBLK_CNT) {
        coarse_count_f(head, N_EDGES, cntE, NB_E, h, bid, NBLK_CNT);
    } else if (bid < 2 * NBLK_CNT) {
        coarse_count_f(iu, NNZ, cntU, NB_U, h, bid - NBLK_CNT, NBLK_CNT);
    } else {
        int i = (bid - 2 * NBLK_CNT) * 256 + threadIdx.x;
        if (i < N_ENT * 16) {
            float4 a = ((const float4*)entity_emb)[i];
            E0[i] = make_uint2(h2u(pk(a.x, a.y)), h2u(pk(a.z, a.w)));
        }
    }
}

__device__ __forceinline__ void coarse_scan_f(const unsigned int* __restrict__ gcnt,
                                              unsigned int* __restrict__ base,
                                              unsigned int* __restrict__ cursor, int nb,
                                              unsigned int* s) {
    int t = threadIdx.x;
    unsigned int v = (t < nb) ? gcnt[t] : 0u;
    s[t] = v;
    __syncthreads();
    for (int off = 1; off < 512; off <<= 1) {
        unsigned int u = 0;
        if (t >= off) u = s[t - off];
        __syncthreads();
        if (t >= off) s[t] += u;
        __syncthreads();
    }
    if (t < nb) { base[t] = s[t] - v; cursor[t] = s[t] - v; }
    if (t == nb) base[t] = s[nb - 1];   // total
}

// p2: both exclusive scans in one dispatch (2 blocks)
__global__ void build_p2(const unsigned int* __restrict__ cntE, unsigned int* __restrict__ baseE,
                         unsigned int* __restrict__ curE,
                         const unsigned int* __restrict__ cntU, unsigned int* __restrict__ baseU,
                         unsigned int* __restrict__ curU) {
    __shared__ unsigned int s[512];
    if (blockIdx.x == 0) coarse_scan_f(cntE, baseE, curE, NB_E, s);
    else                 coarse_scan_f(cntU, baseU, curU, NB_U, s);
}

__device__ __forceinline__ void binscat_ent_f(const int* __restrict__ head,
                                              const int* __restrict__ tail,
                                              unsigned int* __restrict__ cursor,
                                              unsigned int* __restrict__ binned,
                                              unsigned int* h, unsigned int* bb, int bid) {
    int lo = bid * A_CHUNK;
    int hi = min(lo + A_CHUNK, N_EDGES);
    for (int i = threadIdx.x; i < NB_E; i += blockDim.x) h[i] = 0;
    __syncthreads();
    for (int e = lo + threadIdx.x; e < hi; e += blockDim.x)
        atomicAdd(&h[head[e] >> CB_SHIFT], 1u);
    __syncthreads();
    for (int i = threadIdx.x; i < NB_E; i += blockDim.x) {
        unsigned int c = h[i];
        bb[i] = c ? atomicAdd(&cursor[i], c) : 0u;
        h[i] = 0;
    }
    __syncthreads();
    for (int e = lo + threadIdx.x; e < hi; e += blockDim.x) {
        int hd = head[e];
        int b = hd >> CB_SHIFT;
        unsigned int r = atomicAdd(&h[b], 1u);
        unsigned int local = (unsigned int)hd & (CB_SIZE - 1);
        binned[bb[b] + r] = (local << 18) | (unsigned int)tail[e];   // tail < 2^18
    }
}

__device__ __forceinline__ void binscat_user_f(const int* __restrict__ iu,
                                               const int* __restrict__ ii,
                                               const float* __restrict__ iv,
                                               unsigned int* __restrict__ cursor,
                                               unsigned int* __restrict__ binned,
                                               float* __restrict__ binnedv,
                                               unsigned int* h, unsigned int* bb, int bid) {
    int lo = bid * A_CHUNK;
    int hi = min(lo + A_CHUNK, NNZ);
    for (int i = threadIdx.x; i < NB_U; i += blockDim.x) h[i] = 0;
    __syncthreads();
    for (int e = lo + threadIdx.x; e < hi; e += blockDim.x)
        atomicAdd(&h[iu[e] >> CB_SHIFT], 1u);
    __syncthreads();
    for (int i = threadIdx.x; i < NB_U; i += blockDim.x) {
        unsigned int c = h[i];
        bb[i] = c ? atomicAdd(&cursor[i], c) : 0u;
        h[i] = 0;
    }
    __syncthreads();
    for (int e = lo + threadIdx.x; e < hi; e += blockDim.x) {
        int u = iu[e];
        int b = u >> CB_SHIFT;
        unsigned int r = atomicAdd(&h[b], 1u);
        unsigned int slot = bb[b] + r;
        unsigned int local = (unsigned int)u & (CB_SIZE - 1);
        binned[slot] = (local << 16) | (unsigned int)ii[e];          // item < 2^16
        binnedv[slot] = iv[e];
    }
}

// p3: both bin scatters in one dispatch
__global__ void build_p3(const int* __restrict__ head, const int* __restrict__ tail,
                         unsigned int* __restrict__ curE, unsigned int* __restrict__ binnedE,
                         const int* __restrict__ iu, const int* __restrict__ ii,
                         const float* __restrict__ iv, unsigned int* __restrict__ curU,
                         unsigned int* __restrict__ binnedU, float* __restrict__ binnedUV) {
    __shared__ unsigned int h[NB_E];    // NB_E >= NB_U, covers both
    __shared__ unsigned int bb[NB_E];
    if (blockIdx.x < NBLK_BS_E)
        binscat_ent_f(head, tail, curE, binnedE, h, bb, blockIdx.x);
    else
        binscat_user_f(iu, ii, iv, curU, binnedU, binnedUV, h, bb, blockIdx.x - NBLK_BS_E);
}

__device__ __forceinline__ void build_ent_f(const unsigned int* __restrict__ base,
                                            const unsigned int* __restrict__ binned,
                                            int* __restrict__ col,
                                            unsigned int* __restrict__ row_start,
                                            unsigned int* h, unsigned int* ex,
                                            unsigned int* pairs, int b) {
    unsigned int s0 = base[b], s1 = base[b + 1];
    int t = threadIdx.x;
    h[2 * t] = 0; h[2 * t + 1] = 0;
    __syncthreads();
    for (unsigned int j = s0 + t; j < s1; j += 256)
        atomicAdd(&h[binned[j] >> 18], 1u);
    __syncthreads();
    unsigned int a0 = h[2 * t], a1 = h[2 * t + 1];
    pairs[t] = a0 + a1;
    __syncthreads();
    for (int off = 1; off < 256; off <<= 1) {
        unsigned int u = 0;
        if (t >= off) u = pairs[t - off];
        __syncthreads();
        if (t >= off) pairs[t] += u;
        __syncthreads();
    }
    unsigned int pe = pairs[t] - (a0 + a1);
    ex[2 * t] = pe;
    ex[2 * t + 1] = pe + a0;
    __syncthreads();
    int keybase = b << CB_SHIFT;
    #pragma unroll
    for (int k = 0; k < 2; ++k) {
        int i = 2 * t + k;
        int key = keybase + i;
        if (key < N_ENT) row_start[key] = s0 + ex[i];
    }
    if (b == 0 && t == 0) row_start[N_ENT] = base[NB_E];
    __syncthreads();
    h[2 * t] = 0; h[2 * t + 1] = 0;
    __syncthreads();
    for (unsigned int j = s0 + t; j < s1; j += 256) {
        unsigned int p = binned[j];
        unsigned int local = p >> 18;
        unsigned int r = atomicAdd(&h[local], 1u);
        col[s0 + ex[local] + r] = (int)(p & 0x3FFFFu);
    }
}

__device__ __forceinline__ void build_user_f(const unsigned int* __restrict__ base,
                                             const unsigned int* __restrict__ binned,
                                             const float* __restrict__ binnedv,
                                             int2* __restrict__ upair,
                                             unsigned int* __restrict__ u_row_start,
                                             unsigned int* h, unsigned int* ex,
                                             unsigned int* pairs, int b) {
    unsigned int s0 = base[b], s1 = base[b + 1];
    int t = threadIdx.x;
    h[2 * t] = 0; h[2 * t + 1] = 0;
    __syncthreads();
    for (unsigned int j = s0 + t; j < s1; j += 256)
        atomicAdd(&h[binned[j] >> 16], 1u);
    __syncthreads();
    unsigned int a0 = h[2 * t], a1 = h[2 * t + 1];
    pairs[t] = a0 + a1;
    __syncthreads();
    for (int off = 1; off < 256; off <<= 1) {
        unsigned int u = 0;
        if (t >= off) u = pairs[t - off];
        __syncthreads();
        if (t >= off) pairs[t] += u;
        __syncthreads();
    }
    unsigned int pe = pairs[t] - (a0 + a1);
    ex[2 * t] = pe;
    ex[2 * t + 1] = pe + a0;
    __syncthreads();
    int keybase = b << CB_SHIFT;
    #pragma unroll
    for (int k = 0; k < 2; ++k) {
        int i = 2 * t + k;
        int key = keybase + i;
        if (key < N_USERS) u_row_start[key] = s0 + ex[i];
    }
    if (b == 0 && t == 0) u_row_start[N_USERS] = base[NB_U];
    __syncthreads();
    h[2 * t] = 0; h[2 * t + 1] = 0;
    __syncthreads();
    for (unsigned int j = s0 + t; j < s1; j += 256) {
        unsigned int p = binned[j];
        float v = binnedv[j];
        unsigned int local = p >> 16;
        unsigned int r = atomicAdd(&h[local], 1u);
        upair[s0 + ex[local] + r] = make_int2((int)(p & 0xFFFFu), __float_as_int(v));
    }
}

// p4E: entity-side counting sort only (user side is folded into the hop-1 dispatch)
__global__ void build_p4e(const unsigned int* __restrict__ baseE,
                          const unsigned int* __restrict__ binnedE,
                          int* __restrict__ col, unsigned int* __restrict__ row_start) {
    __shared__ unsigned int h[CB_SIZE];
    __shared__ unsigned int ex[CB_SIZE];
    __shared__ unsigned int pairs[256];
    build_ent_f(baseE, binnedE, col, row_start, h, ex, pairs, blockIdx.x);
}

// =================== hop kernels, device bodies ===================

// CSR gather (fp16 in, packed-fp16 acc) + fused finalize: mean -> items (fp16),
// l2norm -> ent_out (fp16, optional) and out_ent = base + norm.
__device__ __forceinline__ void gather_fin_row(int row, int lane,
        const uint2* __restrict__ entb, const unsigned int* __restrict__ row_start,
        const int* __restrict__ col,
        uint2* __restrict__ ent_out, uint2* __restrict__ items_out,
        const float* __restrict__ base_ent, float* __restrict__ out_ent,
        int write_ent) {
    int grp = lane >> 4;
    int t   = lane & 15;
    unsigned int s0 = row_start[row];
    unsigned int s1 = row_start[row + 1];

    h2v a0 = h2z(), a1 = h2z();
    unsigned int j = s0 + grp;
    for (; j + 4 < s1; j += 8) {
        uint2 a = entb[(size_t)col[j]     * 16 + t];
        uint2 b = entb[(size_t)col[j + 4] * 16 + t];
        a0 += u2h(a.x) + u2h(b.x);
        a1 += u2h(a.y) + u2h(b.y);
    }
    if (j < s1) {
        uint2 a = entb[(size_t)col[j] * 16 + t];
        a0 += u2h(a.x);
        a1 += u2h(a.y);
    }
    #pragma unroll
    for (int m = 16; m <= 32; m <<= 1) {
        a0 += u2h(__shfl_xor(h2u(a0), m, 64));
        a1 += u2h(__shfl_xor(h2u(a1), m, 64));
    }
    float inv = 1.0f / fmaxf((float)(s1 - s0), 1.0f);
    float mx = (float)a0[0] * inv, my = (float)a0[1] * inv;
    float mz = (float)a1[0] * inv, mw = (float)a1[1] * inv;

    float sq = mx * mx + my * my + mz * mz + mw * mw;
    #pragma unroll
    for (int m = 1; m <= 8; m <<= 1) sq += __shfl_xor(sq, m, 64);
    float invn = 1.0f / fmaxf(sqrtf(sq), 1e-12f);

    if (grp == 0) {
        size_t o = (size_t)row * 16 + t;
        if (row < N_ITEMS)
            items_out[o] = make_uint2(h2u(pk(mx, my)), h2u(pk(mz, mw)));
        float vx = mx * invn, vy = my * invn, vz = mz * invn, vw = mw * invn;
        if (write_ent)
            ent_out[o] = make_uint2(h2u(pk(vx, vy)), h2u(pk(vz, vw)));
        float4 c = ((const float4*)base_ent)[o];
        ((float4*)out_ent)[o] = make_float4(c.x + vx, c.y + vy, c.z + vz, c.w + vw);
    }
}

// fused user pipeline: one wave per user, 4x16-lane groups, LDS row cache.
// All elementwise math packed fp16; sq via v_dot2_f32_f16 (f32 accumulate);
// softmax in base-2 (scale folds log2e) so exp2f = single v_exp_f32.
__device__ __forceinline__ void fused_user_row(int row, int lane, uint2 (*cw)[16],
        const uint2* __restrict__ itemsb, const unsigned int* __restrict__ u_row_start,
        const int2* __restrict__ up, const float* __restrict__ base_user,
        float* __restrict__ out_user) {
    int grp = lane >> 4;
    int t   = lane & 15;
    unsigned int s0 = u_row_start[row];
    unsigned int s1 = u_row_start[row + 1];

    // ---- pass 1: gather once, cache, weighted sum (packed fp16) ----
    h2v um0 = h2z(), um1 = h2z();
    for (unsigned int j = s0 + grp; j < s1; j += 4) {
        int2 p = up[j];
        uint2 r = itemsb[(size_t)p.x * 16 + t];
        int slot = (int)(j - s0);
        if (slot < UCACHE) cw[slot][t] = r;
        float v = __int_as_float(p.y);
        h2v v2 = pk(v, v);
        um0 += v2 * u2h(r.x);
        um1 += v2 * u2h(r.y);
    }
    #pragma unroll
    for (int m = 16; m <= 32; m <<= 1) {
        um0 += u2h(__shfl_xor(h2u(um0), m, 64));
        um1 += u2h(__shfl_xor(h2u(um1), m, 64));
    }
    // PDIST_EPS = 1e-6 underflows fp16 and shifts scores by <1e-5: omitted.

    // ---- pass 2: per-group online softmax from LDS (same-wave RAW, no barrier) ----
    const float SC = 5.0f * 1.44269504f;   // (1/TEMPERATURE) * log2(e)
    float m_run = -1e30f, l = 0.0f;
    h2v ac0 = h2z(), ac1 = h2z();
    for (unsigned int j = s0 + grp; j < s1; j += 4) {
        int slot = (int)(j - s0);
        uint2 r = (slot < UCACHE) ? cw[slot][t]
                                  : itemsb[(size_t)up[j].x * 16 + t];
        h2v g0 = u2h(r.x), g1 = u2h(r.y);
        h2v d0 = g0 - um0, d1 = g1 - um1;
        float sq = fdot2f(d1, d1, fdot2f(d0, d0, 0.0f));
        #pragma unroll
        for (int m = 1; m <= 8; m <<= 1) sq += __shfl_xor(sq, m, 64);
        float sc = sqrtf(sq) * SC;
        if (sc > m_run) {                  // uniform within the 16-lane group
            float s = exp2f(m_run - sc);
            l *= s;
            h2v s2 = pk(s, s);
            ac0 *= s2; ac1 *= s2;
            m_run = sc;
        }
        float e = exp2f(sc - m_run);
        l += e;
        h2v e2 = pk(e, e);
        ac0 += e2 * g0;
        ac1 += e2 * g1;
    }

    // ---- merge the 4 group softmax states ----
    float M = fmaxf(m_run, __shfl_xor(m_run, 16, 64));
    M = fmaxf(M, __shfl_xor(M, 32, 64));
    float wgt = (l > 0.0f) ? exp2f(m_run - M) : 0.0f;
    l *= wgt;
    h2v w2 = pk(wgt, wgt);
    ac0 *= w2; ac1 *= w2;
    #pragma unroll
    for (int m = 16; m <= 32; m <<= 1) {
        l   += __shfl_xor(l, m, 64);
        ac0 += u2h(__shfl_xor(h2u(ac0), m, 64));
        ac1 += u2h(__shfl_xor(h2u(ac1), m, 64));
    }
    float invl = (l > 0.0f) ? (1.0f / l) : 0.0f;
    float ux = (float)ac0[0] * invl, uy = (float)ac0[1] * invl;
    float uz = (float)ac1[0] * invl, uw = (float)ac1[1] * invl;

    float sq2 = ux * ux + uy * uy + uz * uz + uw * uw;
    #pragma unroll
    for (int m = 1; m <= 8; m <<= 1) sq2 += __shfl_xor(sq2, m, 64);
    float inv = 1.0f / fmaxf(sqrtf(sq2), 1e-12f);
    if (grp == 0) {
        size_t o = (size_t)row * 16 + t;
        float4 c = ((const float4*)base_user)[o];
        ((float4*)out_user)[o] = make_float4(c.x + ux * inv, c.y + uy * inv,
                                             c.z + uz * inv, c.w + uw * inv);
    }
}

// =================== hop kernel wrappers ===================

// hop-1 gather+finalize co-scheduled with the user-side counting sort
// (independent work: gather needs only CSR-E + E0; sort-U consumes binnedU).
__global__ void gf1_p4u_k(const uint2* __restrict__ E0,
                          const unsigned int* __restrict__ row_start,
                          const int* __restrict__ col,
                          uint2* __restrict__ E1, uint2* __restrict__ itemsA,
                          const float* __restrict__ entity_emb, float* __restrict__ out_ent,
                          const unsigned int* __restrict__ baseU,
                          const unsigned int* __restrict__ binnedU,
                          const float* __restrict__ binnedUV,
                          int2* __restrict__ upair, unsigned int* __restrict__ u_row_start) {
    __shared__ unsigned int h[CB_SIZE];
    __shared__ unsigned int ex[CB_SIZE];
    __shared__ unsigned int pairs[256];
    int bid = blockIdx.x;
    if (bid < NB_U) {
        build_user_f(baseU, binnedU, binnedUV, upair, u_row_start, h, ex, pairs, bid);
    } else {
        int row  = (bid - NB_U) * 4 + (threadIdx.x >> 6);
        gather_fin_row(row, threadIdx.x & 63, E0, row_start, col, E1, itemsA,
                       entity_emb, out_ent, 1);
    }
}

// combined: hop-2 gather+finalize co-scheduled with hop-1 fused_user (3:2 interleave)
__global__ void g2_u1_k(const uint2* __restrict__ entb,           // E1 (hop-1 normalized)
                        const unsigned int* __restrict__ row_start,
                        const int* __restrict__ col,
                        uint2* __restrict__ items_out,            // itemsB (hop-2 means)
                        const float* __restrict__ base_ent,       // out_ent (hop-1 result)
                        float* __restrict__ out_ent,
                        const uint2* __restrict__ itemsb1,        // itemsA (hop-1 means)
                        const unsigned int* __restrict__ u_row_start,
                        const int2* __restrict__ up,
                        const float* __restrict__ base_user,      // user_emb
                        float* __restrict__ out_user) {
    __shared__ uint2 cache[4][UCACHE][16];   // 16 KB (only user blocks use it)
    int bid = blockIdx.x;
    int g5 = bid / 5, r5 = bid - g5 * 5;     // 62500 = 12500 * 5 exactly
    int w    = threadIdx.x >> 6;
    int lane = threadIdx.x & 63;
    if (r5 < 3) {
        int row = (g5 * 3 + r5) * 4 + w;     // < 37500*4 = N_ENT exactly
        gather_fin_row(row, lane, entb, row_start, col, nullptr, items_out,
                       base_ent, out_ent, 0);
    } else {
        int row = (g5 * 2 + (r5 - 3)) * 4 + w;   // < 25000*4 = N_USERS exactly
        fused_user_row(row, lane, cache[w], itemsb1, u_row_start, up,
                       base_user, out_user);
    }
}

// hop-2 user pipeline (nothing left to overlap with)
__global__ void fused_user_k(const uint2* __restrict__ itemsb,
                             const unsigned int* __restrict__ u_row_start,
                             const int2* __restrict__ up,
                             const float* __restrict__ base_user,
                             float* __restrict__ out_user) {
    __shared__ uint2 cache[4][UCACHE][16];
    int wave = (blockIdx.x * blockDim.x + threadIdx.x) >> 6;
    int w    = threadIdx.x >> 6;
    int lane = threadIdx.x & 63;
    if (wave >= N_USERS) return;
    fused_user_row(wave, lane, cache[w], itemsb, u_row_start, up, base_user, out_user);
}

extern "C" void kernel_launch(void* const* d_in, const int* in_sizes, int n_in,
                              void* d_out, int out_size, void* d_ws, size_t ws_size,
                              hipStream_t stream) {
    const float* user_emb   = (const float*)d_in[0];
    const float* entity_emb = (const float*)d_in[1];
    const int*   edge_index = (const int*)d_in[3];
    const int*   iu = (const int*)d_in[5];
    const int*   ii = (const int*)d_in[6];
    const float* iv = (const float*)d_in[7];

    float* out_user = (float*)d_out;
    float* out_ent  = out_user + (size_t)N_USERS * CH;

    // ---- workspace layout (~68.3 MB) ----
    uint2* E0     = (uint2*)d_ws;                        // N_ENT*16  (19.2 MB)
    uint2* E1     = E0 + (size_t)N_ENT * 16;             // N_ENT*16  (19.2 MB)
    uint2* itemsA = E1 + (size_t)N_ENT * 16;             // N_ITEMS*16 (6.4 MB)
    uint2* itemsB = itemsA + (size_t)N_ITEMS * 16;       // N_ITEMS*16 (6.4 MB)
    int2*  upair  = (int2*)(itemsB + (size_t)N_ITEMS * 16);      // NNZ (8 MB)
    int*   col    = (int*)(upair + NNZ);                 // N_EDGES (8 MB)
    unsigned int* row_start   = (unsigned int*)(col + N_EDGES);  // N_ENT+1
    unsigned int* u_row_start = row_start + N_ENT + 1;           // N_USERS+1
    unsigned int* cntE  = u_row_start + N_USERS + 1;             // NB_E
    unsigned int* cntU  = cntE + NB_E;                           // NB_U
    unsigned int* baseE = cntU + NB_U;                           // NB_E+1
    unsigned int* curE  = baseE + NB_E + 1;                      // NB_E
    unsigned int* baseU = curE + NB_E;                           // NB_U+1
    unsigned int* curU  = baseU + NB_U + 1;                      // NB_U

    // build-time scratch:
    //  - binnedE aliased over E1 (8 MB < 19.2 MB): consumed by build_p4e, which
    //    completes before gf1_p4u_k writes E1.
    //  - binnedU/UV aliased over out_user (8 MB < 25.6 MB): consumed by the
    //    sort-U blocks of gf1_p4u_k; out_user is first really written by g2_u1_k.
    unsigned int* binnedE  = (unsigned int*)E1;                  // N_EDGES
    unsigned int* binnedU  = (unsigned int*)out_user;            // NNZ
    float*        binnedUV = (float*)(binnedU + NNZ);            // NNZ

    const int* head = edge_index;
    const int* tail = edge_index + N_EDGES;

    // ---- CSR builds (structure constant across hops) ----
    (void)hipMemsetAsync(cntE, 0, (size_t)(NB_E + NB_U) * 4, stream);
    build_p1<<<2 * NBLK_CNT + NBLK_CONV, 256, 0, stream>>>(head, iu, entity_emb, E0, cntE, cntU);
    build_p2<<<2, 512, 0, stream>>>(cntE, baseE, curE, cntU, baseU, curU);
    build_p3<<<NBLK_BS_E + NBLK_BS_U, 256, 0, stream>>>(head, tail, curE, binnedE,
                                                        iu, ii, iv, curU, binnedU, binnedUV);
    build_p4e<<<NB_E, 256, 0, stream>>>(baseE, binnedE, col, row_start);

    // ---- hop-1 gather+finalize (E0 -> E1, itemsA, out_ent) + user-side sort ----
    gf1_p4u_k<<<NB_U + GB_GATHER, 256, 0, stream>>>(E0, row_start, col, E1, itemsA,
                                                    entity_emb, out_ent,
                                                    baseU, binnedU, binnedUV,
                                                    upair, u_row_start);

    // ---- hop-2 gather+finalize co-scheduled with hop-1 user pipeline ----
    g2_u1_k<<<GB_GATHER + GB_USER, 256, 0, stream>>>(E1, row_start, col, itemsB,
                                                     out_ent, out_ent,
                                                     itemsA, u_row_start, upair,
                                                     user_emb, out_user);

    // ---- hop 2 user pipeline: out_user += u2 ----
    fused_user_k<<<GB_USER, 256, 0, stream>>>(itemsB, u_row_start, upair,
                                              out_user, out_user);
}

// Round 4
// 519.307 us; speedup vs baseline: 1.1553x; 1.0354x over previous
//
#include <hip/hip_runtime.h>

#define N_USERS   100000
#define N_ITEMS   50000
#define N_ENT     150000
#define N_EDGES   2000000
#define NNZ       1000000
#define CH        64

#define CB_SHIFT  9
#define CB_SIZE   512
#define NB_E      ((N_ENT   + CB_SIZE - 1) >> CB_SHIFT)   // 293
#define NB_U      ((N_USERS + CB_SIZE - 1) >> CB_SHIFT)   // 196
#define A_CHUNK   4096
#define UCACHE    32   // LDS-cached rows per user; fast path requires deg <= UCACHE

#define NBLK_CNT   512
#define NBLK_CONV  ((N_ENT * 16 + 255) / 256)             // 9375
#define NBLK_BS_E  ((N_EDGES + A_CHUNK - 1) / A_CHUNK)    // 489
#define NBLK_BS_U  ((NNZ + A_CHUNK - 1) / A_CHUNK)        // 245
#define GB_GATHER  (N_ENT / 4)                            // 37500 blocks (1 wave = 1 row)
#define GB_USER    (N_USERS / 4)                          // 25000 blocks

// ---- packed fp16 helpers: tables are fp16 pairs in uint2; math is v_pk_* ----
typedef __fp16 h2v __attribute__((ext_vector_type(2)));

__device__ __forceinline__ h2v h2z() { h2v z = {(__fp16)0.f, (__fp16)0.f}; return z; }
__device__ __forceinline__ h2v pk(float a, float b) { return __builtin_amdgcn_cvt_pkrtz(a, b); }
__device__ __forceinline__ unsigned int h2u(h2v h) { return __builtin_bit_cast(unsigned int, h); }
__device__ __forceinline__ h2v u2h(unsigned int u) { return __builtin_bit_cast(h2v, u); }
__device__ __forceinline__ float fdot2f(h2v a, h2v b, float c) {
    return __builtin_amdgcn_fdot2(a, b, c, false);   // f32 accumulate of packed f16 dot
}

// ---- DPP 16-lane all-reduce (VALU-only, no DS pipe; DPP row == 16-lane group) ----
template<int CTRL>
__device__ __forceinline__ float dpp_mov(float x) {
    return __builtin_bit_cast(float, __builtin_amdgcn_update_dpp(
        0, __builtin_bit_cast(int, x), CTRL, 0xF, 0xF, true));
}
__device__ __forceinline__ float red16(float x) {
    x += dpp_mov<0xB1>(x);    // quad_perm [1,0,3,2]  (xor 1)
    x += dpp_mov<0x4E>(x);    // quad_perm [2,3,0,1]  (xor 2)
    x += dpp_mov<0x140>(x);   // row_mirror           (cross-quad 0<->3, 1<->2)
    x += dpp_mov<0x141>(x);   // row_half_mirror      ({0,3} <-> {1,2})
    return x;                  // all 16 lanes hold the row sum
}

// =================== build phase, device bodies ===================

__device__ __forceinline__ void coarse_count_f(const int* __restrict__ key, int n,
                                               unsigned int* __restrict__ gcnt, int nb,
                                               unsigned int* h, int bid, int nblk) {
    for (int i = threadIdx.x; i < nb; i += blockDim.x) h[i] = 0;
    __syncthreads();
    for (int e = bid * blockDim.x + threadIdx.x; e < n; e += nblk * blockDim.x)
        atomicAdd(&h[key[e] >> CB_SHIFT], 1u);
    __syncthreads();
    for (int i = threadIdx.x; i < nb; i += blockDim.x)
        if (h[i]) atomicAdd(&gcnt[i], h[i]);
}

// p1: coarse counts (E and U) + fp32->fp16 convert of entity_emb, one dispatch
__global__ void build_p1(const int* __restrict__ head, const int* __restrict__ iu,
                         const float* __restrict__ entity_emb, uint2* __restrict__ E0,
                         unsigned int* __restrict__ cntE, unsigned int* __restrict__ cntU) {
    __shared__ unsigned int h[CB_SIZE];
    int bid = blockIdx.x;
    if (bid < NBLK_CNT) {
        coarse_count_f(head, N_EDGES, cntE, NB_E, h, bid, NBLK_CNT);
    } else if (bid < 2 * NBLK_CNT) {
        coarse_count_f(iu, NNZ, cntU, NB_U, h, bid - NBLK_CNT, NBLK_CNT);
    } else {
        int i = (bid - 2 * NBLK_CNT) * 256 + threadIdx.x;
        if (i < N_ENT * 16) {
            float4 a = ((const float4*)entity_emb)[i];
            E0[i] = make_uint2(h2u(pk(a.x, a.y)), h2u(pk(a.z, a.w)));
        }
    }
}

__device__ __forceinline__ void coarse_scan_f(const unsigned int* __restrict__ gcnt,
                                              unsigned int* __restrict__ base,
                                              unsigned int* __restrict__ cursor, int nb,
                                              unsigned int* s) {
    int t = threadIdx.x;
    unsigned int v = (t < nb) ? gcnt[t] : 0u;
    s[t] = v;
    __syncthreads();
    for (int off = 1; off < 512; off <<= 1) {
        unsigned int u = 0;
        if (t >= off) u = s[t - off];
        __syncthreads();
        if (t >= off) s[t] += u;
        __syncthreads();
    }
    if (t < nb) { base[t] = s[t] - v; cursor[t] = s[t] - v; }
    if (t == nb) base[t] = s[nb - 1];   // total
}

// p2: both exclusive scans in one dispatch (2 blocks)
__global__ void build_p2(const unsigned int* __restrict__ cntE, unsigned int* __restrict__ baseE,
                         unsigned int* __restrict__ curE,
                         const unsigned int* __restrict__ cntU, unsigned int* __restrict__ baseU,
                         unsigned int* __restrict__ curU) {
    __shared__ unsigned int s[512];
    if (blockIdx.x == 0) coarse_scan_f(cntE, baseE, curE, NB_E, s);
    else                 coarse_scan_f(cntU, baseU, curU, NB_U, s);
}

__device__ __forceinline__ void binscat_ent_f(const int* __restrict__ head,
                                              const int* __restrict__ tail,
                                              unsigned int* __restrict__ cursor,
                                              unsigned int* __restrict__ binned,
                                              unsigned int* h, unsigned int* bb, int bid) {
    int lo = bid * A_CHUNK;
    int hi = min(lo + A_CHUNK, N_EDGES);
    for (int i = threadIdx.x; i < NB_E; i += blockDim.x) h[i] = 0;
    __syncthreads();
    for (int e = lo + threadIdx.x; e < hi; e += blockDim.x)
        atomicAdd(&h[head[e] >> CB_SHIFT], 1u);
    __syncthreads();
    for (int i = threadIdx.x; i < NB_E; i += blockDim.x) {
        unsigned int c = h[i];
        bb[i] = c ? atomicAdd(&cursor[i], c) : 0u;
        h[i] = 0;
    }
    __syncthreads();
    for (int e = lo + threadIdx.x; e < hi; e += blockDim.x) {
        int hd = head[e];
        int b = hd >> CB_SHIFT;
        unsigned int r = atomicAdd(&h[b], 1u);
        unsigned int local = (unsigned int)hd & (CB_SIZE - 1);
        binned[bb[b] + r] = (local << 18) | (unsigned int)tail[e];   // tail < 2^18
    }
}

__device__ __forceinline__ void binscat_user_f(const int* __restrict__ iu,
                                               const int* __restrict__ ii,
                                               const float* __restrict__ iv,
                                               unsigned int* __restrict__ cursor,
                                               unsigned int* __restrict__ binned,
                                               float* __restrict__ binnedv,
                                               unsigned int* h, unsigned int* bb, int bid) {
    int lo = bid * A_CHUNK;
    int hi = min(lo + A_CHUNK, NNZ);
    for (int i = threadIdx.x; i < NB_U; i += blockDim.x) h[i] = 0;
    __syncthreads();
    for (int e = lo + threadIdx.x; e < hi; e += blockDim.x)
        atomicAdd(&h[iu[e] >> CB_SHIFT], 1u);
    __syncthreads();
    for (int i = threadIdx.x; i < NB_U; i += blockDim.x) {
        unsigned int c = h[i];
        bb[i] = c ? atomicAdd(&cursor[i], c) : 0u;
        h[i] = 0;
    }
    __syncthreads();
    for (int e = lo + threadIdx.x; e < hi; e += blockDim.x) {
        int u = iu[e];
        int b = u >> CB_SHIFT;
        unsigned int r = atomicAdd(&h[b], 1u);
        unsigned int slot = bb[b] + r;
        unsigned int local = (unsigned int)u & (CB_SIZE - 1);
        binned[slot] = (local << 16) | (unsigned int)ii[e];          // item < 2^16
        binnedv[slot] = iv[e];
    }
}

// p3: both bin scatters in one dispatch
__global__ void build_p3(const int* __restrict__ head, const int* __restrict__ tail,
                         unsigned int* __restrict__ curE, unsigned int* __restrict__ binnedE,
                         const int* __restrict__ iu, const int* __restrict__ ii,
                         const float* __restrict__ iv, unsigned int* __restrict__ curU,
                         unsigned int* __restrict__ binnedU, float* __restrict__ binnedUV) {
    __shared__ unsigned int h[NB_E];    // NB_E >= NB_U, covers both
    __shared__ unsigned int bb[NB_E];
    if (blockIdx.x < NBLK_BS_E)
        binscat_ent_f(head, tail, curE, binnedE, h, bb, blockIdx.x);
    else
        binscat_user_f(iu, ii, iv, curU, binnedU, binnedUV, h, bb, blockIdx.x - NBLK_BS_E);
}

__device__ __forceinline__ void build_ent_f(const unsigned int* __restrict__ base,
                                            const unsigned int* __restrict__ binned,
                                            int* __restrict__ col,
                                            unsigned int* __restrict__ row_start,
                                            unsigned int* h, unsigned int* ex,
                                            unsigned int* pairs, int b) {
    unsigned int s0 = base[b], s1 = base[b + 1];
    int t = threadIdx.x;
    h[2 * t] = 0; h[2 * t + 1] = 0;
    __syncthreads();
    for (unsigned int j = s0 + t; j < s1; j += 256)
        atomicAdd(&h[binned[j] >> 18], 1u);
    __syncthreads();
    unsigned int a0 = h[2 * t], a1 = h[2 * t + 1];
    pairs[t] = a0 + a1;
    __syncthreads();
    for (int off = 1; off < 256; off <<= 1) {
        unsigned int u = 0;
        if (t >= off) u = pairs[t - off];
        __syncthreads();
        if (t >= off) pairs[t] += u;
        __syncthreads();
    }
    unsigned int pe = pairs[t] - (a0 + a1);
    ex[2 * t] = pe;
    ex[2 * t + 1] = pe + a0;
    __syncthreads();
    int keybase = b << CB_SHIFT;
    #pragma unroll
    for (int k = 0; k < 2; ++k) {
        int i = 2 * t + k;
        int key = keybase + i;
        if (key < N_ENT) row_start[key] = s0 + ex[i];
    }
    if (b == 0 && t == 0) row_start[N_ENT] = base[NB_E];
    __syncthreads();
    h[2 * t] = 0; h[2 * t + 1] = 0;
    __syncthreads();
    for (unsigned int j = s0 + t; j < s1; j += 256) {
        unsigned int p = binned[j];
        unsigned int local = p >> 18;
        unsigned int r = atomicAdd(&h[local], 1u);
        col[s0 + ex[local] + r] = (int)(p & 0x3FFFFu);
    }
}

__device__ __forceinline__ void build_user_f(const unsigned int* __restrict__ base,
                                             const unsigned int* __restrict__ binned,
                                             const float* __restrict__ binnedv,
                                             int2* __restrict__ upair,
                                             unsigned int* __restrict__ u_row_start,
                                             unsigned int* h, unsigned int* ex,
                                             unsigned int* pairs, int b) {
    unsigned int s0 = base[b], s1 = base[b + 1];
    int t = threadIdx.x;
    h[2 * t] = 0; h[2 * t + 1] = 0;
    __syncthreads();
    for (unsigned int j = s0 + t; j < s1; j += 256)
        atomicAdd(&h[binned[j] >> 16], 1u);
    __syncthreads();
    unsigned int a0 = h[2 * t], a1 = h[2 * t + 1];
    pairs[t] = a0 + a1;
    __syncthreads();
    for (int off = 1; off < 256; off <<= 1) {
        unsigned int u = 0;
        if (t >= off) u = pairs[t - off];
        __syncthreads();
        if (t >= off) pairs[t] += u;
        __syncthreads();
    }
    unsigned int pe = pairs[t] - (a0 + a1);
    ex[2 * t] = pe;
    ex[2 * t + 1] = pe + a0;
    __syncthreads();
    int keybase = b << CB_SHIFT;
    #pragma unroll
    for (int k = 0; k < 2; ++k) {
        int i = 2 * t + k;
        int key = keybase + i;
        if (key < N_USERS) u_row_start[key] = s0 + ex[i];
    }
    if (b == 0 && t == 0) u_row_start[N_USERS] = base[NB_U];
    __syncthreads();
    h[2 * t] = 0; h[2 * t + 1] = 0;
    __syncthreads();
    for (unsigned int j = s0 + t; j < s1; j += 256) {
        unsigned int p = binned[j];
        float v = binnedv[j];
        unsigned int local = p >> 16;
        unsigned int r = atomicAdd(&h[local], 1u);
        upair[s0 + ex[local] + r] = make_int2((int)(p & 0xFFFFu), __float_as_int(v));
    }
}

// p4E: entity-side counting sort only (user side is folded into the hop-1 dispatch)
__global__ void build_p4e(const unsigned int* __restrict__ baseE,
                          const unsigned int* __restrict__ binnedE,
                          int* __restrict__ col, unsigned int* __restrict__ row_start) {
    __shared__ unsigned int h[CB_SIZE];
    __shared__ unsigned int ex[CB_SIZE];
    __shared__ unsigned int pairs[256];
    build_ent_f(baseE, binnedE, col, row_start, h, ex, pairs, blockIdx.x);
}

// =================== hop kernels, device bodies ===================

// CSR gather (fp16 in, packed-fp16 acc) + fused finalize: mean -> items (fp16),
// l2norm -> ent_out (fp16, optional) and out_ent = base + norm.
__device__ __forceinline__ void gather_fin_row(int row, int lane,
        const uint2* __restrict__ entb, const unsigned int* __restrict__ row_start,
        const int* __restrict__ col,
        uint2* __restrict__ ent_out, uint2* __restrict__ items_out,
        const float* __restrict__ base_ent, float* __restrict__ out_ent,
        int write_ent) {
    int grp = lane >> 4;
    int t   = lane & 15;
    unsigned int s0 = row_start[row];
    unsigned int s1 = row_start[row + 1];

    h2v a0 = h2z(), a1 = h2z();
    unsigned int j = s0 + grp;
    for (; j + 4 < s1; j += 8) {
        uint2 a = entb[(size_t)col[j]     * 16 + t];
        uint2 b = entb[(size_t)col[j + 4] * 16 + t];
        a0 += u2h(a.x) + u2h(b.x);
        a1 += u2h(a.y) + u2h(b.y);
    }
    if (j < s1) {
        uint2 a = entb[(size_t)col[j] * 16 + t];
        a0 += u2h(a.x);
        a1 += u2h(a.y);
    }
    #pragma unroll
    for (int m = 16; m <= 32; m <<= 1) {
        a0 += u2h(__shfl_xor(h2u(a0), m, 64));
        a1 += u2h(__shfl_xor(h2u(a1), m, 64));
    }
    float inv = 1.0f / fmaxf((float)(s1 - s0), 1.0f);
    float mx = (float)a0[0] * inv, my = (float)a0[1] * inv;
    float mz = (float)a1[0] * inv, mw = (float)a1[1] * inv;

    float sq = red16(mx * mx + my * my + mz * mz + mw * mw);
    float invn = 1.0f / fmaxf(sqrtf(sq), 1e-12f);

    if (grp == 0) {
        size_t o = (size_t)row * 16 + t;
        if (row < N_ITEMS)
            items_out[o] = make_uint2(h2u(pk(mx, my)), h2u(pk(mz, mw)));
        float vx = mx * invn, vy = my * invn, vz = mz * invn, vw = mw * invn;
        if (write_ent)
            ent_out[o] = make_uint2(h2u(pk(vx, vy)), h2u(pk(vz, vw)));
        float4 c = ((const float4*)base_ent)[o];
        ((float4*)out_ent)[o] = make_float4(c.x + vx, c.y + vy, c.z + vz, c.w + vw);
    }
}

// fused user pipeline: one wave per user, 4x16-lane groups, LDS row cache.
// deg <= UCACHE fast path: two-phase softmax (scores in regs, no rescale,
// independent j-iterations, DPP reductions). Fallback: online softmax.
__device__ __forceinline__ void fused_user_row(int row, int lane, uint2 (*cw)[16],
        const uint2* __restrict__ itemsb, const unsigned int* __restrict__ u_row_start,
        const int2* __restrict__ up, const float* __restrict__ base_user,
        float* __restrict__ out_user) {
    int grp = lane >> 4;
    int t   = lane & 15;
    unsigned int s0 = u_row_start[row];
    unsigned int s1 = u_row_start[row + 1];
    unsigned int deg = s1 - s0;

    // ---- pass 1: gather once, cache, weighted sum (packed fp16) ----
    h2v um0 = h2z(), um1 = h2z();
    for (unsigned int j = s0 + grp; j < s1; j += 4) {
        int2 p = up[j];
        uint2 r = itemsb[(size_t)p.x * 16 + t];
        int slot = (int)(j - s0);
        if (slot < UCACHE) cw[slot][t] = r;
        float v = __int_as_float(p.y);
        h2v v2 = pk(v, v);
        um0 += v2 * u2h(r.x);
        um1 += v2 * u2h(r.y);
    }
    #pragma unroll
    for (int m = 16; m <= 32; m <<= 1) {
        um0 += u2h(__shfl_xor(h2u(um0), m, 64));
        um1 += u2h(__shfl_xor(h2u(um1), m, 64));
    }
    // PDIST_EPS = 1e-6 underflows fp16 and shifts scores by <1e-5: omitted.

    const float SC = 5.0f * 1.44269504f;   // (1/TEMPERATURE) * log2(e)
    float l = 0.0f;
    h2v ac0 = h2z(), ac1 = h2z();

    if (__builtin_expect(deg <= UCACHE, 1)) {
        // ---- fast path: all rows LDS-cached; scores in 8 static regs ----
        float scv[8];
        float mloc = -1e30f;
        #pragma unroll
        for (int k = 0; k < 8; ++k) {
            unsigned int slot = (unsigned int)grp + 4u * k;
            if (slot < deg) {
                uint2 r = cw[slot][t];
                h2v d0 = u2h(r.x) - um0, d1 = u2h(r.y) - um1;
                float sq = red16(fdot2f(d1, d1, fdot2f(d0, d0, 0.0f)));
                float sc = sqrtf(sq) * SC;
                scv[k] = sc;
                mloc = fmaxf(mloc, sc);
            } else {
                scv[k] = -1e30f;
            }
        }
        float M = fmaxf(mloc, __shfl_xor(mloc, 16, 64));
        M = fmaxf(M, __shfl_xor(M, 32, 64));
        #pragma unroll
        for (int k = 0; k < 8; ++k) {
            unsigned int slot = (unsigned int)grp + 4u * k;
            if (slot < deg) {
                uint2 r = cw[slot][t];
                float e = exp2f(scv[k] - M);
                l += e;
                h2v e2 = pk(e, e);
                ac0 += e2 * u2h(r.x);
                ac1 += e2 * u2h(r.y);
            }
        }
        // common M across groups: plain sums
        #pragma unroll
        for (int m = 16; m <= 32; m <<= 1) {
            l   += __shfl_xor(l, m, 64);
            ac0 += u2h(__shfl_xor(h2u(ac0), m, 64));
            ac1 += u2h(__shfl_xor(h2u(ac1), m, 64));
        }
    } else {
        // ---- fallback: online softmax with per-group states ----
        float m_run = -1e30f;
        for (unsigned int j = s0 + grp; j < s1; j += 4) {
            int slot = (int)(j - s0);
            uint2 r = (slot < UCACHE) ? cw[slot][t]
                                      : itemsb[(size_t)up[j].x * 16 + t];
            h2v g0 = u2h(r.x), g1 = u2h(r.y);
            h2v d0 = g0 - um0, d1 = g1 - um1;
            float sq = red16(fdot2f(d1, d1, fdot2f(d0, d0, 0.0f)));
            float sc = sqrtf(sq) * SC;
            if (sc > m_run) {
                float s = exp2f(m_run - sc);
                l *= s;
                h2v s2 = pk(s, s);
                ac0 *= s2; ac1 *= s2;
                m_run = sc;
            }
            float e = exp2f(sc - m_run);
            l += e;
            h2v e2 = pk(e, e);
            ac0 += e2 * g0;
            ac1 += e2 * g1;
        }
        float M = fmaxf(m_run, __shfl_xor(m_run, 16, 64));
        M = fmaxf(M, __shfl_xor(M, 32, 64));
        float wgt = (l > 0.0f) ? exp2f(m_run - M) : 0.0f;
        l *= wgt;
        h2v w2 = pk(wgt, wgt);
        ac0 *= w2; ac1 *= w2;
        #pragma unroll
        for (int m = 16; m <= 32; m <<= 1) {
            l   += __shfl_xor(l, m, 64);
            ac0 += u2h(__shfl_xor(h2u(ac0), m, 64));
            ac1 += u2h(__shfl_xor(h2u(ac1), m, 64));
        }
    }

    float invl = (l > 0.0f) ? (1.0f / l) : 0.0f;
    float ux = (float)ac0[0] * invl, uy = (float)ac0[1] * invl;
    float uz = (float)ac1[0] * invl, uw = (float)ac1[1] * invl;

    float sq2 = red16(ux * ux + uy * uy + uz * uz + uw * uw);
    float inv = 1.0f / fmaxf(sqrtf(sq2), 1e-12f);
    if (grp == 0) {
        size_t o = (size_t)row * 16 + t;
        float4 c = ((const float4*)base_user)[o];
        ((float4*)out_user)[o] = make_float4(c.x + ux * inv, c.y + uy * inv,
                                             c.z + uz * inv, c.w + uw * inv);
    }
}

// =================== hop kernel wrappers ===================

// hop-1 gather+finalize co-scheduled with the user-side counting sort
// (independent work: gather needs only CSR-E + E0; sort-U consumes binnedU).
__global__ void gf1_p4u_k(const uint2* __restrict__ E0,
                          const unsigned int* __restrict__ row_start,
                          const int* __restrict__ col,
                          uint2* __restrict__ E1, uint2* __restrict__ itemsA,
                          const float* __restrict__ entity_emb, float* __restrict__ out_ent,
                          const unsigned int* __restrict__ baseU,
                          const unsigned int* __restrict__ binnedU,
                          const float* __restrict__ binnedUV,
                          int2* __restrict__ upair, unsigned int* __restrict__ u_row_start) {
    __shared__ unsigned int h[CB_SIZE];
    __shared__ unsigned int ex[CB_SIZE];
    __shared__ unsigned int pairs[256];
    int bid = blockIdx.x;
    if (bid < NB_U) {
        build_user_f(baseU, binnedU, binnedUV, upair, u_row_start, h, ex, pairs, bid);
    } else {
        int row  = (bid - NB_U) * 4 + (threadIdx.x >> 6);
        gather_fin_row(row, threadIdx.x & 63, E0, row_start, col, E1, itemsA,
                       entity_emb, out_ent, 1);
    }
}

// combined: hop-2 gather+finalize co-scheduled with hop-1 fused_user (3:2 interleave)
__global__ void g2_u1_k(const uint2* __restrict__ entb,           // E1 (hop-1 normalized)
                        const unsigned int* __restrict__ row_start,
                        const int* __restrict__ col,
                        uint2* __restrict__ items_out,            // itemsB (hop-2 means)
                        const float* __restrict__ base_ent,       // out_ent (hop-1 result)
                        float* __restrict__ out_ent,
                        const uint2* __restrict__ itemsb1,        // itemsA (hop-1 means)
                        const unsigned int* __restrict__ u_row_start,
                        const int2* __restrict__ up,
                        const float* __restrict__ base_user,      // user_emb
                        float* __restrict__ out_user) {
    __shared__ uint2 cache[4][UCACHE][16];   // 16 KB (only user blocks use it)
    int bid = blockIdx.x;
    int g5 = bid / 5, r5 = bid - g5 * 5;     // 62500 = 12500 * 5 exactly
    int w    = threadIdx.x >> 6;
    int lane = threadIdx.x & 63;
    if (r5 < 3) {
        int row = (g5 * 3 + r5) * 4 + w;     // < 37500*4 = N_ENT exactly
        gather_fin_row(row, lane, entb, row_start, col, nullptr, items_out,
                       base_ent, out_ent, 0);
    } else {
        int row = (g5 * 2 + (r5 - 3)) * 4 + w;   // < 25000*4 = N_USERS exactly
        fused_user_row(row, lane, cache[w], itemsb1, u_row_start, up,
                       base_user, out_user);
    }
}

// hop-2 user pipeline (nothing left to overlap with)
__global__ void fused_user_k(const uint2* __restrict__ itemsb,
                             const unsigned int* __restrict__ u_row_start,
                             const int2* __restrict__ up,
                             const float* __restrict__ base_user,
                             float* __restrict__ out_user) {
    __shared__ uint2 cache[4][UCACHE][16];
    int wave = (blockIdx.x * blockDim.x + threadIdx.x) >> 6;
    int w    = threadIdx.x >> 6;
    int lane = threadIdx.x & 63;
    if (wave >= N_USERS) return;
    fused_user_row(wave, lane, cache[w], itemsb, u_row_start, up, base_user, out_user);
}

extern "C" void kernel_launch(void* const* d_in, const int* in_sizes, int n_in,
                              void* d_out, int out_size, void* d_ws, size_t ws_size,
                              hipStream_t stream) {
    const float* user_emb   = (const float*)d_in[0];
    const float* entity_emb = (const float*)d_in[1];
    const int*   edge_index = (const int*)d_in[3];
    const int*   iu = (const int*)d_in[5];
    const int*   ii = (const int*)d_in[6];
    const float* iv = (const float*)d_in[7];

    float* out_user = (float*)d_out;
    float* out_ent  = out_user + (size_t)N_USERS * CH;

    // ---- workspace layout (~68.3 MB) ----
    uint2* E0     = (uint2*)d_ws;                        // N_ENT*16  (19.2 MB)
    uint2* E1     = E0 + (size_t)N_ENT * 16;             // N_ENT*16  (19.2 MB)
    uint2* itemsA = E1 + (size_t)N_ENT * 16;             // N_ITEMS*16 (6.4 MB)
    uint2* itemsB = itemsA + (size_t)N_ITEMS * 16;       // N_ITEMS*16 (6.4 MB)
    int2*  upair  = (int2*)(itemsB + (size_t)N_ITEMS * 16);      // NNZ (8 MB)
    int*   col    = (int*)(upair + NNZ);                 // N_EDGES (8 MB)
    unsigned int* row_start   = (unsigned int*)(col + N_EDGES);  // N_ENT+1
    unsigned int* u_row_start = row_start + N_ENT + 1;           // N_USERS+1
    unsigned int* cntE  = u_row_start + N_USERS + 1;             // NB_E
    unsigned int* cntU  = cntE + NB_E;                           // NB_U
    unsigned int* baseE = cntU + NB_U;                           // NB_E+1
    unsigned int* curE  = baseE + NB_E + 1;                      // NB_E
    unsigned int* baseU = curE + NB_E;                           // NB_U+1
    unsigned int* curU  = baseU + NB_U + 1;                      // NB_U

    // build-time scratch:
    //  - binnedE aliased over E1 (8 MB < 19.2 MB): consumed by build_p4e, which
    //    completes before gf1_p4u_k writes E1.
    //  - binnedU/UV aliased over out_user (8 MB < 25.6 MB): consumed by the
    //    sort-U blocks of gf1_p4u_k; out_user is first really written by g2_u1_k.
    unsigned int* binnedE  = (unsigned int*)E1;                  // N_EDGES
    unsigned int* binnedU  = (unsigned int*)out_user;            // NNZ
    float*        binnedUV = (float*)(binnedU + NNZ);            // NNZ

    const int* head = edge_index;
    const int* tail = edge_index + N_EDGES;

    // ---- CSR builds (structure constant across hops) ----
    (void)hipMemsetAsync(cntE, 0, (size_t)(NB_E + NB_U) * 4, stream);
    build_p1<<<2 * NBLK_CNT + NBLK_CONV, 256, 0, stream>>>(head, iu, entity_emb, E0, cntE, cntU);
    build_p2<<<2, 512, 0, stream>>>(cntE, baseE, curE, cntU, baseU, curU);
    build_p3<<<NBLK_BS_E + NBLK_BS_U, 256, 0, stream>>>(head, tail, curE, binnedE,
                                                        iu, ii, iv, curU, binnedU, binnedUV);
    build_p4e<<<NB_E, 256, 0, stream>>>(baseE, binnedE, col, row_start);

    // ---- hop-1 gather+finalize (E0 -> E1, itemsA, out_ent) + user-side sort ----
    gf1_p4u_k<<<NB_U + GB_GATHER, 256, 0, stream>>>(E0, row_start, col, E1, itemsA,
                                                    entity_emb, out_ent,
                                                    baseU, binnedU, binnedUV,
                                                    upair, u_row_start);

    // ---- hop-2 gather+finalize co-scheduled with hop-1 user pipeline ----
    g2_u1_k<<<GB_GATHER + GB_USER, 256, 0, stream>>>(E1, row_start, col, itemsB,
                                                     out_ent, out_ent,
                                                     itemsA, u_row_start, upair,
                                                     user_emb, out_user);

    // ---- hop 2 user pipeline: out_user += u2 ----
    fused_user_k<<<GB_USER, 256, 0, stream>>>(itemsB, u_row_start, upair,
                                              out_user, out_user);
}

// Round 5
// 515.489 us; speedup vs baseline: 1.1639x; 1.0074x over previous
//
#include <hip/hip_runtime.h>

#define N_USERS   100000
#define N_ITEMS   50000
#define N_ENT     150000
#define N_EDGES   2000000
#define NNZ       1000000
#define CH        64

#define CB_SHIFT  9
#define CB_SIZE   512
#define NB_E      ((N_ENT   + CB_SIZE - 1) >> CB_SHIFT)   // 293
#define NB_U      ((N_USERS + CB_SIZE - 1) >> CB_SHIFT)   // 196
#define A_CHUNK   4096
#define UCACHE    32   // LDS-cached rows per user; fast path requires deg <= UCACHE

#define NBLK_CNT   512
#define NBLK_CONV  ((N_ENT * 16 + 255) / 256)             // 9375
#define NBLK_BS_E  ((N_EDGES + A_CHUNK - 1) / A_CHUNK)    // 489
#define NBLK_BS_U  ((NNZ + A_CHUNK - 1) / A_CHUNK)        // 245
#define GB_GATHER  (N_ENT / 4)                            // 37500 blocks (1 wave = 1 row)
#define GB_USER    (N_USERS / 4)                          // 25000 blocks

// ---- packed fp16 helpers: tables are fp16 pairs in uint2; math is v_pk_* ----
typedef __fp16 h2v __attribute__((ext_vector_type(2)));

__device__ __forceinline__ h2v h2z() { h2v z = {(__fp16)0.f, (__fp16)0.f}; return z; }
__device__ __forceinline__ h2v pk(float a, float b) { return __builtin_amdgcn_cvt_pkrtz(a, b); }
__device__ __forceinline__ unsigned int h2u(h2v h) { return __builtin_bit_cast(unsigned int, h); }
__device__ __forceinline__ h2v u2h(unsigned int u) { return __builtin_bit_cast(h2v, u); }
__device__ __forceinline__ float fdot2f(h2v a, h2v b, float c) {
    return __builtin_amdgcn_fdot2(a, b, c, false);   // f32 accumulate of packed f16 dot
}

// ---- DPP 16-lane all-reduce (VALU-only, no DS pipe; DPP row == 16-lane group) ----
template<int CTRL>
__device__ __forceinline__ float dpp_mov(float x) {
    return __builtin_bit_cast(float, __builtin_amdgcn_update_dpp(
        0, __builtin_bit_cast(int, x), CTRL, 0xF, 0xF, true));
}
__device__ __forceinline__ float red16(float x) {
    x += dpp_mov<0xB1>(x);    // quad_perm [1,0,3,2]  (xor 1)
    x += dpp_mov<0x4E>(x);    // quad_perm [2,3,0,1]  (xor 2)
    x += dpp_mov<0x140>(x);   // row_mirror           (cross-quad 0<->3, 1<->2)
    x += dpp_mov<0x141>(x);   // row_half_mirror      ({0,3} <-> {1,2})
    return x;                  // all 16 lanes hold the row sum
}

// =================== build phase, device bodies ===================

__device__ __forceinline__ void coarse_count_f(const int* __restrict__ key, int n,
                                               unsigned int* __restrict__ gcnt, int nb,
                                               unsigned int* h, int bid, int nblk) {
    for (int i = threadIdx.x; i < nb; i += blockDim.x) h[i] = 0;
    __syncthreads();
    for (int e = bid * blockDim.x + threadIdx.x; e < n; e += nblk * blockDim.x)
        atomicAdd(&h[key[e] >> CB_SHIFT], 1u);
    __syncthreads();
    for (int i = threadIdx.x; i < nb; i += blockDim.x)
        if (h[i]) atomicAdd(&gcnt[i], h[i]);
}

// p1: coarse counts (E and U) + fp32->fp16 convert of entity_emb, one dispatch
__global__ void build_p1(const int* __restrict__ head, const int* __restrict__ iu,
                         const float* __restrict__ entity_emb, uint2* __restrict__ E0,
                         unsigned int* __restrict__ cntE, unsigned int* __restrict__ cntU) {
    __shared__ unsigned int h[CB_SIZE];
    int bid = blockIdx.x;
    if (bid < NBLK_CNT) {
        coarse_count_f(head, N_EDGES, cntE, NB_E, h, bid, NBLK_CNT);
    } else if (bid < 2 * NBLK_CNT) {
        coarse_count_f(iu, NNZ, cntU, NB_U, h, bid - NBLK_CNT, NBLK_CNT);
    } else {
        int i = (bid - 2 * NBLK_CNT) * 256 + threadIdx.x;
        if (i < N_ENT * 16) {
            float4 a = ((const float4*)entity_emb)[i];
            E0[i] = make_uint2(h2u(pk(a.x, a.y)), h2u(pk(a.z, a.w)));
        }
    }
}

__device__ __forceinline__ void coarse_scan_f(const unsigned int* __restrict__ gcnt,
                                              unsigned int* __restrict__ base,
                                              unsigned int* __restrict__ cursor, int nb,
                                              unsigned int* s) {
    int t = threadIdx.x;
    unsigned int v = (t < nb) ? gcnt[t] : 0u;
    s[t] = v;
    __syncthreads();
    for (int off = 1; off < 512; off <<= 1) {
        unsigned int u = 0;
        if (t >= off) u = s[t - off];
        __syncthreads();
        if (t >= off) s[t] += u;
        __syncthreads();
    }
    if (t < nb) { base[t] = s[t] - v; cursor[t] = s[t] - v; }
    if (t == nb) base[t] = s[nb - 1];   // total
}

// p2: both exclusive scans in one dispatch (2 blocks)
__global__ void build_p2(const unsigned int* __restrict__ cntE, unsigned int* __restrict__ baseE,
                         unsigned int* __restrict__ curE,
                         const unsigned int* __restrict__ cntU, unsigned int* __restrict__ baseU,
                         unsigned int* __restrict__ curU) {
    __shared__ unsigned int s[512];
    if (blockIdx.x == 0) coarse_scan_f(cntE, baseE, curE, NB_E, s);
    else                 coarse_scan_f(cntU, baseU, curU, NB_U, s);
}

__device__ __forceinline__ void binscat_ent_f(const int* __restrict__ head,
                                              const int* __restrict__ tail,
                                              unsigned int* __restrict__ cursor,
                                              unsigned int* __restrict__ binned,
                                              unsigned int* h, unsigned int* bb, int bid) {
    int lo = bid * A_CHUNK;
    int hi = min(lo + A_CHUNK, N_EDGES);
    for (int i = threadIdx.x; i < NB_E; i += blockDim.x) h[i] = 0;
    __syncthreads();
    for (int e = lo + threadIdx.x; e < hi; e += blockDim.x)
        atomicAdd(&h[head[e] >> CB_SHIFT], 1u);
    __syncthreads();
    for (int i = threadIdx.x; i < NB_E; i += blockDim.x) {
        unsigned int c = h[i];
        bb[i] = c ? atomicAdd(&cursor[i], c) : 0u;
        h[i] = 0;
    }
    __syncthreads();
    for (int e = lo + threadIdx.x; e < hi; e += blockDim.x) {
        int hd = head[e];
        int b = hd >> CB_SHIFT;
        unsigned int r = atomicAdd(&h[b], 1u);
        unsigned int local = (unsigned int)hd & (CB_SIZE - 1);
        binned[bb[b] + r] = (local << 18) | (unsigned int)tail[e];   // tail < 2^18
    }
}

__device__ __forceinline__ void binscat_user_f(const int* __restrict__ iu,
                                               const int* __restrict__ ii,
                                               const float* __restrict__ iv,
                                               unsigned int* __restrict__ cursor,
                                               unsigned int* __restrict__ binned,
                                               float* __restrict__ binnedv,
                                               unsigned int* h, unsigned int* bb, int bid) {
    int lo = bid * A_CHUNK;
    int hi = min(lo + A_CHUNK, NNZ);
    for (int i = threadIdx.x; i < NB_U; i += blockDim.x) h[i] = 0;
    __syncthreads();
    for (int e = lo + threadIdx.x; e < hi; e += blockDim.x)
        atomicAdd(&h[iu[e] >> CB_SHIFT], 1u);
    __syncthreads();
    for (int i = threadIdx.x; i < NB_U; i += blockDim.x) {
        unsigned int c = h[i];
        bb[i] = c ? atomicAdd(&cursor[i], c) : 0u;
        h[i] = 0;
    }
    __syncthreads();
    for (int e = lo + threadIdx.x; e < hi; e += blockDim.x) {
        int u = iu[e];
        int b = u >> CB_SHIFT;
        unsigned int r = atomicAdd(&h[b], 1u);
        unsigned int slot = bb[b] + r;
        unsigned int local = (unsigned int)u & (CB_SIZE - 1);
        binned[slot] = (local << 16) | (unsigned int)ii[e];          // item < 2^16
        binnedv[slot] = iv[e];
    }
}

// p3e: entity bin scatter only
__global__ void build_p3e(const int* __restrict__ head, const int* __restrict__ tail,
                          unsigned int* __restrict__ curE, unsigned int* __restrict__ binnedE) {
    __shared__ unsigned int h[NB_E];
    __shared__ unsigned int bb[NB_E];
    binscat_ent_f(head, tail, curE, binnedE, h, bb, blockIdx.x);
}

__device__ __forceinline__ void build_ent_f(const unsigned int* __restrict__ base,
                                            const unsigned int* __restrict__ binned,
                                            int* __restrict__ col,
                                            unsigned int* __restrict__ row_start,
                                            unsigned int* h, unsigned int* ex,
                                            unsigned int* pairs, int b) {
    unsigned int s0 = base[b], s1 = base[b + 1];
    int t = threadIdx.x;
    h[2 * t] = 0; h[2 * t + 1] = 0;
    __syncthreads();
    for (unsigned int j = s0 + t; j < s1; j += 256)
        atomicAdd(&h[binned[j] >> 18], 1u);
    __syncthreads();
    unsigned int a0 = h[2 * t], a1 = h[2 * t + 1];
    pairs[t] = a0 + a1;
    __syncthreads();
    for (int off = 1; off < 256; off <<= 1) {
        unsigned int u = 0;
        if (t >= off) u = pairs[t - off];
        __syncthreads();
        if (t >= off) pairs[t] += u;
        __syncthreads();
    }
    unsigned int pe = pairs[t] - (a0 + a1);
    ex[2 * t] = pe;
    ex[2 * t + 1] = pe + a0;
    __syncthreads();
    int keybase = b << CB_SHIFT;
    #pragma unroll
    for (int k = 0; k < 2; ++k) {
        int i = 2 * t + k;
        int key = keybase + i;
        if (key < N_ENT) row_start[key] = s0 + ex[i];
    }
    if (b == 0 && t == 0) row_start[N_ENT] = base[NB_E];
    __syncthreads();
    h[2 * t] = 0; h[2 * t + 1] = 0;
    __syncthreads();
    for (unsigned int j = s0 + t; j < s1; j += 256) {
        unsigned int p = binned[j];
        unsigned int local = p >> 18;
        unsigned int r = atomicAdd(&h[local], 1u);
        col[s0 + ex[local] + r] = (int)(p & 0x3FFFFu);
    }
}

__device__ __forceinline__ void build_user_f(const unsigned int* __restrict__ base,
                                             const unsigned int* __restrict__ binned,
                                             const float* __restrict__ binnedv,
                                             int2* __restrict__ upair,
                                             unsigned int* __restrict__ u_row_start,
                                             unsigned int* h, unsigned int* ex,
                                             unsigned int* pairs, int b) {
    unsigned int s0 = base[b], s1 = base[b + 1];
    int t = threadIdx.x;
    h[2 * t] = 0; h[2 * t + 1] = 0;
    __syncthreads();
    for (unsigned int j = s0 + t; j < s1; j += 256)
        atomicAdd(&h[binned[j] >> 16], 1u);
    __syncthreads();
    unsigned int a0 = h[2 * t], a1 = h[2 * t + 1];
    pairs[t] = a0 + a1;
    __syncthreads();
    for (int off = 1; off < 256; off <<= 1) {
        unsigned int u = 0;
        if (t >= off) u = pairs[t - off];
        __syncthreads();
        if (t >= off) pairs[t] += u;
        __syncthreads();
    }
    unsigned int pe = pairs[t] - (a0 + a1);
    ex[2 * t] = pe;
    ex[2 * t + 1] = pe + a0;
    __syncthreads();
    int keybase = b << CB_SHIFT;
    #pragma unroll
    for (int k = 0; k < 2; ++k) {
        int i = 2 * t + k;
        int key = keybase + i;
        if (key < N_USERS) u_row_start[key] = s0 + ex[i];
    }
    if (b == 0 && t == 0) u_row_start[N_USERS] = base[NB_U];
    __syncthreads();
    h[2 * t] = 0; h[2 * t + 1] = 0;
    __syncthreads();
    for (unsigned int j = s0 + t; j < s1; j += 256) {
        unsigned int p = binned[j];
        float v = binnedv[j];
        unsigned int local = p >> 16;
        unsigned int r = atomicAdd(&h[local], 1u);
        upair[s0 + ex[local] + r] = make_int2((int)(p & 0xFFFFu), __float_as_int(v));
    }
}

// p3u+p4e: user bin scatter co-scheduled with entity counting sort
// (p4e depends only on binnedE, complete after p3e; p3u independent of both)
__global__ void build_p3u_p4e(const int* __restrict__ iu, const int* __restrict__ ii,
                              const float* __restrict__ iv, unsigned int* __restrict__ curU,
                              unsigned int* __restrict__ binnedU, float* __restrict__ binnedUV,
                              const unsigned int* __restrict__ baseE,
                              const unsigned int* __restrict__ binnedE,
                              int* __restrict__ col, unsigned int* __restrict__ row_start) {
    __shared__ unsigned int h[CB_SIZE];
    __shared__ unsigned int ex[CB_SIZE];
    __shared__ unsigned int pairs[256];
    if (blockIdx.x < NBLK_BS_U)
        binscat_user_f(iu, ii, iv, curU, binnedU, binnedUV, h, ex /*as bb, NB_U<=512*/, blockIdx.x);
    else
        build_ent_f(baseE, binnedE, col, row_start, h, ex, pairs, blockIdx.x - NBLK_BS_U);
}

// =================== hop kernels, device bodies ===================

// CSR gather (fp16 in, packed-fp16 acc) + fused finalize: mean -> items (fp16),
// l2norm -> ent_out (fp16, optional) and out_ent = base + norm.
__device__ __forceinline__ void gather_fin_row(int row, int lane,
        const uint2* __restrict__ entb, const unsigned int* __restrict__ row_start,
        const int* __restrict__ col,
        uint2* __restrict__ ent_out, uint2* __restrict__ items_out,
        const float* __restrict__ base_ent, float* __restrict__ out_ent,
        int write_ent) {
    int grp = lane >> 4;
    int t   = lane & 15;
    unsigned int s0 = row_start[row];
    unsigned int s1 = row_start[row + 1];

    h2v a0 = h2z(), a1 = h2z();
    unsigned int j = s0 + grp;
    for (; j + 4 < s1; j += 8) {
        uint2 a = entb[(size_t)col[j]     * 16 + t];
        uint2 b = entb[(size_t)col[j + 4] * 16 + t];
        a0 += u2h(a.x) + u2h(b.x);
        a1 += u2h(a.y) + u2h(b.y);
    }
    if (j < s1) {
        uint2 a = entb[(size_t)col[j] * 16 + t];
        a0 += u2h(a.x);
        a1 += u2h(a.y);
    }
    #pragma unroll
    for (int m = 16; m <= 32; m <<= 1) {
        a0 += u2h(__shfl_xor(h2u(a0), m, 64));
        a1 += u2h(__shfl_xor(h2u(a1), m, 64));
    }
    float inv = 1.0f / fmaxf((float)(s1 - s0), 1.0f);
    float mx = (float)a0[0] * inv, my = (float)a0[1] * inv;
    float mz = (float)a1[0] * inv, mw = (float)a1[1] * inv;

    float sq = red16(mx * mx + my * my + mz * mz + mw * mw);
    float invn = 1.0f / fmaxf(sqrtf(sq), 1e-12f);

    if (grp == 0) {
        size_t o = (size_t)row * 16 + t;
        if (row < N_ITEMS)
            items_out[o] = make_uint2(h2u(pk(mx, my)), h2u(pk(mz, mw)));
        float vx = mx * invn, vy = my * invn, vz = mz * invn, vw = mw * invn;
        if (write_ent)
            ent_out[o] = make_uint2(h2u(pk(vx, vy)), h2u(pk(vz, vw)));
        float4 c = ((const float4*)base_ent)[o];
        ((float4*)out_ent)[o] = make_float4(c.x + vx, c.y + vy, c.z + vz, c.w + vw);
    }
}

// two-phase softmax scoring over NS statically-unrolled slots (deg <= 4*NS)
template<int NS>
__device__ __forceinline__ void user_fast_score(
        unsigned int deg, int grp, int t, uint2 (*cw)[16],
        h2v um0, h2v um1, float& l, h2v& ac0, h2v& ac1) {
    const float SC = 5.0f * 1.44269504f;   // (1/TEMPERATURE) * log2(e)
    float scv[NS];
    float mloc = -1e30f;
    #pragma unroll
    for (int k = 0; k < NS; ++k) {
        unsigned int slot = (unsigned int)grp + 4u * k;
        if (slot < deg) {
            uint2 r = cw[slot][t];
            h2v d0 = u2h(r.x) - um0, d1 = u2h(r.y) - um1;
            float sq = red16(fdot2f(d1, d1, fdot2f(d0, d0, 0.0f)));
            float sc = sqrtf(sq) * SC;
            scv[k] = sc;
            mloc = fmaxf(mloc, sc);
        } else {
            scv[k] = -1e30f;
        }
    }
    float M = fmaxf(mloc, __shfl_xor(mloc, 16, 64));
    M = fmaxf(M, __shfl_xor(M, 32, 64));
    #pragma unroll
    for (int k = 0; k < NS; ++k) {
        unsigned int slot = (unsigned int)grp + 4u * k;
        if (slot < deg) {
            uint2 r = cw[slot][t];
            float e = exp2f(scv[k] - M);
            l += e;
            h2v e2 = pk(e, e);
            ac0 += e2 * u2h(r.x);
            ac1 += e2 * u2h(r.y);
        }
    }
}

// fused user pipeline: one wave per user, 4x16-lane groups, LDS row cache.
// deg-tiered fast path (4 or 8 unrolled slots); fallback: online softmax.
__device__ __forceinline__ void fused_user_row(int row, int lane, uint2 (*cw)[16],
        const uint2* __restrict__ itemsb, const unsigned int* __restrict__ u_row_start,
        const int2* __restrict__ up, const float* __restrict__ base_user,
        float* __restrict__ out_user) {
    int grp = lane >> 4;
    int t   = lane & 15;
    unsigned int s0 = u_row_start[row];
    unsigned int s1 = u_row_start[row + 1];
    unsigned int deg = s1 - s0;
    bool fast = deg <= UCACHE;

    // ---- pass 1: gather once, cache, weighted sum (packed fp16) ----
    h2v um0 = h2z(), um1 = h2z();
    if (fast) {
        for (unsigned int j = s0 + grp; j < s1; j += 4) {
            int2 p = up[j];
            uint2 r = itemsb[(size_t)p.x * 16 + t];
            cw[(int)(j - s0)][t] = r;            // deg<=UCACHE: always in range
            float v = __int_as_float(p.y);
            h2v v2 = pk(v, v);
            um0 += v2 * u2h(r.x);
            um1 += v2 * u2h(r.y);
        }
    } else {
        for (unsigned int j = s0 + grp; j < s1; j += 4) {
            int2 p = up[j];
            uint2 r = itemsb[(size_t)p.x * 16 + t];
            int slot = (int)(j - s0);
            if (slot < UCACHE) cw[slot][t] = r;
            float v = __int_as_float(p.y);
            h2v v2 = pk(v, v);
            um0 += v2 * u2h(r.x);
            um1 += v2 * u2h(r.y);
        }
    }
    #pragma unroll
    for (int m = 16; m <= 32; m <<= 1) {
        um0 += u2h(__shfl_xor(h2u(um0), m, 64));
        um1 += u2h(__shfl_xor(h2u(um1), m, 64));
    }
    // PDIST_EPS = 1e-6 underflows fp16 and shifts scores by <1e-5: omitted.

    const float SC = 5.0f * 1.44269504f;   // (1/TEMPERATURE) * log2(e)
    float l = 0.0f;
    h2v ac0 = h2z(), ac1 = h2z();

    if (__builtin_expect(fast, 1)) {
        if (deg <= 16) user_fast_score<4>(deg, grp, t, cw, um0, um1, l, ac0, ac1);
        else           user_fast_score<8>(deg, grp, t, cw, um0, um1, l, ac0, ac1);
        // common M across groups: plain sums
        #pragma unroll
        for (int m = 16; m <= 32; m <<= 1) {
            l   += __shfl_xor(l, m, 64);
            ac0 += u2h(__shfl_xor(h2u(ac0), m, 64));
            ac1 += u2h(__shfl_xor(h2u(ac1), m, 64));
        }
    } else {
        // ---- fallback: online softmax with per-group states ----
        float m_run = -1e30f;
        for (unsigned int j = s0 + grp; j < s1; j += 4) {
            int slot = (int)(j - s0);
            uint2 r = (slot < UCACHE) ? cw[slot][t]
                                      : itemsb[(size_t)up[j].x * 16 + t];
            h2v g0 = u2h(r.x), g1 = u2h(r.y);
            h2v d0 = g0 - um0, d1 = g1 - um1;
            float sq = red16(fdot2f(d1, d1, fdot2f(d0, d0, 0.0f)));
            float sc = sqrtf(sq) * SC;
            if (sc > m_run) {
                float s = exp2f(m_run - sc);
                l *= s;
                h2v s2 = pk(s, s);
                ac0 *= s2; ac1 *= s2;
                m_run = sc;
            }
            float e = exp2f(sc - m_run);
            l += e;
            h2v e2 = pk(e, e);
            ac0 += e2 * g0;
            ac1 += e2 * g1;
        }
        float M = fmaxf(m_run, __shfl_xor(m_run, 16, 64));
        M = fmaxf(M, __shfl_xor(M, 32, 64));
        float wgt = (l > 0.0f) ? exp2f(m_run - M) : 0.0f;
        l *= wgt;
        h2v w2 = pk(wgt, wgt);
        ac0 *= w2; ac1 *= w2;
        #pragma unroll
        for (int m = 16; m <= 32; m <<= 1) {
            l   += __shfl_xor(l, m, 64);
            ac0 += u2h(__shfl_xor(h2u(ac0), m, 64));
            ac1 += u2h(__shfl_xor(h2u(ac1), m, 64));
        }
    }

    float invl = (l > 0.0f) ? (1.0f / l) : 0.0f;
    float ux = (float)ac0[0] * invl, uy = (float)ac0[1] * invl;
    float uz = (float)ac1[0] * invl, uw = (float)ac1[1] * invl;

    float sq2 = red16(ux * ux + uy * uy + uz * uz + uw * uw);
    float inv = 1.0f / fmaxf(sqrtf(sq2), 1e-12f);
    if (grp == 0) {
        size_t o = (size_t)row * 16 + t;
        float4 c = ((const float4*)base_user)[o];
        ((float4*)out_user)[o] = make_float4(c.x + ux * inv, c.y + uy * inv,
                                             c.z + uz * inv, c.w + uw * inv);
    }
}

// =================== hop kernel wrappers ===================

// hop-1 gather+finalize co-scheduled with the user-side counting sort
// (independent work: gather needs only CSR-E + E0; sort-U consumes binnedU).
__global__ void gf1_p4u_k(const uint2* __restrict__ E0,
                          const unsigned int* __restrict__ row_start,
                          const int* __restrict__ col,
                          uint2* __restrict__ E1, uint2* __restrict__ itemsA,
                          const float* __restrict__ entity_emb, float* __restrict__ out_ent,
                          const unsigned int* __restrict__ baseU,
                          const unsigned int* __restrict__ binnedU,
                          const float* __restrict__ binnedUV,
                          int2* __restrict__ upair, unsigned int* __restrict__ u_row_start) {
    __shared__ unsigned int h[CB_SIZE];
    __shared__ unsigned int ex[CB_SIZE];
    __shared__ unsigned int pairs[256];
    int bid = blockIdx.x;
    if (bid < NB_U) {
        build_user_f(baseU, binnedU, binnedUV, upair, u_row_start, h, ex, pairs, bid);
    } else {
        int row  = (bid - NB_U) * 4 + (threadIdx.x >> 6);
        gather_fin_row(row, threadIdx.x & 63, E0, row_start, col, E1, itemsA,
                       entity_emb, out_ent, 1);
    }
}

// combined: hop-2 gather+finalize co-scheduled with hop-1 fused_user (3:2 interleave)
__global__ void g2_u1_k(const uint2* __restrict__ entb,           // E1 (hop-1 normalized)
                        const unsigned int* __restrict__ row_start,
                        const int* __restrict__ col,
                        uint2* __restrict__ items_out,            // itemsB (hop-2 means)
                        const float* __restrict__ base_ent,       // out_ent (hop-1 result)
                        float* __restrict__ out_ent,
                        const uint2* __restrict__ itemsb1,        // itemsA (hop-1 means)
                        const unsigned int* __restrict__ u_row_start,
                        const int2* __restrict__ up,
                        const float* __restrict__ base_user,      // user_emb
                        float* __restrict__ out_user) {
    __shared__ uint2 cache[4][UCACHE][16];   // 16 KB (only user blocks use it)
    int bid = blockIdx.x;
    int g5 = bid / 5, r5 = bid - g5 * 5;     // 62500 = 12500 * 5 exactly
    int w    = threadIdx.x >> 6;
    int lane = threadIdx.x & 63;
    if (r5 < 3) {
        int row = (g5 * 3 + r5) * 4 + w;     // < 37500*4 = N_ENT exactly
        gather_fin_row(row, lane, entb, row_start, col, nullptr, items_out,
                       base_ent, out_ent, 0);
    } else {
        int row = (g5 * 2 + (r5 - 3)) * 4 + w;   // < 25000*4 = N_USERS exactly
        fused_user_row(row, lane, cache[w], itemsb1, u_row_start, up,
                       base_user, out_user);
    }
}

// hop-2 user pipeline (nothing left to overlap with)
__global__ void fused_user_k(const uint2* __restrict__ itemsb,
                             const unsigned int* __restrict__ u_row_start,
                             const int2* __restrict__ up,
                             const float* __restrict__ base_user,
                             float* __restrict__ out_user) {
    __shared__ uint2 cache[4][UCACHE][16];
    int wave = (blockIdx.x * blockDim.x + threadIdx.x) >> 6;
    int w    = threadIdx.x >> 6;
    int lane = threadIdx.x & 63;
    if (wave >= N_USERS) return;
    fused_user_row(wave, lane, cache[w], itemsb, u_row_start, up, base_user, out_user);
}

extern "C" void kernel_launch(void* const* d_in, const int* in_sizes, int n_in,
                              void* d_out, int out_size, void* d_ws, size_t ws_size,
                              hipStream_t stream) {
    const float* user_emb   = (const float*)d_in[0];
    const float* entity_emb = (const float*)d_in[1];
    const int*   edge_index = (const int*)d_in[3];
    const int*   iu = (const int*)d_in[5];
    const int*   ii = (const int*)d_in[6];
    const float* iv = (const float*)d_in[7];

    float* out_user = (float*)d_out;
    float* out_ent  = out_user + (size_t)N_USERS * CH;

    // ---- workspace layout (~68.3 MB) ----
    uint2* E0     = (uint2*)d_ws;                        // N_ENT*16  (19.2 MB)
    uint2* E1     = E0 + (size_t)N_ENT * 16;             // N_ENT*16  (19.2 MB)
    uint2* itemsA = E1 + (size_t)N_ENT * 16;             // N_ITEMS*16 (6.4 MB)
    uint2* itemsB = itemsA + (size_t)N_ITEMS * 16;       // N_ITEMS*16 (6.4 MB)
    int2*  upair  = (int2*)(itemsB + (size_t)N_ITEMS * 16);      // NNZ (8 MB)
    int*   col    = (int*)(upair + NNZ);                 // N_EDGES (8 MB)
    unsigned int* row_start   = (unsigned int*)(col + N_EDGES);  // N_ENT+1
    unsigned int* u_row_start = row_start + N_ENT + 1;           // N_USERS+1
    unsigned int* cntE  = u_row_start + N_USERS + 1;             // NB_E
    unsigned int* cntU  = cntE + NB_E;                           // NB_U
    unsigned int* baseE = cntU + NB_U;                           // NB_E+1
    unsigned int* curE  = baseE + NB_E + 1;                      // NB_E
    unsigned int* baseU = curE + NB_E;                           // NB_U+1
    unsigned int* curU  = baseU + NB_U + 1;                      // NB_U

    // build-time scratch:
    //  - binnedE aliased over E1 (8 MB < 19.2 MB): consumed by build_p3u_p4e, which
    //    completes before gf1_p4u_k writes E1.
    //  - binnedU/UV aliased over out_user (8 MB < 25.6 MB): consumed by the
    //    sort-U blocks of gf1_p4u_k; out_user is first really written by g2_u1_k.
    unsigned int* binnedE  = (unsigned int*)E1;                  // N_EDGES
    unsigned int* binnedU  = (unsigned int*)out_user;            // NNZ
    float*        binnedUV = (float*)(binnedU + NNZ);            // NNZ

    const int* head = edge_index;
    const int* tail = edge_index + N_EDGES;

    // ---- CSR builds (structure constant across hops) ----
    (void)hipMemsetAsync(cntE, 0, (size_t)(NB_E + NB_U) * 4, stream);
    build_p1<<<2 * NBLK_CNT + NBLK_CONV, 256, 0, stream>>>(head, iu, entity_emb, E0, cntE, cntU);
    build_p2<<<2, 512, 0, stream>>>(cntE, baseE, curE, cntU, baseU, curU);
    build_p3e<<<NBLK_BS_E, 256, 0, stream>>>(head, tail, curE, binnedE);
    build_p3u_p4e<<<NBLK_BS_U + NB_E, 256, 0, stream>>>(iu, ii, iv, curU, binnedU, binnedUV,
                                                        baseE, binnedE, col, row_start);

    // ---- hop-1 gather+finalize (E0 -> E1, itemsA, out_ent) + user-side sort ----
    gf1_p4u_k<<<NB_U + GB_GATHER, 256, 0, stream>>>(E0, row_start, col, E1, itemsA,
                                                    entity_emb, out_ent,
                                                    baseU, binnedU, binnedUV,
                                                    upair, u_row_start);

    // ---- hop-2 gather+finalize co-scheduled with hop-1 user pipeline ----
    g2_u1_k<<<GB_GATHER + GB_USER, 256, 0, stream>>>(E1, row_start, col, itemsB,
                                                     out_ent, out_ent,
                                                     itemsA, u_row_start, upair,
                                                     user_emb, out_user);

    // ---- hop 2 user pipeline: out_user += u2 ----
    fused_user_k<<<GB_USER, 256, 0, stream>>>(itemsB, u_row_start, upair,
                                              out_user, out_user);
}

// Round 6
// 496.914 us; speedup vs baseline: 1.2074x; 1.0374x over previous
//
#include <hip/hip_runtime.h>

#define N_USERS   100000
#define N_ITEMS   50000
#define N_ENT     150000
#define N_EDGES   2000000
#define NNZ       1000000
#define CH        64

#define CB_SHIFT  9
#define CB_SIZE   512
#define NB_E      ((N_ENT   + CB_SIZE - 1) >> CB_SHIFT)   // 293
#define NB_U      ((N_USERS + CB_SIZE - 1) >> CB_SHIFT)   // 196
#define A_CHUNK   4096
#define UCACHE    32   // register/LDS fast-path bound; fallback handles deg > UCACHE

#define NBLK_CNT   512
#define NBLK_CONV  ((N_ENT * 16 + 255) / 256)             // 9375
#define NBLK_BS_E  ((N_EDGES + A_CHUNK - 1) / A_CHUNK)    // 489
#define NBLK_BS_U  ((NNZ + A_CHUNK - 1) / A_CHUNK)        // 245
#define GB_GATHER  (N_ENT / 4)                            // 37500 blocks (1 wave = 1 row)
#define GB_USER    (N_USERS / 4)                          // 25000 blocks

// ---- packed fp16 helpers: tables are fp16 pairs in uint2; math is v_pk_* ----
typedef __fp16 h2v __attribute__((ext_vector_type(2)));

__device__ __forceinline__ h2v h2z() { h2v z = {(__fp16)0.f, (__fp16)0.f}; return z; }
__device__ __forceinline__ h2v pk(float a, float b) { return __builtin_amdgcn_cvt_pkrtz(a, b); }
__device__ __forceinline__ unsigned int h2u(h2v h) { return __builtin_bit_cast(unsigned int, h); }
__device__ __forceinline__ h2v u2h(unsigned int u) { return __builtin_bit_cast(h2v, u); }
__device__ __forceinline__ float fdot2f(h2v a, h2v b, float c) {
    return __builtin_amdgcn_fdot2(a, b, c, false);   // f32 accumulate of packed f16 dot
}

// ---- DPP 16-lane all-reduce (VALU-only, no DS pipe; DPP row == 16-lane group) ----
template<int CTRL>
__device__ __forceinline__ float dpp_mov(float x) {
    return __builtin_bit_cast(float, __builtin_amdgcn_update_dpp(
        0, __builtin_bit_cast(int, x), CTRL, 0xF, 0xF, true));
}
__device__ __forceinline__ float red16(float x) {
    x += dpp_mov<0xB1>(x);    // quad_perm [1,0,3,2]  (xor 1)
    x += dpp_mov<0x4E>(x);    // quad_perm [2,3,0,1]  (xor 2)
    x += dpp_mov<0x140>(x);   // row_mirror           (cross-quad 0<->3, 1<->2)
    x += dpp_mov<0x141>(x);   // row_half_mirror      ({0,3} <-> {1,2})
    return x;                  // all 16 lanes hold the row sum
}

// =================== build phase, device bodies ===================

__device__ __forceinline__ void coarse_count_f(const int* __restrict__ key, int n,
                                               unsigned int* __restrict__ gcnt, int nb,
                                               unsigned int* h, int bid, int nblk) {
    for (int i = threadIdx.x; i < nb; i += blockDim.x) h[i] = 0;
    __syncthreads();
    for (int e = bid * blockDim.x + threadIdx.x; e < n; e += nblk * blockDim.x)
        atomicAdd(&h[key[e] >> CB_SHIFT], 1u);
    __syncthreads();
    for (int i = threadIdx.x; i < nb; i += blockDim.x)
        if (h[i]) atomicAdd(&gcnt[i], h[i]);
}

// p1: coarse counts (E and U) + fp32->fp16 convert of entity_emb, one dispatch
__global__ void build_p1(const int* __restrict__ head, const int* __restrict__ iu,
                         const float* __restrict__ entity_emb, uint2* __restrict__ E0,
                         unsigned int* __restrict__ cntE, unsigned int* __restrict__ cntU) {
    __shared__ unsigned int h[CB_SIZE];
    int bid = blockIdx.x;
    if (bid < NBLK_CNT) {
        coarse_count_f(head, N_EDGES, cntE, NB_E, h, bid, NBLK_CNT);
    } else if (bid < 2 * NBLK_CNT) {
        coarse_count_f(iu, NNZ, cntU, NB_U, h, bid - NBLK_CNT, NBLK_CNT);
    } else {
        int i = (bid - 2 * NBLK_CNT) * 256 + threadIdx.x;
        if (i < N_ENT * 16) {
            float4 a = ((const float4*)entity_emb)[i];
            E0[i] = make_uint2(h2u(pk(a.x, a.y)), h2u(pk(a.z, a.w)));
        }
    }
}

__device__ __forceinline__ void coarse_scan_f(const unsigned int* __restrict__ gcnt,
                                              unsigned int* __restrict__ base,
                                              unsigned int* __restrict__ cursor, int nb,
                                              unsigned int* s) {
    int t = threadIdx.x;
    unsigned int v = (t < nb) ? gcnt[t] : 0u;
    s[t] = v;
    __syncthreads();
    for (int off = 1; off < 512; off <<= 1) {
        unsigned int u = 0;
        if (t >= off) u = s[t - off];
        __syncthreads();
        if (t >= off) s[t] += u;
        __syncthreads();
    }
    if (t < nb) { base[t] = s[t] - v; cursor[t] = s[t] - v; }
    if (t == nb) base[t] = s[nb - 1];   // total
}

// p2: both exclusive scans in one dispatch (2 blocks)
__global__ void build_p2(const unsigned int* __restrict__ cntE, unsigned int* __restrict__ baseE,
                         unsigned int* __restrict__ curE,
                         const unsigned int* __restrict__ cntU, unsigned int* __restrict__ baseU,
                         unsigned int* __restrict__ curU) {
    __shared__ unsigned int s[512];
    if (blockIdx.x == 0) coarse_scan_f(cntE, baseE, curE, NB_E, s);
    else                 coarse_scan_f(cntU, baseU, curU, NB_U, s);
}

__device__ __forceinline__ void binscat_ent_f(const int* __restrict__ head,
                                              const int* __restrict__ tail,
                                              unsigned int* __restrict__ cursor,
                                              unsigned int* __restrict__ binned,
                                              unsigned int* h, unsigned int* bb, int bid) {
    int lo = bid * A_CHUNK;
    int hi = min(lo + A_CHUNK, N_EDGES);
    for (int i = threadIdx.x; i < NB_E; i += blockDim.x) h[i] = 0;
    __syncthreads();
    for (int e = lo + threadIdx.x; e < hi; e += blockDim.x)
        atomicAdd(&h[head[e] >> CB_SHIFT], 1u);
    __syncthreads();
    for (int i = threadIdx.x; i < NB_E; i += blockDim.x) {
        unsigned int c = h[i];
        bb[i] = c ? atomicAdd(&cursor[i], c) : 0u;
        h[i] = 0;
    }
    __syncthreads();
    for (int e = lo + threadIdx.x; e < hi; e += blockDim.x) {
        int hd = head[e];
        int b = hd >> CB_SHIFT;
        unsigned int r = atomicAdd(&h[b], 1u);
        unsigned int local = (unsigned int)hd & (CB_SIZE - 1);
        binned[bb[b] + r] = (local << 18) | (unsigned int)tail[e];   // tail < 2^18
    }
}

__device__ __forceinline__ void binscat_user_f(const int* __restrict__ iu,
                                               const int* __restrict__ ii,
                                               const float* __restrict__ iv,
                                               unsigned int* __restrict__ cursor,
                                               unsigned int* __restrict__ binned,
                                               float* __restrict__ binnedv,
                                               unsigned int* h, unsigned int* bb, int bid) {
    int lo = bid * A_CHUNK;
    int hi = min(lo + A_CHUNK, NNZ);
    for (int i = threadIdx.x; i < NB_U; i += blockDim.x) h[i] = 0;
    __syncthreads();
    for (int e = lo + threadIdx.x; e < hi; e += blockDim.x)
        atomicAdd(&h[iu[e] >> CB_SHIFT], 1u);
    __syncthreads();
    for (int i = threadIdx.x; i < NB_U; i += blockDim.x) {
        unsigned int c = h[i];
        bb[i] = c ? atomicAdd(&cursor[i], c) : 0u;
        h[i] = 0;
    }
    __syncthreads();
    for (int e = lo + threadIdx.x; e < hi; e += blockDim.x) {
        int u = iu[e];
        int b = u >> CB_SHIFT;
        unsigned int r = atomicAdd(&h[b], 1u);
        unsigned int slot = bb[b] + r;
        unsigned int local = (unsigned int)u & (CB_SIZE - 1);
        binned[slot] = (local << 16) | (unsigned int)ii[e];          // item < 2^16
        binnedv[slot] = iv[e];
    }
}

// p3e: entity bin scatter only
__global__ void build_p3e(const int* __restrict__ head, const int* __restrict__ tail,
                          unsigned int* __restrict__ curE, unsigned int* __restrict__ binnedE) {
    __shared__ unsigned int h[NB_E];
    __shared__ unsigned int bb[NB_E];
    binscat_ent_f(head, tail, curE, binnedE, h, bb, blockIdx.x);
}

__device__ __forceinline__ void build_ent_f(const unsigned int* __restrict__ base,
                                            const unsigned int* __restrict__ binned,
                                            int* __restrict__ col,
                                            unsigned int* __restrict__ row_start,
                                            unsigned int* h, unsigned int* ex,
                                            unsigned int* pairs, int b) {
    unsigned int s0 = base[b], s1 = base[b + 1];
    int t = threadIdx.x;
    h[2 * t] = 0; h[2 * t + 1] = 0;
    __syncthreads();
    for (unsigned int j = s0 + t; j < s1; j += 256)
        atomicAdd(&h[binned[j] >> 18], 1u);
    __syncthreads();
    unsigned int a0 = h[2 * t], a1 = h[2 * t + 1];
    pairs[t] = a0 + a1;
    __syncthreads();
    for (int off = 1; off < 256; off <<= 1) {
        unsigned int u = 0;
        if (t >= off) u = pairs[t - off];
        __syncthreads();
        if (t >= off) pairs[t] += u;
        __syncthreads();
    }
    unsigned int pe = pairs[t] - (a0 + a1);
    ex[2 * t] = pe;
    ex[2 * t + 1] = pe + a0;
    __syncthreads();
    int keybase = b << CB_SHIFT;
    #pragma unroll
    for (int k = 0; k < 2; ++k) {
        int i = 2 * t + k;
        int key = keybase + i;
        if (key < N_ENT) row_start[key] = s0 + ex[i];
    }
    if (b == 0 && t == 0) row_start[N_ENT] = base[NB_E];
    __syncthreads();
    h[2 * t] = 0; h[2 * t + 1] = 0;
    __syncthreads();
    for (unsigned int j = s0 + t; j < s1; j += 256) {
        unsigned int p = binned[j];
        unsigned int local = p >> 18;
        unsigned int r = atomicAdd(&h[local], 1u);
        col[s0 + ex[local] + r] = (int)(p & 0x3FFFFu);
    }
}

__device__ __forceinline__ void build_user_f(const unsigned int* __restrict__ base,
                                             const unsigned int* __restrict__ binned,
                                             const float* __restrict__ binnedv,
                                             int2* __restrict__ upair,
                                             unsigned int* __restrict__ u_row_start,
                                             unsigned int* h, unsigned int* ex,
                                             unsigned int* pairs, int b) {
    unsigned int s0 = base[b], s1 = base[b + 1];
    int t = threadIdx.x;
    h[2 * t] = 0; h[2 * t + 1] = 0;
    __syncthreads();
    for (unsigned int j = s0 + t; j < s1; j += 256)
        atomicAdd(&h[binned[j] >> 16], 1u);
    __syncthreads();
    unsigned int a0 = h[2 * t], a1 = h[2 * t + 1];
    pairs[t] = a0 + a1;
    __syncthreads();
    for (int off = 1; off < 256; off <<= 1) {
        unsigned int u = 0;
        if (t >= off) u = pairs[t - off];
        __syncthreads();
        if (t >= off) pairs[t] += u;
        __syncthreads();
    }
    unsigned int pe = pairs[t] - (a0 + a1);
    ex[2 * t] = pe;
    ex[2 * t + 1] = pe + a0;
    __syncthreads();
    int keybase = b << CB_SHIFT;
    #pragma unroll
    for (int k = 0; k < 2; ++k) {
        int i = 2 * t + k;
        int key = keybase + i;
        if (key < N_USERS) u_row_start[key] = s0 + ex[i];
    }
    if (b == 0 && t == 0) u_row_start[N_USERS] = base[NB_U];
    __syncthreads();
    h[2 * t] = 0; h[2 * t + 1] = 0;
    __syncthreads();
    for (unsigned int j = s0 + t; j < s1; j += 256) {
        unsigned int p = binned[j];
        float v = binnedv[j];
        unsigned int local = p >> 16;
        unsigned int r = atomicAdd(&h[local], 1u);
        upair[s0 + ex[local] + r] = make_int2((int)(p & 0xFFFFu), __float_as_int(v));
    }
}

// p3u+p4e: user bin scatter co-scheduled with entity counting sort
__global__ void build_p3u_p4e(const int* __restrict__ iu, const int* __restrict__ ii,
                              const float* __restrict__ iv, unsigned int* __restrict__ curU,
                              unsigned int* __restrict__ binnedU, float* __restrict__ binnedUV,
                              const unsigned int* __restrict__ baseE,
                              const unsigned int* __restrict__ binnedE,
                              int* __restrict__ col, unsigned int* __restrict__ row_start) {
    __shared__ unsigned int h[CB_SIZE];
    __shared__ unsigned int ex[CB_SIZE];
    __shared__ unsigned int pairs[256];
    if (blockIdx.x < NBLK_BS_U)
        binscat_user_f(iu, ii, iv, curU, binnedU, binnedUV, h, ex /*as bb*/, blockIdx.x);
    else
        build_ent_f(baseE, binnedE, col, row_start, h, ex, pairs, blockIdx.x - NBLK_BS_U);
}

// =================== hop kernels, device bodies ===================

// CSR gather (fp16 in, packed-fp16 acc, 4-deep MLP unroll) + fused finalize.
// mode 0 (hop 1): write ent_out = fp16(l2norm(mean)), items_out = fp16(mean).
// mode 1 (hop 2): write items_out = fp16(mean), out_ent = emb + fp16(v1) + v2.
__device__ __forceinline__ void gather_fin_row(int row, int lane,
        const uint2* __restrict__ entb, const unsigned int* __restrict__ row_start,
        const int* __restrict__ col,
        uint2* __restrict__ ent_out, uint2* __restrict__ items_out,
        const float* __restrict__ base_ent, const uint2* __restrict__ v1tab,
        float* __restrict__ out_ent, int mode) {
    int grp = lane >> 4;
    int t   = lane & 15;
    unsigned int s0 = row_start[row];
    unsigned int s1 = row_start[row + 1];

    h2v a0 = h2z(), a1 = h2z();
    unsigned int j = s0 + grp;
    for (; j + 12 < s1; j += 16) {               // 4 concurrent row loads per group
        uint2 x0 = entb[(size_t)col[j]      * 16 + t];
        uint2 x1 = entb[(size_t)col[j + 4]  * 16 + t];
        uint2 x2 = entb[(size_t)col[j + 8]  * 16 + t];
        uint2 x3 = entb[(size_t)col[j + 12] * 16 + t];
        a0 += (u2h(x0.x) + u2h(x1.x)) + (u2h(x2.x) + u2h(x3.x));
        a1 += (u2h(x0.y) + u2h(x1.y)) + (u2h(x2.y) + u2h(x3.y));
    }
    for (; j < s1; j += 4) {
        uint2 x = entb[(size_t)col[j] * 16 + t];
        a0 += u2h(x.x);
        a1 += u2h(x.y);
    }
    #pragma unroll
    for (int m = 16; m <= 32; m <<= 1) {
        a0 += u2h(__shfl_xor(h2u(a0), m, 64));
        a1 += u2h(__shfl_xor(h2u(a1), m, 64));
    }
    float inv = 1.0f / fmaxf((float)(s1 - s0), 1.0f);
    float mx = (float)a0[0] * inv, my = (float)a0[1] * inv;
    float mz = (float)a1[0] * inv, mw = (float)a1[1] * inv;

    float sq = red16(mx * mx + my * my + mz * mz + mw * mw);
    float invn = 1.0f / fmaxf(sqrtf(sq), 1e-12f);

    if (grp == 0) {
        size_t o = (size_t)row * 16 + t;
        if (row < N_ITEMS)
            items_out[o] = make_uint2(h2u(pk(mx, my)), h2u(pk(mz, mw)));
        float vx = mx * invn, vy = my * invn, vz = mz * invn, vw = mw * invn;
        if (mode == 0) {
            ent_out[o] = make_uint2(h2u(pk(vx, vy)), h2u(pk(vz, vw)));
        } else {
            float4 c = ((const float4*)base_ent)[o];     // entity_emb (fp32)
            uint2 v1 = v1tab[o];                          // E1 = fp16 v1
            h2v p0 = u2h(v1.x), p1 = u2h(v1.y);
            ((float4*)out_ent)[o] = make_float4(c.x + (float)p0[0] + vx,
                                                c.y + (float)p0[1] + vy,
                                                c.z + (float)p1[0] + vz,
                                                c.w + (float)p1[1] + vw);
        }
    }
}

// register-resident user fast path: rows live in r[NS] VGPRs (no LDS round-trip).
// Pass-2 slots (grp + 4k) are exactly the rows this group loaded in pass 1.
template<int NS>
__device__ __forceinline__ void user_fast_path(
        unsigned int s0, unsigned int deg, int grp, int t,
        const uint2* __restrict__ itemsb, const int2* __restrict__ up,
        float& l, h2v& ac0, h2v& ac1) {
    const float SC = 5.0f * 1.44269504f;   // (1/TEMPERATURE) * log2(e)
    uint2 r[NS];
    float vw[NS];
    #pragma unroll
    for (int k = 0; k < NS; ++k) {
        unsigned int slot = (unsigned int)grp + 4u * k;
        if (slot < deg) {
            int2 p = up[s0 + slot];
            r[k] = itemsb[(size_t)p.x * 16 + t];
            vw[k] = __int_as_float(p.y);
        } else {
            r[k] = make_uint2(0u, 0u);
            vw[k] = 0.0f;
        }
    }
    // weighted mean (invalid slots contribute 0)
    h2v um0 = h2z(), um1 = h2z();
    #pragma unroll
    for (int k = 0; k < NS; ++k) {
        h2v v2 = pk(vw[k], vw[k]);
        um0 += v2 * u2h(r[k].x);
        um1 += v2 * u2h(r[k].y);
    }
    #pragma unroll
    for (int m = 16; m <= 32; m <<= 1) {
        um0 += u2h(__shfl_xor(h2u(um0), m, 64));
        um1 += u2h(__shfl_xor(h2u(um1), m, 64));
    }
    // scores (branchless: invalid -> -1e30 -> exp2 -> 0)
    float scv[NS];
    float mloc = -1e30f;
    #pragma unroll
    for (int k = 0; k < NS; ++k) {
        unsigned int slot = (unsigned int)grp + 4u * k;
        h2v d0 = u2h(r[k].x) - um0, d1 = u2h(r[k].y) - um1;
        float sq = red16(fdot2f(d1, d1, fdot2f(d0, d0, 0.0f)));
        float sc = sqrtf(sq) * SC;
        scv[k] = (slot < deg) ? sc : -1e30f;
        mloc = fmaxf(mloc, scv[k]);
    }
    float M = fmaxf(mloc, __shfl_xor(mloc, 16, 64));
    M = fmaxf(M, __shfl_xor(M, 32, 64));
    #pragma unroll
    for (int k = 0; k < NS; ++k) {
        float e = exp2f(scv[k] - M);
        l += e;
        h2v e2 = pk(e, e);
        ac0 += e2 * u2h(r[k].x);
        ac1 += e2 * u2h(r[k].y);
    }
}

// fused user pipeline: one wave per user, 4x16-lane groups.
// deg<=16: 4-slot reg path; deg<=32: 8-slot reg path; else LDS online fallback.
__device__ __forceinline__ void fused_user_row(int row, int lane, uint2 (*cw)[16],
        const uint2* __restrict__ itemsb, const unsigned int* __restrict__ u_row_start,
        const int2* __restrict__ up, const float* __restrict__ base_user,
        float* __restrict__ out_user) {
    int grp = lane >> 4;
    int t   = lane & 15;
    unsigned int s0 = u_row_start[row];
    unsigned int s1 = u_row_start[row + 1];
    unsigned int deg = s1 - s0;

    const float SC = 5.0f * 1.44269504f;
    float l = 0.0f;
    h2v ac0 = h2z(), ac1 = h2z();

    if (__builtin_expect(deg <= 16, 1)) {
        user_fast_path<4>(s0, deg, grp, t, itemsb, up, l, ac0, ac1);
    } else if (deg <= UCACHE) {
        user_fast_path<8>(s0, deg, grp, t, itemsb, up, l, ac0, ac1);
    } else {
        // ---- fallback (deg > 32, ~never): LDS cache + online softmax ----
        h2v um0 = h2z(), um1 = h2z();
        for (unsigned int j = s0 + grp; j < s1; j += 4) {
            int2 p = up[j];
            uint2 r = itemsb[(size_t)p.x * 16 + t];
            int slot = (int)(j - s0);
            if (slot < UCACHE) cw[slot][t] = r;
            float v = __int_as_float(p.y);
            h2v v2 = pk(v, v);
            um0 += v2 * u2h(r.x);
            um1 += v2 * u2h(r.y);
        }
        #pragma unroll
        for (int m = 16; m <= 32; m <<= 1) {
            um0 += u2h(__shfl_xor(h2u(um0), m, 64));
            um1 += u2h(__shfl_xor(h2u(um1), m, 64));
        }
        float m_run = -1e30f;
        for (unsigned int j = s0 + grp; j < s1; j += 4) {
            int slot = (int)(j - s0);
            uint2 r = (slot < UCACHE) ? cw[slot][t]
                                      : itemsb[(size_t)up[j].x * 16 + t];
            h2v g0 = u2h(r.x), g1 = u2h(r.y);
            h2v d0 = g0 - um0, d1 = g1 - um1;
            float sq = red16(fdot2f(d1, d1, fdot2f(d0, d0, 0.0f)));
            float sc = sqrtf(sq) * SC;
            if (sc > m_run) {
                float s = exp2f(m_run - sc);
                l *= s;
                h2v s2 = pk(s, s);
                ac0 *= s2; ac1 *= s2;
                m_run = sc;
            }
            float e = exp2f(sc - m_run);
            l += e;
            h2v e2 = pk(e, e);
            ac0 += e2 * g0;
            ac1 += e2 * g1;
        }
        float M = fmaxf(m_run, __shfl_xor(m_run, 16, 64));
        M = fmaxf(M, __shfl_xor(M, 32, 64));
        float wgt = (l > 0.0f) ? exp2f(m_run - M) : 0.0f;
        l *= wgt;
        h2v w2 = pk(wgt, wgt);
        ac0 *= w2; ac1 *= w2;
    }

    // cross-group merge (fast paths share a common M; fallback pre-scaled)
    #pragma unroll
    for (int m = 16; m <= 32; m <<= 1) {
        l   += __shfl_xor(l, m, 64);
        ac0 += u2h(__shfl_xor(h2u(ac0), m, 64));
        ac1 += u2h(__shfl_xor(h2u(ac1), m, 64));
    }
    float invl = (l > 0.0f) ? (1.0f / l) : 0.0f;
    float ux = (float)ac0[0] * invl, uy = (float)ac0[1] * invl;
    float uz = (float)ac1[0] * invl, uw = (float)ac1[1] * invl;

    float sq2 = red16(ux * ux + uy * uy + uz * uz + uw * uw);
    float inv = 1.0f / fmaxf(sqrtf(sq2), 1e-12f);
    if (grp == 0) {
        size_t o = (size_t)row * 16 + t;
        float4 c = ((const float4*)base_user)[o];
        ((float4*)out_user)[o] = make_float4(c.x + ux * inv, c.y + uy * inv,
                                             c.z + uz * inv, c.w + uw * inv);
    }
}

// =================== hop kernel wrappers ===================

// hop-1 gather+finalize (no out_ent RMW) co-scheduled with the user-side sort
__global__ void gf1_p4u_k(const uint2* __restrict__ E0,
                          const unsigned int* __restrict__ row_start,
                          const int* __restrict__ col,
                          uint2* __restrict__ E1, uint2* __restrict__ itemsA,
                          const unsigned int* __restrict__ baseU,
                          const unsigned int* __restrict__ binnedU,
                          const float* __restrict__ binnedUV,
                          int2* __restrict__ upair, unsigned int* __restrict__ u_row_start) {
    __shared__ unsigned int h[CB_SIZE];
    __shared__ unsigned int ex[CB_SIZE];
    __shared__ unsigned int pairs[256];
    int bid = blockIdx.x;
    if (bid < NB_U) {
        build_user_f(baseU, binnedU, binnedUV, upair, u_row_start, h, ex, pairs, bid);
    } else {
        int row  = (bid - NB_U) * 4 + (threadIdx.x >> 6);
        gather_fin_row(row, threadIdx.x & 63, E0, row_start, col, E1, itemsA,
                       nullptr, nullptr, nullptr, 0);
    }
}

// combined: hop-2 gather+finalize (out_ent = emb + v1 + v2) co-scheduled with
// hop-1 fused_user (3:2 interleave)
__global__ void g2_u1_k(const uint2* __restrict__ entb,           // E1
                        const unsigned int* __restrict__ row_start,
                        const int* __restrict__ col,
                        uint2* __restrict__ items_out,            // itemsB
                        const float* __restrict__ entity_emb,
                        float* __restrict__ out_ent,
                        const uint2* __restrict__ itemsb1,        // itemsA
                        const unsigned int* __restrict__ u_row_start,
                        const int2* __restrict__ up,
                        const float* __restrict__ base_user,      // user_emb
                        float* __restrict__ out_user) {
    __shared__ uint2 cache[4][UCACHE][16];   // 16 KB (fallback only)
    int bid = blockIdx.x;
    int g5 = bid / 5, r5 = bid - g5 * 5;     // 62500 = 12500 * 5 exactly
    int w    = threadIdx.x >> 6;
    int lane = threadIdx.x & 63;
    if (r5 < 3) {
        int row = (g5 * 3 + r5) * 4 + w;     // < 37500*4 = N_ENT exactly
        gather_fin_row(row, lane, entb, row_start, col, nullptr, items_out,
                       entity_emb, entb, out_ent, 1);
    } else {
        int row = (g5 * 2 + (r5 - 3)) * 4 + w;   // < 25000*4 = N_USERS exactly
        fused_user_row(row, lane, cache[w], itemsb1, u_row_start, up,
                       base_user, out_user);
    }
}

// hop-2 user pipeline
__global__ void fused_user_k(const uint2* __restrict__ itemsb,
                             const unsigned int* __restrict__ u_row_start,
                             const int2* __restrict__ up,
                             const float* __restrict__ base_user,
                             float* __restrict__ out_user) {
    __shared__ uint2 cache[4][UCACHE][16];
    int wave = (blockIdx.x * blockDim.x + threadIdx.x) >> 6;
    int w    = threadIdx.x >> 6;
    int lane = threadIdx.x & 63;
    if (wave >= N_USERS) return;
    fused_user_row(wave, lane, cache[w], itemsb, u_row_start, up, base_user, out_user);
}

extern "C" void kernel_launch(void* const* d_in, const int* in_sizes, int n_in,
                              void* d_out, int out_size, void* d_ws, size_t ws_size,
                              hipStream_t stream) {
    const float* user_emb   = (const float*)d_in[0];
    const float* entity_emb = (const float*)d_in[1];
    const int*   edge_index = (const int*)d_in[3];
    const int*   iu = (const int*)d_in[5];
    const int*   ii = (const int*)d_in[6];
    const float* iv = (const float*)d_in[7];

    float* out_user = (float*)d_out;
    float* out_ent  = out_user + (size_t)N_USERS * CH;

    // ---- workspace layout (~68.3 MB) ----
    uint2* E0     = (uint2*)d_ws;                        // N_ENT*16  (19.2 MB)
    uint2* E1     = E0 + (size_t)N_ENT * 16;             // N_ENT*16  (19.2 MB)
    uint2* itemsA = E1 + (size_t)N_ENT * 16;             // N_ITEMS*16 (6.4 MB)
    uint2* itemsB = itemsA + (size_t)N_ITEMS * 16;       // N_ITEMS*16 (6.4 MB)
    int2*  upair  = (int2*)(itemsB + (size_t)N_ITEMS * 16);      // NNZ (8 MB)
    int*   col    = (int*)(upair + NNZ);                 // N_EDGES (8 MB)
    unsigned int* row_start   = (unsigned int*)(col + N_EDGES);  // N_ENT+1
    unsigned int* u_row_start = row_start + N_ENT + 1;           // N_USERS+1
    unsigned int* cntE  = u_row_start + N_USERS + 1;             // NB_E
    unsigned int* cntU  = cntE + NB_E;                           // NB_U
    unsigned int* baseE = cntU + NB_U;                           // NB_E+1
    unsigned int* curE  = baseE + NB_E + 1;                      // NB_E
    unsigned int* baseU = curE + NB_E;                           // NB_U+1
    unsigned int* curU  = baseU + NB_U + 1;                      // NB_U

    // build-time scratch:
    //  - binnedE aliased over E1: consumed by build_p3u_p4e, before gf1 writes E1.
    //  - binnedU/UV aliased over out_user: consumed by gf1's sort-U blocks;
    //    out_user first really written by g2_u1_k.
    unsigned int* binnedE  = (unsigned int*)E1;                  // N_EDGES
    unsigned int* binnedU  = (unsigned int*)out_user;            // NNZ
    float*        binnedUV = (float*)(binnedU + NNZ);            // NNZ

    const int* head = edge_index;
    const int* tail = edge_index + N_EDGES;

    // ---- CSR builds (structure constant across hops) ----
    (void)hipMemsetAsync(cntE, 0, (size_t)(NB_E + NB_U) * 4, stream);
    build_p1<<<2 * NBLK_CNT + NBLK_CONV, 256, 0, stream>>>(head, iu, entity_emb, E0, cntE, cntU);
    build_p2<<<2, 512, 0, stream>>>(cntE, baseE, curE, cntU, baseU, curU);
    build_p3e<<<NBLK_BS_E, 256, 0, stream>>>(head, tail, curE, binnedE);
    build_p3u_p4e<<<NBLK_BS_U + NB_E, 256, 0, stream>>>(iu, ii, iv, curU, binnedU, binnedUV,
                                                        baseE, binnedE, col, row_start);

    // ---- hop-1 gather+finalize (E0 -> E1, itemsA) + user-side sort ----
    gf1_p4u_k<<<NB_U + GB_GATHER, 256, 0, stream>>>(E0, row_start, col, E1, itemsA,
                                                    baseU, binnedU, binnedUV,
                                                    upair, u_row_start);

    // ---- hop-2 gather+finalize (out_ent = emb + v1 + v2) + hop-1 user ----
    g2_u1_k<<<GB_GATHER + GB_USER, 256, 0, stream>>>(E1, row_start, col, itemsB,
                                                     entity_emb, out_ent,
                                                     itemsA, u_row_start, upair,
                                                     user_emb, out_user);

    // ---- hop 2 user pipeline: out_user += u2 ----
    fused_user_k<<<GB_USER, 256, 0, stream>>>(itemsB, u_row_start, upair,
                                              out_user, out_user);
}

// Round 7
// 463.599 us; speedup vs baseline: 1.2942x; 1.0719x over previous
//
#include <hip/hip_runtime.h>

#define N_USERS   100000
#define N_ITEMS   50000
#define N_ENT     150000
#define N_EDGES   2000000
#define NNZ       1000000
#define CH        64

#define CB_SHIFT  9
#define CB_SIZE   512
#define NB_E      ((N_ENT   + CB_SIZE - 1) >> CB_SHIFT)   // 293
#define NB_U      ((N_USERS + CB_SIZE - 1) >> CB_SHIFT)   // 196
#define A_CHUNK   4096
#define UCACHE    32   // register/LDS fast-path bound; fallback handles deg > UCACHE

#define NBLK_CNT   512
#define NBLK_CONV  ((N_ENT * 16 + 255) / 256)             // 9375
#define NBLK_BS_E  ((N_EDGES + A_CHUNK - 1) / A_CHUNK)    // 489
#define NBLK_BS_U  ((NNZ + A_CHUNK - 1) / A_CHUNK)        // 245
#define GB_GATHER  (N_ENT / 4)                            // 37500 blocks (1 wave = 1 row)
#define GB_USER    (N_USERS / 4)                          // 25000 blocks

// ---- packed fp16 helpers: tables are fp16; rows are 8 lanes x uint4 (16B) ----
typedef __fp16 h2v __attribute__((ext_vector_type(2)));

__device__ __forceinline__ h2v h2z() { h2v z = {(__fp16)0.f, (__fp16)0.f}; return z; }
__device__ __forceinline__ h2v pk(float a, float b) { return __builtin_amdgcn_cvt_pkrtz(a, b); }
__device__ __forceinline__ unsigned int h2u(h2v h) { return __builtin_bit_cast(unsigned int, h); }
__device__ __forceinline__ h2v u2h(unsigned int u) { return __builtin_bit_cast(h2v, u); }
__device__ __forceinline__ float fdot2f(h2v a, h2v b, float c) {
    return __builtin_amdgcn_fdot2(a, b, c, false);   // f32 accumulate of packed f16 dot
}

// ---- DPP helpers (VALU-only cross-lane; DPP row = 16 lanes) ----
template<int CTRL>
__device__ __forceinline__ float dpp_mov(float x) {
    return __builtin_bit_cast(float, __builtin_amdgcn_update_dpp(
        0, __builtin_bit_cast(int, x), CTRL, 0xF, 0xF, true));
}
template<int CTRL>
__device__ __forceinline__ unsigned dpp_mov_u(unsigned x) {
    return (unsigned)__builtin_amdgcn_update_dpp(0, (int)x, CTRL, 0xF, 0xF, true);
}
// 8-lane all-reduce sum (within each 8-lane group): quads then cross-quad mirror
__device__ __forceinline__ float red8(float x) {
    x += dpp_mov<0xB1>(x);    // quad_perm [1,0,3,2]  (xor 1)
    x += dpp_mov<0x4E>(x);    // quad_perm [2,3,0,1]  (xor 2)
    x += dpp_mov<0x141>(x);   // row_half_mirror: i<->7-i within 8 (cross-quad)
    return x;
}
// lane^8 partner add for packed fp16 (row_ror:8 == xor8 within the 16-lane row)
__device__ __forceinline__ h2v grpadd8(h2v a) {
    return a + u2h(dpp_mov_u<0x128>(h2u(a)));
}

// =================== build phase, device bodies ===================

__device__ __forceinline__ void coarse_count_f(const int* __restrict__ key, int n,
                                               unsigned int* __restrict__ gcnt, int nb,
                                               unsigned int* h, int bid, int nblk) {
    for (int i = threadIdx.x; i < nb; i += blockDim.x) h[i] = 0;
    __syncthreads();
    for (int e = bid * blockDim.x + threadIdx.x; e < n; e += nblk * blockDim.x)
        atomicAdd(&h[key[e] >> CB_SHIFT], 1u);
    __syncthreads();
    for (int i = threadIdx.x; i < nb; i += blockDim.x)
        if (h[i]) atomicAdd(&gcnt[i], h[i]);
}

// p1: coarse counts (E and U) + fp32->fp16 convert of entity_emb, one dispatch
__global__ void build_p1(const int* __restrict__ head, const int* __restrict__ iu,
                         const float* __restrict__ entity_emb, uint2* __restrict__ E0,
                         unsigned int* __restrict__ cntE, unsigned int* __restrict__ cntU) {
    __shared__ unsigned int h[CB_SIZE];
    int bid = blockIdx.x;
    if (bid < NBLK_CNT) {
        coarse_count_f(head, N_EDGES, cntE, NB_E, h, bid, NBLK_CNT);
    } else if (bid < 2 * NBLK_CNT) {
        coarse_count_f(iu, NNZ, cntU, NB_U, h, bid - NBLK_CNT, NBLK_CNT);
    } else {
        int i = (bid - 2 * NBLK_CNT) * 256 + threadIdx.x;
        if (i < N_ENT * 16) {
            float4 a = ((const float4*)entity_emb)[i];
            E0[i] = make_uint2(h2u(pk(a.x, a.y)), h2u(pk(a.z, a.w)));
        }
    }
}

__device__ __forceinline__ void coarse_scan_f(const unsigned int* __restrict__ gcnt,
                                              unsigned int* __restrict__ base,
                                              unsigned int* __restrict__ cursor, int nb,
                                              unsigned int* s) {
    int t = threadIdx.x;
    unsigned int v = (t < nb) ? gcnt[t] : 0u;
    s[t] = v;
    __syncthreads();
    for (int off = 1; off < 512; off <<= 1) {
        unsigned int u = 0;
        if (t >= off) u = s[t - off];
        __syncthreads();
        if (t >= off) s[t] += u;
        __syncthreads();
    }
    if (t < nb) { base[t] = s[t] - v; cursor[t] = s[t] - v; }
    if (t == nb) base[t] = s[nb - 1];   // total
}

// p2: both exclusive scans in one dispatch (2 blocks)
__global__ void build_p2(const unsigned int* __restrict__ cntE, unsigned int* __restrict__ baseE,
                         unsigned int* __restrict__ curE,
                         const unsigned int* __restrict__ cntU, unsigned int* __restrict__ baseU,
                         unsigned int* __restrict__ curU) {
    __shared__ unsigned int s[512];
    if (blockIdx.x == 0) coarse_scan_f(cntE, baseE, curE, NB_E, s);
    else                 coarse_scan_f(cntU, baseU, curU, NB_U, s);
}

__device__ __forceinline__ void binscat_ent_f(const int* __restrict__ head,
                                              const int* __restrict__ tail,
                                              unsigned int* __restrict__ cursor,
                                              unsigned int* __restrict__ binned,
                                              unsigned int* h, unsigned int* bb, int bid) {
    int lo = bid * A_CHUNK;
    int hi = min(lo + A_CHUNK, N_EDGES);
    for (int i = threadIdx.x; i < NB_E; i += blockDim.x) h[i] = 0;
    __syncthreads();
    for (int e = lo + threadIdx.x; e < hi; e += blockDim.x)
        atomicAdd(&h[head[e] >> CB_SHIFT], 1u);
    __syncthreads();
    for (int i = threadIdx.x; i < NB_E; i += blockDim.x) {
        unsigned int c = h[i];
        bb[i] = c ? atomicAdd(&cursor[i], c) : 0u;
        h[i] = 0;
    }
    __syncthreads();
    for (int e = lo + threadIdx.x; e < hi; e += blockDim.x) {
        int hd = head[e];
        int b = hd >> CB_SHIFT;
        unsigned int r = atomicAdd(&h[b], 1u);
        unsigned int local = (unsigned int)hd & (CB_SIZE - 1);
        binned[bb[b] + r] = (local << 18) | (unsigned int)tail[e];   // tail < 2^18
    }
}

__device__ __forceinline__ void binscat_user_f(const int* __restrict__ iu,
                                               const int* __restrict__ ii,
                                               const float* __restrict__ iv,
                                               unsigned int* __restrict__ cursor,
                                               unsigned int* __restrict__ binned,
                                               float* __restrict__ binnedv,
                                               unsigned int* h, unsigned int* bb, int bid) {
    int lo = bid * A_CHUNK;
    int hi = min(lo + A_CHUNK, NNZ);
    for (int i = threadIdx.x; i < NB_U; i += blockDim.x) h[i] = 0;
    __syncthreads();
    for (int e = lo + threadIdx.x; e < hi; e += blockDim.x)
        atomicAdd(&h[iu[e] >> CB_SHIFT], 1u);
    __syncthreads();
    for (int i = threadIdx.x; i < NB_U; i += blockDim.x) {
        unsigned int c = h[i];
        bb[i] = c ? atomicAdd(&cursor[i], c) : 0u;
        h[i] = 0;
    }
    __syncthreads();
    for (int e = lo + threadIdx.x; e < hi; e += blockDim.x) {
        int u = iu[e];
        int b = u >> CB_SHIFT;
        unsigned int r = atomicAdd(&h[b], 1u);
        unsigned int slot = bb[b] + r;
        unsigned int local = (unsigned int)u & (CB_SIZE - 1);
        binned[slot] = (local << 16) | (unsigned int)ii[e];          // item < 2^16
        binnedv[slot] = iv[e];
    }
}

// p3e: entity bin scatter only
__global__ void build_p3e(const int* __restrict__ head, const int* __restrict__ tail,
                          unsigned int* __restrict__ curE, unsigned int* __restrict__ binnedE) {
    __shared__ unsigned int h[NB_E];
    __shared__ unsigned int bb[NB_E];
    binscat_ent_f(head, tail, curE, binnedE, h, bb, blockIdx.x);
}

__device__ __forceinline__ void build_ent_f(const unsigned int* __restrict__ base,
                                            const unsigned int* __restrict__ binned,
                                            int* __restrict__ col,
                                            unsigned int* __restrict__ row_start,
                                            unsigned int* h, unsigned int* ex,
                                            unsigned int* pairs, int b) {
    unsigned int s0 = base[b], s1 = base[b + 1];
    int t = threadIdx.x;
    h[2 * t] = 0; h[2 * t + 1] = 0;
    __syncthreads();
    for (unsigned int j = s0 + t; j < s1; j += 256)
        atomicAdd(&h[binned[j] >> 18], 1u);
    __syncthreads();
    unsigned int a0 = h[2 * t], a1 = h[2 * t + 1];
    pairs[t] = a0 + a1;
    __syncthreads();
    for (int off = 1; off < 256; off <<= 1) {
        unsigned int u = 0;
        if (t >= off) u = pairs[t - off];
        __syncthreads();
        if (t >= off) pairs[t] += u;
        __syncthreads();
    }
    unsigned int pe = pairs[t] - (a0 + a1);
    ex[2 * t] = pe;
    ex[2 * t + 1] = pe + a0;
    __syncthreads();
    int keybase = b << CB_SHIFT;
    #pragma unroll
    for (int k = 0; k < 2; ++k) {
        int i = 2 * t + k;
        int key = keybase + i;
        if (key < N_ENT) row_start[key] = s0 + ex[i];
    }
    if (b == 0 && t == 0) row_start[N_ENT] = base[NB_E];
    __syncthreads();
    h[2 * t] = 0; h[2 * t + 1] = 0;
    __syncthreads();
    for (unsigned int j = s0 + t; j < s1; j += 256) {
        unsigned int p = binned[j];
        unsigned int local = p >> 18;
        unsigned int r = atomicAdd(&h[local], 1u);
        col[s0 + ex[local] + r] = (int)(p & 0x3FFFFu);
    }
}

__device__ __forceinline__ void build_user_f(const unsigned int* __restrict__ base,
                                             const unsigned int* __restrict__ binned,
                                             const float* __restrict__ binnedv,
                                             int2* __restrict__ upair,
                                             unsigned int* __restrict__ u_row_start,
                                             unsigned int* h, unsigned int* ex,
                                             unsigned int* pairs, int b) {
    unsigned int s0 = base[b], s1 = base[b + 1];
    int t = threadIdx.x;
    h[2 * t] = 0; h[2 * t + 1] = 0;
    __syncthreads();
    for (unsigned int j = s0 + t; j < s1; j += 256)
        atomicAdd(&h[binned[j] >> 16], 1u);
    __syncthreads();
    unsigned int a0 = h[2 * t], a1 = h[2 * t + 1];
    pairs[t] = a0 + a1;
    __syncthreads();
    for (int off = 1; off < 256; off <<= 1) {
        unsigned int u = 0;
        if (t >= off) u = pairs[t - off];
        __syncthreads();
        if (t >= off) pairs[t] += u;
        __syncthreads();
    }
    unsigned int pe = pairs[t] - (a0 + a1);
    ex[2 * t] = pe;
    ex[2 * t + 1] = pe + a0;
    __syncthreads();
    int keybase = b << CB_SHIFT;
    #pragma unroll
    for (int k = 0; k < 2; ++k) {
        int i = 2 * t + k;
        int key = keybase + i;
        if (key < N_USERS) u_row_start[key] = s0 + ex[i];
    }
    if (b == 0 && t == 0) u_row_start[N_USERS] = base[NB_U];
    __syncthreads();
    h[2 * t] = 0; h[2 * t + 1] = 0;
    __syncthreads();
    for (unsigned int j = s0 + t; j < s1; j += 256) {
        unsigned int p = binned[j];
        float v = binnedv[j];
        unsigned int local = p >> 16;
        unsigned int r = atomicAdd(&h[local], 1u);
        upair[s0 + ex[local] + r] = make_int2((int)(p & 0xFFFFu), __float_as_int(v));
    }
}

// p3u+p4e: user bin scatter co-scheduled with entity counting sort
__global__ void build_p3u_p4e(const int* __restrict__ iu, const int* __restrict__ ii,
                              const float* __restrict__ iv, unsigned int* __restrict__ curU,
                              unsigned int* __restrict__ binnedU, float* __restrict__ binnedUV,
                              const unsigned int* __restrict__ baseE,
                              const unsigned int* __restrict__ binnedE,
                              int* __restrict__ col, unsigned int* __restrict__ row_start) {
    __shared__ unsigned int h[CB_SIZE];
    __shared__ unsigned int ex[CB_SIZE];
    __shared__ unsigned int pairs[256];
    if (blockIdx.x < NBLK_BS_U)
        binscat_user_f(iu, ii, iv, curU, binnedU, binnedUV, h, ex /*as bb*/, blockIdx.x);
    else
        build_ent_f(baseE, binnedE, col, row_start, h, ex, pairs, blockIdx.x - NBLK_BS_U);
}

// =================== hop kernels, device bodies ===================

// CSR gather: 8-lane groups, 16B/lane (uint4 = 8 channels). 8 rows/wave in
// flight (2-deep MLP). mode 0: ent_out = fp16(l2norm(mean)), items = fp16(mean).
// mode 1: items = fp16(mean), out_ent = emb + fp16(v1) + v2.
__device__ __forceinline__ void gather_fin_row(int row, int lane,
        const uint4* __restrict__ entb, const unsigned int* __restrict__ row_start,
        const int* __restrict__ col,
        uint4* __restrict__ ent_out, uint4* __restrict__ items_out,
        const float* __restrict__ base_ent, const uint4* __restrict__ v1tab,
        float* __restrict__ out_ent, int mode) {
    int grp = lane >> 3;            // 8 groups of 8 lanes
    int t   = lane & 7;             // lane t: channels [8t, 8t+8)
    unsigned int s0 = row_start[row];
    unsigned int s1 = row_start[row + 1];

    h2v a0 = h2z(), a1 = h2z(), a2 = h2z(), a3 = h2z();
    unsigned int j = s0 + grp;
    for (; j + 8 < s1; j += 16) {            // 2 concurrent row loads per group
        uint4 x0 = entb[(size_t)col[j]     * 8 + t];
        uint4 x1 = entb[(size_t)col[j + 8] * 8 + t];
        a0 += u2h(x0.x) + u2h(x1.x);
        a1 += u2h(x0.y) + u2h(x1.y);
        a2 += u2h(x0.z) + u2h(x1.z);
        a3 += u2h(x0.w) + u2h(x1.w);
    }
    if (j < s1) {
        uint4 x = entb[(size_t)col[j] * 8 + t];
        a0 += u2h(x.x); a1 += u2h(x.y); a2 += u2h(x.z); a3 += u2h(x.w);
    }
    // cross-group sum: xor8 (DPP row_ror:8) + xor16/32 (shfl)
    a0 = grpadd8(a0); a1 = grpadd8(a1); a2 = grpadd8(a2); a3 = grpadd8(a3);
    #pragma unroll
    for (int m = 16; m <= 32; m <<= 1) {
        a0 += u2h(__shfl_xor(h2u(a0), m, 64));
        a1 += u2h(__shfl_xor(h2u(a1), m, 64));
        a2 += u2h(__shfl_xor(h2u(a2), m, 64));
        a3 += u2h(__shfl_xor(h2u(a3), m, 64));
    }
    float inv = 1.0f / fmaxf((float)(s1 - s0), 1.0f);
    float m0 = (float)a0[0] * inv, m1 = (float)a0[1] * inv;
    float m2 = (float)a1[0] * inv, m3 = (float)a1[1] * inv;
    float m4 = (float)a2[0] * inv, m5 = (float)a2[1] * inv;
    float m6 = (float)a3[0] * inv, m7 = (float)a3[1] * inv;

    float sq = m0*m0 + m1*m1 + m2*m2 + m3*m3 + m4*m4 + m5*m5 + m6*m6 + m7*m7;
    sq = red8(sq);                            // 64-ch norm within the 8-lane group
    float invn = 1.0f / fmaxf(sqrtf(sq), 1e-12f);

    if (grp == 0) {
        size_t o = (size_t)row * 8 + t;
        if (row < N_ITEMS)
            items_out[o] = make_uint4(h2u(pk(m0, m1)), h2u(pk(m2, m3)),
                                      h2u(pk(m4, m5)), h2u(pk(m6, m7)));
        if (mode == 0) {
            ent_out[o] = make_uint4(h2u(pk(m0*invn, m1*invn)), h2u(pk(m2*invn, m3*invn)),
                                    h2u(pk(m4*invn, m5*invn)), h2u(pk(m6*invn, m7*invn)));
        } else {
            size_t fo = (size_t)row * 16 + 2 * t;          // float4 index
            float4 c0 = ((const float4*)base_ent)[fo];
            float4 c1 = ((const float4*)base_ent)[fo + 1];
            uint4 v1 = v1tab[o];
            h2v p0 = u2h(v1.x), p1 = u2h(v1.y), p2 = u2h(v1.z), p3 = u2h(v1.w);
            ((float4*)out_ent)[fo]     = make_float4(c0.x + (float)p0[0] + m0*invn,
                                                     c0.y + (float)p0[1] + m1*invn,
                                                     c0.z + (float)p1[0] + m2*invn,
                                                     c0.w + (float)p1[1] + m3*invn);
            ((float4*)out_ent)[fo + 1] = make_float4(c1.x + (float)p2[0] + m4*invn,
                                                     c1.y + (float)p2[1] + m5*invn,
                                                     c1.z + (float)p3[0] + m6*invn,
                                                     c1.w + (float)p3[1] + m7*invn);
        }
    }
}

// register-resident user fast path: rows in r[NS] uint4 VGPRs, 8-lane groups.
template<int NS>
__device__ __forceinline__ void user_fast_path(
        unsigned int s0, unsigned int deg, int grp, int t,
        const uint4* __restrict__ itemsb, const int2* __restrict__ up,
        float& l, h2v& ac0, h2v& ac1, h2v& ac2, h2v& ac3) {
    const float SC = 5.0f * 1.44269504f;   // (1/TEMPERATURE) * log2(e)
    uint4 r[NS];
    float vw[NS];
    #pragma unroll
    for (int k = 0; k < NS; ++k) {
        unsigned int slot = (unsigned int)grp + 8u * k;
        if (slot < deg) {
            int2 p = up[s0 + slot];
            r[k] = itemsb[(size_t)p.x * 8 + t];
            vw[k] = __int_as_float(p.y);
        } else {
            r[k] = make_uint4(0u, 0u, 0u, 0u);
            vw[k] = 0.0f;
        }
    }
    // weighted mean (invalid slots contribute 0)
    h2v um0 = h2z(), um1 = h2z(), um2 = h2z(), um3 = h2z();
    #pragma unroll
    for (int k = 0; k < NS; ++k) {
        h2v v2 = pk(vw[k], vw[k]);
        um0 += v2 * u2h(r[k].x); um1 += v2 * u2h(r[k].y);
        um2 += v2 * u2h(r[k].z); um3 += v2 * u2h(r[k].w);
    }
    um0 = grpadd8(um0); um1 = grpadd8(um1); um2 = grpadd8(um2); um3 = grpadd8(um3);
    #pragma unroll
    for (int m = 16; m <= 32; m <<= 1) {
        um0 += u2h(__shfl_xor(h2u(um0), m, 64));
        um1 += u2h(__shfl_xor(h2u(um1), m, 64));
        um2 += u2h(__shfl_xor(h2u(um2), m, 64));
        um3 += u2h(__shfl_xor(h2u(um3), m, 64));
    }
    // scores (branchless: invalid -> -1e30 -> exp2 -> 0)
    float scv[NS];
    float mloc = -1e30f;
    #pragma unroll
    for (int k = 0; k < NS; ++k) {
        unsigned int slot = (unsigned int)grp + 8u * k;
        h2v d0 = u2h(r[k].x) - um0, d1 = u2h(r[k].y) - um1;
        h2v d2 = u2h(r[k].z) - um2, d3 = u2h(r[k].w) - um3;
        float sq = fdot2f(d3, d3, fdot2f(d2, d2, fdot2f(d1, d1, fdot2f(d0, d0, 0.0f))));
        sq = red8(sq);
        float sc = sqrtf(sq) * SC;
        scv[k] = (slot < deg) ? sc : -1e30f;
        mloc = fmaxf(mloc, scv[k]);
    }
    mloc = fmaxf(mloc, dpp_mov<0x128>(mloc));          // xor8
    float M = fmaxf(mloc, __shfl_xor(mloc, 16, 64));
    M = fmaxf(M, __shfl_xor(M, 32, 64));
    #pragma unroll
    for (int k = 0; k < NS; ++k) {
        float e = exp2f(scv[k] - M);
        l += e;
        h2v e2 = pk(e, e);
        ac0 += e2 * u2h(r[k].x); ac1 += e2 * u2h(r[k].y);
        ac2 += e2 * u2h(r[k].z); ac3 += e2 * u2h(r[k].w);
    }
}

// fused user pipeline: one wave per user, 8x8-lane groups.
// deg<=16: 2-slot reg path; deg<=32: 4-slot reg path; else LDS online fallback.
__device__ __forceinline__ void fused_user_row(int row, int lane, uint4 (*cw)[8],
        const uint4* __restrict__ itemsb, const unsigned int* __restrict__ u_row_start,
        const int2* __restrict__ up, const float* __restrict__ base_user,
        float* __restrict__ out_user) {
    int grp = lane >> 3;
    int t   = lane & 7;
    unsigned int s0 = u_row_start[row];
    unsigned int s1 = u_row_start[row + 1];
    unsigned int deg = s1 - s0;

    const float SC = 5.0f * 1.44269504f;
    float l = 0.0f;
    h2v ac0 = h2z(), ac1 = h2z(), ac2 = h2z(), ac3 = h2z();

    if (__builtin_expect(deg <= 16, 1)) {
        user_fast_path<2>(s0, deg, grp, t, itemsb, up, l, ac0, ac1, ac2, ac3);
    } else if (deg <= UCACHE) {
        user_fast_path<4>(s0, deg, grp, t, itemsb, up, l, ac0, ac1, ac2, ac3);
    } else {
        // ---- fallback (deg > 32, ~never): LDS cache + online softmax ----
        h2v um0 = h2z(), um1 = h2z(), um2 = h2z(), um3 = h2z();
        for (unsigned int j = s0 + grp; j < s1; j += 8) {
            int2 p = up[j];
            uint4 r = itemsb[(size_t)p.x * 8 + t];
            int slot = (int)(j - s0);
            if (slot < UCACHE) cw[slot][t] = r;
            float v = __int_as_float(p.y);
            h2v v2 = pk(v, v);
            um0 += v2 * u2h(r.x); um1 += v2 * u2h(r.y);
            um2 += v2 * u2h(r.z); um3 += v2 * u2h(r.w);
        }
        um0 = grpadd8(um0); um1 = grpadd8(um1); um2 = grpadd8(um2); um3 = grpadd8(um3);
        #pragma unroll
        for (int m = 16; m <= 32; m <<= 1) {
            um0 += u2h(__shfl_xor(h2u(um0), m, 64));
            um1 += u2h(__shfl_xor(h2u(um1), m, 64));
            um2 += u2h(__shfl_xor(h2u(um2), m, 64));
            um3 += u2h(__shfl_xor(h2u(um3), m, 64));
        }
        float m_run = -1e30f;
        for (unsigned int j = s0 + grp; j < s1; j += 8) {
            int slot = (int)(j - s0);
            uint4 r = (slot < UCACHE) ? cw[slot][t]
                                      : itemsb[(size_t)up[j].x * 8 + t];
            h2v d0 = u2h(r.x) - um0, d1 = u2h(r.y) - um1;
            h2v d2 = u2h(r.z) - um2, d3 = u2h(r.w) - um3;
            float sq = fdot2f(d3, d3, fdot2f(d2, d2, fdot2f(d1, d1, fdot2f(d0, d0, 0.0f))));
            sq = red8(sq);                       // uniform within 8-lane group
            float sc = sqrtf(sq) * SC;
            if (sc > m_run) {                    // group-uniform branch
                float s = exp2f(m_run - sc);
                l *= s;
                h2v s2 = pk(s, s);
                ac0 *= s2; ac1 *= s2; ac2 *= s2; ac3 *= s2;
                m_run = sc;
            }
            float e = exp2f(sc - m_run);
            l += e;
            h2v e2 = pk(e, e);
            ac0 += e2 * u2h(r.x); ac1 += e2 * u2h(r.y);
            ac2 += e2 * u2h(r.z); ac3 += e2 * u2h(r.w);
        }
        float mx = fmaxf(m_run, dpp_mov<0x128>(m_run));
        float M = fmaxf(mx, __shfl_xor(mx, 16, 64));
        M = fmaxf(M, __shfl_xor(M, 32, 64));
        float wgt = (l > 0.0f) ? exp2f(m_run - M) : 0.0f;
        l *= wgt;
        h2v w2 = pk(wgt, wgt);
        ac0 *= w2; ac1 *= w2; ac2 *= w2; ac3 *= w2;
    }

    // cross-group merge (fast paths share a common M; fallback pre-scaled)
    l = l + dpp_mov<0x128>(l);
    ac0 = grpadd8(ac0); ac1 = grpadd8(ac1); ac2 = grpadd8(ac2); ac3 = grpadd8(ac3);
    #pragma unroll
    for (int m = 16; m <= 32; m <<= 1) {
        l   += __shfl_xor(l, m, 64);
        ac0 += u2h(__shfl_xor(h2u(ac0), m, 64));
        ac1 += u2h(__shfl_xor(h2u(ac1), m, 64));
        ac2 += u2h(__shfl_xor(h2u(ac2), m, 64));
        ac3 += u2h(__shfl_xor(h2u(ac3), m, 64));
    }
    float invl = (l > 0.0f) ? (1.0f / l) : 0.0f;
    float u0 = (float)ac0[0] * invl, u1 = (float)ac0[1] * invl;
    float u2 = (float)ac1[0] * invl, u3 = (float)ac1[1] * invl;
    float u4 = (float)ac2[0] * invl, u5 = (float)ac2[1] * invl;
    float u6 = (float)ac3[0] * invl, u7 = (float)ac3[1] * invl;

    float sq2 = u0*u0 + u1*u1 + u2*u2 + u3*u3 + u4*u4 + u5*u5 + u6*u6 + u7*u7;
    sq2 = red8(sq2);
    float inv = 1.0f / fmaxf(sqrtf(sq2), 1e-12f);
    if (grp == 0) {
        size_t fo = (size_t)row * 16 + 2 * t;
        float4 c0 = ((const float4*)base_user)[fo];
        float4 c1 = ((const float4*)base_user)[fo + 1];
        ((float4*)out_user)[fo]     = make_float4(c0.x + u0*inv, c0.y + u1*inv,
                                                  c0.z + u2*inv, c0.w + u3*inv);
        ((float4*)out_user)[fo + 1] = make_float4(c1.x + u4*inv, c1.y + u5*inv,
                                                  c1.z + u6*inv, c1.w + u7*inv);
    }
}

// =================== hop kernel wrappers ===================

// hop-1 gather+finalize (no out_ent RMW) co-scheduled with the user-side sort
__global__ void gf1_p4u_k(const uint4* __restrict__ E0,
                          const unsigned int* __restrict__ row_start,
                          const int* __restrict__ col,
                          uint4* __restrict__ E1, uint4* __restrict__ itemsA,
                          const unsigned int* __restrict__ baseU,
                          const unsigned int* __restrict__ binnedU,
                          const float* __restrict__ binnedUV,
                          int2* __restrict__ upair, unsigned int* __restrict__ u_row_start) {
    __shared__ unsigned int h[CB_SIZE];
    __shared__ unsigned int ex[CB_SIZE];
    __shared__ unsigned int pairs[256];
    int bid = blockIdx.x;
    if (bid < NB_U) {
        build_user_f(baseU, binnedU, binnedUV, upair, u_row_start, h, ex, pairs, bid);
    } else {
        int row  = (bid - NB_U) * 4 + (threadIdx.x >> 6);
        gather_fin_row(row, threadIdx.x & 63, E0, row_start, col, E1, itemsA,
                       nullptr, nullptr, nullptr, 0);
    }
}

// combined: hop-2 gather+finalize (out_ent = emb + v1 + v2) co-scheduled with
// hop-1 fused_user (3:2 interleave)
__global__ void g2_u1_k(const uint4* __restrict__ entb,           // E1
                        const unsigned int* __restrict__ row_start,
                        const int* __restrict__ col,
                        uint4* __restrict__ items_out,            // itemsB
                        const float* __restrict__ entity_emb,
                        float* __restrict__ out_ent,
                        const uint4* __restrict__ itemsb1,        // itemsA
                        const unsigned int* __restrict__ u_row_start,
                        const int2* __restrict__ up,
                        const float* __restrict__ base_user,      // user_emb
                        float* __restrict__ out_user) {
    __shared__ uint4 cache[4][UCACHE][8];   // 16 KB (fallback only)
    int bid = blockIdx.x;
    int g5 = bid / 5, r5 = bid - g5 * 5;     // 62500 = 12500 * 5 exactly
    int w    = threadIdx.x >> 6;
    int lane = threadIdx.x & 63;
    if (r5 < 3) {
        int row = (g5 * 3 + r5) * 4 + w;     // < 37500*4 = N_ENT exactly
        gather_fin_row(row, lane, entb, row_start, col, nullptr, items_out,
                       entity_emb, entb, out_ent, 1);
    } else {
        int row = (g5 * 2 + (r5 - 3)) * 4 + w;   // < 25000*4 = N_USERS exactly
        fused_user_row(row, lane, cache[w], itemsb1, u_row_start, up,
                       base_user, out_user);
    }
}

// hop-2 user pipeline
__global__ void fused_user_k(const uint4* __restrict__ itemsb,
                             const unsigned int* __restrict__ u_row_start,
                             const int2* __restrict__ up,
                             const float* __restrict__ base_user,
                             float* __restrict__ out_user) {
    __shared__ uint4 cache[4][UCACHE][8];
    int wave = (blockIdx.x * blockDim.x + threadIdx.x) >> 6;
    int w    = threadIdx.x >> 6;
    int lane = threadIdx.x & 63;
    if (wave >= N_USERS) return;
    fused_user_row(wave, lane, cache[w], itemsb, u_row_start, up, base_user, out_user);
}

extern "C" void kernel_launch(void* const* d_in, const int* in_sizes, int n_in,
                              void* d_out, int out_size, void* d_ws, size_t ws_size,
                              hipStream_t stream) {
    const float* user_emb   = (const float*)d_in[0];
    const float* entity_emb = (const float*)d_in[1];
    const int*   edge_index = (const int*)d_in[3];
    const int*   iu = (const int*)d_in[5];
    const int*   ii = (const int*)d_in[6];
    const float* iv = (const float*)d_in[7];

    float* out_user = (float*)d_out;
    float* out_ent  = out_user + (size_t)N_USERS * CH;

    // ---- workspace layout (~68.3 MB), same bytes as before, uint4 view ----
    uint4* E0     = (uint4*)d_ws;                        // N_ENT*8   (19.2 MB)
    uint4* E1     = E0 + (size_t)N_ENT * 8;              // N_ENT*8   (19.2 MB)
    uint4* itemsA = E1 + (size_t)N_ENT * 8;              // N_ITEMS*8 (6.4 MB)
    uint4* itemsB = itemsA + (size_t)N_ITEMS * 8;        // N_ITEMS*8 (6.4 MB)
    int2*  upair  = (int2*)(itemsB + (size_t)N_ITEMS * 8);       // NNZ (8 MB)
    int*   col    = (int*)(upair + NNZ);                 // N_EDGES (8 MB)
    unsigned int* row_start   = (unsigned int*)(col + N_EDGES);  // N_ENT+1
    unsigned int* u_row_start = row_start + N_ENT + 1;           // N_USERS+1
    unsigned int* cntE  = u_row_start + N_USERS + 1;             // NB_E
    unsigned int* cntU  = cntE + NB_E;                           // NB_U
    unsigned int* baseE = cntU + NB_U;                           // NB_E+1
    unsigned int* curE  = baseE + NB_E + 1;                      // NB_E
    unsigned int* baseU = curE + NB_E;                           // NB_U+1
    unsigned int* curU  = baseU + NB_U + 1;                      // NB_U

    // build-time scratch:
    //  - binnedE aliased over E1: consumed by build_p3u_p4e, before gf1 writes E1.
    //  - binnedU/UV aliased over out_user: consumed by gf1's sort-U blocks;
    //    out_user first really written by g2_u1_k.
    unsigned int* binnedE  = (unsigned int*)E1;                  // N_EDGES
    unsigned int* binnedU  = (unsigned int*)out_user;            // NNZ
    float*        binnedUV = (float*)(binnedU + NNZ);            // NNZ

    const int* head = edge_index;
    const int* tail = edge_index + N_EDGES;

    // ---- CSR builds (structure constant across hops) ----
    (void)hipMemsetAsync(cntE, 0, (size_t)(NB_E + NB_U) * 4, stream);
    build_p1<<<2 * NBLK_CNT + NBLK_CONV, 256, 0, stream>>>(head, iu, entity_emb,
                                                           (uint2*)E0, cntE, cntU);
    build_p2<<<2, 512, 0, stream>>>(cntE, baseE, curE, cntU, baseU, curU);
    build_p3e<<<NBLK_BS_E, 256, 0, stream>>>(head, tail, curE, binnedE);
    build_p3u_p4e<<<NBLK_BS_U + NB_E, 256, 0, stream>>>(iu, ii, iv, curU, binnedU, binnedUV,
                                                        baseE, binnedE, col, row_start);

    // ---- hop-1 gather+finalize (E0 -> E1, itemsA) + user-side sort ----
    gf1_p4u_k<<<NB_U + GB_GATHER, 256, 0, stream>>>(E0, row_start, col, E1, itemsA,
                                                    baseU, binnedU, binnedUV,
                                                    upair, u_row_start);

    // ---- hop-2 gather+finalize (out_ent = emb + v1 + v2) + hop-1 user ----
    g2_u1_k<<<GB_GATHER + GB_USER, 256, 0, stream>>>(E1, row_start, col, itemsB,
                                                     entity_emb, out_ent,
                                                     itemsA, u_row_start, upair,
                                                     user_emb, out_user);

    // ---- hop 2 user pipeline: out_user += u2 ----
    fused_user_k<<<GB_USER, 256, 0, stream>>>(itemsB, u_row_start, upair,
                                              out_user, out_user);
}

// Round 8
// 434.816 us; speedup vs baseline: 1.3798x; 1.0662x over previous
//
#include <hip/hip_runtime.h>

#define N_USERS   100000
#define N_ITEMS   50000
#define N_ENT     150000
#define N_EDGES   2000000
#define NNZ       1000000
#define CH        64

#define CB_SHIFT  9
#define CB_SIZE   512
#define NB_E      ((N_ENT   + CB_SIZE - 1) >> CB_SHIFT)   // 293
#define NB_U      ((N_USERS + CB_SIZE - 1) >> CB_SHIFT)   // 196
#define A_CHUNK   4096
#define UCACHE    32   // register/LDS fast-path bound; fallback handles deg > UCACHE

#define NBLK_CNT   512
#define NBLK_CONV  ((N_ENT * 16 + 255) / 256)             // 9375
#define NBLK_BS_E  ((N_EDGES + A_CHUNK - 1) / A_CHUNK)    // 489
#define NBLK_BS_U  ((NNZ + A_CHUNK - 1) / A_CHUNK)        // 245
#define GB_G8      ((N_ENT + 31) / 32)                    // 4688 gather blocks (32 rows/block)
#define GB_USER    (N_USERS / 4)                          // 25000 blocks (1 wave = 1 user)
#define G2U1_NG    1563                                   // ceil(4688/3) == ceil(25000/16)

// ---- packed fp16 helpers: tables are fp16; rows are 8 lanes x uint4 (16B) ----
typedef __fp16 h2v __attribute__((ext_vector_type(2)));

__device__ __forceinline__ h2v h2z() { h2v z = {(__fp16)0.f, (__fp16)0.f}; return z; }
__device__ __forceinline__ h2v pk(float a, float b) { return __builtin_amdgcn_cvt_pkrtz(a, b); }
__device__ __forceinline__ unsigned int h2u(h2v h) { return __builtin_bit_cast(unsigned int, h); }
__device__ __forceinline__ h2v u2h(unsigned int u) { return __builtin_bit_cast(h2v, u); }
__device__ __forceinline__ float fdot2f(h2v a, h2v b, float c) {
    return __builtin_amdgcn_fdot2(a, b, c, false);   // f32 accumulate of packed f16 dot
}

// ---- DPP helpers (VALU-only cross-lane; DPP row = 16 lanes) ----
template<int CTRL>
__device__ __forceinline__ float dpp_mov(float x) {
    return __builtin_bit_cast(float, __builtin_amdgcn_update_dpp(
        0, __builtin_bit_cast(int, x), CTRL, 0xF, 0xF, true));
}
template<int CTRL>
__device__ __forceinline__ unsigned dpp_mov_u(unsigned x) {
    return (unsigned)__builtin_amdgcn_update_dpp(0, (int)x, CTRL, 0xF, 0xF, true);
}
// 8-lane all-reduce sum (within each 8-lane group): quads then cross-quad mirror
__device__ __forceinline__ float red8(float x) {
    x += dpp_mov<0xB1>(x);    // quad_perm [1,0,3,2]  (xor 1)
    x += dpp_mov<0x4E>(x);    // quad_perm [2,3,0,1]  (xor 2)
    x += dpp_mov<0x141>(x);   // row_half_mirror: i<->7-i within 8 (cross-quad)
    return x;
}
// lane^8 partner add for packed fp16 (row_ror:8 == xor8 within the 16-lane row)
__device__ __forceinline__ h2v grpadd8(h2v a) {
    return a + u2h(dpp_mov_u<0x128>(h2u(a)));
}

// =================== build phase, device bodies ===================

__device__ __forceinline__ void coarse_count_f(const int* __restrict__ key, int n,
                                               unsigned int* __restrict__ gcnt, int nb,
                                               unsigned int* h, int bid, int nblk) {
    for (int i = threadIdx.x; i < nb; i += blockDim.x) h[i] = 0;
    __syncthreads();
    for (int e = bid * blockDim.x + threadIdx.x; e < n; e += nblk * blockDim.x)
        atomicAdd(&h[key[e] >> CB_SHIFT], 1u);
    __syncthreads();
    for (int i = threadIdx.x; i < nb; i += blockDim.x)
        if (h[i]) atomicAdd(&gcnt[i], h[i]);
}

// p1: coarse counts (E and U) + fp32->fp16 convert of entity_emb, one dispatch
__global__ void build_p1(const int* __restrict__ head, const int* __restrict__ iu,
                         const float* __restrict__ entity_emb, uint2* __restrict__ E0,
                         unsigned int* __restrict__ cntE, unsigned int* __restrict__ cntU) {
    __shared__ unsigned int h[CB_SIZE];
    int bid = blockIdx.x;
    if (bid < NBLK_CNT) {
        coarse_count_f(head, N_EDGES, cntE, NB_E, h, bid, NBLK_CNT);
    } else if (bid < 2 * NBLK_CNT) {
        coarse_count_f(iu, NNZ, cntU, NB_U, h, bid - NBLK_CNT, NBLK_CNT);
    } else {
        int i = (bid - 2 * NBLK_CNT) * 256 + threadIdx.x;
        if (i < N_ENT * 16) {
            float4 a = ((const float4*)entity_emb)[i];
            E0[i] = make_uint2(h2u(pk(a.x, a.y)), h2u(pk(a.z, a.w)));
        }
    }
}

__device__ __forceinline__ void coarse_scan_f(const unsigned int* __restrict__ gcnt,
                                              unsigned int* __restrict__ base,
                                              unsigned int* __restrict__ cursor, int nb,
                                              unsigned int* s) {
    int t = threadIdx.x;
    unsigned int v = (t < nb) ? gcnt[t] : 0u;
    s[t] = v;
    __syncthreads();
    for (int off = 1; off < 512; off <<= 1) {
        unsigned int u = 0;
        if (t >= off) u = s[t - off];
        __syncthreads();
        if (t >= off) s[t] += u;
        __syncthreads();
    }
    if (t < nb) { base[t] = s[t] - v; cursor[t] = s[t] - v; }
    if (t == nb) base[t] = s[nb - 1];   // total
}

// p2: both exclusive scans in one dispatch (2 blocks)
__global__ void build_p2(const unsigned int* __restrict__ cntE, unsigned int* __restrict__ baseE,
                         unsigned int* __restrict__ curE,
                         const unsigned int* __restrict__ cntU, unsigned int* __restrict__ baseU,
                         unsigned int* __restrict__ curU) {
    __shared__ unsigned int s[512];
    if (blockIdx.x == 0) coarse_scan_f(cntE, baseE, curE, NB_E, s);
    else                 coarse_scan_f(cntU, baseU, curU, NB_U, s);
}

__device__ __forceinline__ void binscat_ent_f(const int* __restrict__ head,
                                              const int* __restrict__ tail,
                                              unsigned int* __restrict__ cursor,
                                              unsigned int* __restrict__ binned,
                                              unsigned int* h, unsigned int* bb, int bid) {
    int lo = bid * A_CHUNK;
    int hi = min(lo + A_CHUNK, N_EDGES);
    for (int i = threadIdx.x; i < NB_E; i += blockDim.x) h[i] = 0;
    __syncthreads();
    for (int e = lo + threadIdx.x; e < hi; e += blockDim.x)
        atomicAdd(&h[head[e] >> CB_SHIFT], 1u);
    __syncthreads();
    for (int i = threadIdx.x; i < NB_E; i += blockDim.x) {
        unsigned int c = h[i];
        bb[i] = c ? atomicAdd(&cursor[i], c) : 0u;
        h[i] = 0;
    }
    __syncthreads();
    for (int e = lo + threadIdx.x; e < hi; e += blockDim.x) {
        int hd = head[e];
        int b = hd >> CB_SHIFT;
        unsigned int r = atomicAdd(&h[b], 1u);
        unsigned int local = (unsigned int)hd & (CB_SIZE - 1);
        binned[bb[b] + r] = (local << 18) | (unsigned int)tail[e];   // tail < 2^18
    }
}

__device__ __forceinline__ void binscat_user_f(const int* __restrict__ iu,
                                               const int* __restrict__ ii,
                                               const float* __restrict__ iv,
                                               unsigned int* __restrict__ cursor,
                                               unsigned int* __restrict__ binned,
                                               float* __restrict__ binnedv,
                                               unsigned int* h, unsigned int* bb, int bid) {
    int lo = bid * A_CHUNK;
    int hi = min(lo + A_CHUNK, NNZ);
    for (int i = threadIdx.x; i < NB_U; i += blockDim.x) h[i] = 0;
    __syncthreads();
    for (int e = lo + threadIdx.x; e < hi; e += blockDim.x)
        atomicAdd(&h[iu[e] >> CB_SHIFT], 1u);
    __syncthreads();
    for (int i = threadIdx.x; i < NB_U; i += blockDim.x) {
        unsigned int c = h[i];
        bb[i] = c ? atomicAdd(&cursor[i], c) : 0u;
        h[i] = 0;
    }
    __syncthreads();
    for (int e = lo + threadIdx.x; e < hi; e += blockDim.x) {
        int u = iu[e];
        int b = u >> CB_SHIFT;
        unsigned int r = atomicAdd(&h[b], 1u);
        unsigned int slot = bb[b] + r;
        unsigned int local = (unsigned int)u & (CB_SIZE - 1);
        binned[slot] = (local << 16) | (unsigned int)ii[e];          // item < 2^16
        binnedv[slot] = iv[e];
    }
}

// p3e: entity bin scatter only
__global__ void build_p3e(const int* __restrict__ head, const int* __restrict__ tail,
                          unsigned int* __restrict__ curE, unsigned int* __restrict__ binnedE) {
    __shared__ unsigned int h[NB_E];
    __shared__ unsigned int bb[NB_E];
    binscat_ent_f(head, tail, curE, binnedE, h, bb, blockIdx.x);
}

__device__ __forceinline__ void build_ent_f(const unsigned int* __restrict__ base,
                                            const unsigned int* __restrict__ binned,
                                            int* __restrict__ col,
                                            unsigned int* __restrict__ row_start,
                                            unsigned int* h, unsigned int* ex,
                                            unsigned int* pairs, int b) {
    unsigned int s0 = base[b], s1 = base[b + 1];
    int t = threadIdx.x;
    h[2 * t] = 0; h[2 * t + 1] = 0;
    __syncthreads();
    for (unsigned int j = s0 + t; j < s1; j += 256)
        atomicAdd(&h[binned[j] >> 18], 1u);
    __syncthreads();
    unsigned int a0 = h[2 * t], a1 = h[2 * t + 1];
    pairs[t] = a0 + a1;
    __syncthreads();
    for (int off = 1; off < 256; off <<= 1) {
        unsigned int u = 0;
        if (t >= off) u = pairs[t - off];
        __syncthreads();
        if (t >= off) pairs[t] += u;
        __syncthreads();
    }
    unsigned int pe = pairs[t] - (a0 + a1);
    ex[2 * t] = pe;
    ex[2 * t + 1] = pe + a0;
    __syncthreads();
    int keybase = b << CB_SHIFT;
    #pragma unroll
    for (int k = 0; k < 2; ++k) {
        int i = 2 * t + k;
        int key = keybase + i;
        if (key < N_ENT) row_start[key] = s0 + ex[i];
    }
    if (b == 0 && t == 0) row_start[N_ENT] = base[NB_E];
    __syncthreads();
    h[2 * t] = 0; h[2 * t + 1] = 0;
    __syncthreads();
    for (unsigned int j = s0 + t; j < s1; j += 256) {
        unsigned int p = binned[j];
        unsigned int local = p >> 18;
        unsigned int r = atomicAdd(&h[local], 1u);
        col[s0 + ex[local] + r] = (int)(p & 0x3FFFFu);
    }
}

__device__ __forceinline__ void build_user_f(const unsigned int* __restrict__ base,
                                             const unsigned int* __restrict__ binned,
                                             const float* __restrict__ binnedv,
                                             int2* __restrict__ upair,
                                             unsigned int* __restrict__ u_row_start,
                                             unsigned int* h, unsigned int* ex,
                                             unsigned int* pairs, int b) {
    unsigned int s0 = base[b], s1 = base[b + 1];
    int t = threadIdx.x;
    h[2 * t] = 0; h[2 * t + 1] = 0;
    __syncthreads();
    for (unsigned int j = s0 + t; j < s1; j += 256)
        atomicAdd(&h[binned[j] >> 16], 1u);
    __syncthreads();
    unsigned int a0 = h[2 * t], a1 = h[2 * t + 1];
    pairs[t] = a0 + a1;
    __syncthreads();
    for (int off = 1; off < 256; off <<= 1) {
        unsigned int u = 0;
        if (t >= off) u = pairs[t - off];
        __syncthreads();
        if (t >= off) pairs[t] += u;
        __syncthreads();
    }
    unsigned int pe = pairs[t] - (a0 + a1);
    ex[2 * t] = pe;
    ex[2 * t + 1] = pe + a0;
    __syncthreads();
    int keybase = b << CB_SHIFT;
    #pragma unroll
    for (int k = 0; k < 2; ++k) {
        int i = 2 * t + k;
        int key = keybase + i;
        if (key < N_USERS) u_row_start[key] = s0 + ex[i];
    }
    if (b == 0 && t == 0) u_row_start[N_USERS] = base[NB_U];
    __syncthreads();
    h[2 * t] = 0; h[2 * t + 1] = 0;
    __syncthreads();
    for (unsigned int j = s0 + t; j < s1; j += 256) {
        unsigned int p = binned[j];
        float v = binnedv[j];
        unsigned int local = p >> 16;
        unsigned int r = atomicAdd(&h[local], 1u);
        upair[s0 + ex[local] + r] = make_int2((int)(p & 0xFFFFu), __float_as_int(v));
    }
}

// p3u+p4e: user bin scatter co-scheduled with entity counting sort
__global__ void build_p3u_p4e(const int* __restrict__ iu, const int* __restrict__ ii,
                              const float* __restrict__ iv, unsigned int* __restrict__ curU,
                              unsigned int* __restrict__ binnedU, float* __restrict__ binnedUV,
                              const unsigned int* __restrict__ baseE,
                              const unsigned int* __restrict__ binnedE,
                              int* __restrict__ col, unsigned int* __restrict__ row_start) {
    __shared__ unsigned int h[CB_SIZE];
    __shared__ unsigned int ex[CB_SIZE];
    __shared__ unsigned int pairs[256];
    if (blockIdx.x < NBLK_BS_U)
        binscat_user_f(iu, ii, iv, curU, binnedU, binnedUV, h, ex /*as bb*/, blockIdx.x);
    else
        build_ent_f(baseE, binnedE, col, row_start, h, ex, pairs, blockIdx.x - NBLK_BS_U);
}

// =================== hop kernels, device bodies ===================

// CSR gather, row-per-group: one 8-lane group owns one entity row (8 rows/wave).
// Group-serially accumulates its own neighbors -> NO cross-group reduction;
// epilogues/stores of the 8 rows issue in the same wave instructions.
// mode 0: ent_out = fp16(l2norm(mean)), items = fp16(mean).
// mode 1: items = fp16(mean), out_ent = emb + fp16(v1) + v2.
__device__ __forceinline__ void gather_fin_row8(int row, int t, bool valid,
        const uint4* __restrict__ entb, const unsigned int* __restrict__ row_start,
        const int* __restrict__ col,
        uint4* __restrict__ ent_out, uint4* __restrict__ items_out,
        const float* __restrict__ base_ent, const uint4* __restrict__ v1tab,
        float* __restrict__ out_ent, int mode) {
    unsigned int s0 = 0, s1 = 0;
    if (valid) { s0 = row_start[row]; s1 = row_start[row + 1]; }

    h2v a0 = h2z(), a1 = h2z(), a2 = h2z(), a3 = h2z();
    unsigned int j = s0;
    for (; j + 1 < s1; j += 2) {               // 2 loads in flight per group
        int c0 = col[j], c1 = col[j + 1];      // group-uniform addr (HW broadcast)
        uint4 x0 = entb[(size_t)c0 * 8 + t];
        uint4 x1 = entb[(size_t)c1 * 8 + t];
        a0 += u2h(x0.x) + u2h(x1.x);
        a1 += u2h(x0.y) + u2h(x1.y);
        a2 += u2h(x0.z) + u2h(x1.z);
        a3 += u2h(x0.w) + u2h(x1.w);
    }
    if (j < s1) {
        uint4 x = entb[(size_t)col[j] * 8 + t];
        a0 += u2h(x.x); a1 += u2h(x.y); a2 += u2h(x.z); a3 += u2h(x.w);
    }
    float inv = 1.0f / fmaxf((float)(s1 - s0), 1.0f);
    float m0 = (float)a0[0] * inv, m1 = (float)a0[1] * inv;
    float m2 = (float)a1[0] * inv, m3 = (float)a1[1] * inv;
    float m4 = (float)a2[0] * inv, m5 = (float)a2[1] * inv;
    float m6 = (float)a3[0] * inv, m7 = (float)a3[1] * inv;

    float sq = m0*m0 + m1*m1 + m2*m2 + m3*m3 + m4*m4 + m5*m5 + m6*m6 + m7*m7;
    sq = red8(sq);                              // 64-ch norm within the 8-lane group
    float invn = 1.0f / fmaxf(sqrtf(sq), 1e-12f);

    if (!valid) return;
    size_t o = (size_t)row * 8 + t;
    if (row < N_ITEMS)
        items_out[o] = make_uint4(h2u(pk(m0, m1)), h2u(pk(m2, m3)),
                                  h2u(pk(m4, m5)), h2u(pk(m6, m7)));
    if (mode == 0) {
        ent_out[o] = make_uint4(h2u(pk(m0*invn, m1*invn)), h2u(pk(m2*invn, m3*invn)),
                                h2u(pk(m4*invn, m5*invn)), h2u(pk(m6*invn, m7*invn)));
    } else {
        size_t fo = (size_t)row * 16 + 2 * t;          // float4 index
        float4 c0 = ((const float4*)base_ent)[fo];
        float4 c1 = ((const float4*)base_ent)[fo + 1];
        uint4 v1 = v1tab[o];
        h2v p0 = u2h(v1.x), p1 = u2h(v1.y), p2 = u2h(v1.z), p3 = u2h(v1.w);
        ((float4*)out_ent)[fo]     = make_float4(c0.x + (float)p0[0] + m0*invn,
                                                 c0.y + (float)p0[1] + m1*invn,
                                                 c0.z + (float)p1[0] + m2*invn,
                                                 c0.w + (float)p1[1] + m3*invn);
        ((float4*)out_ent)[fo + 1] = make_float4(c1.x + (float)p2[0] + m4*invn,
                                                 c1.y + (float)p2[1] + m5*invn,
                                                 c1.z + (float)p3[0] + m6*invn,
                                                 c1.w + (float)p3[1] + m7*invn);
    }
}

// register-resident user fast path: rows in r[NS] uint4 VGPRs, 8-lane groups.
template<int NS>
__device__ __forceinline__ void user_fast_path(
        unsigned int s0, unsigned int deg, int grp, int t,
        const uint4* __restrict__ itemsb, const int2* __restrict__ up,
        float& l, h2v& ac0, h2v& ac1, h2v& ac2, h2v& ac3) {
    const float SC = 5.0f * 1.44269504f;   // (1/TEMPERATURE) * log2(e)
    uint4 r[NS];
    float vw[NS];
    #pragma unroll
    for (int k = 0; k < NS; ++k) {
        unsigned int slot = (unsigned int)grp + 8u * k;
        if (slot < deg) {
            int2 p = up[s0 + slot];
            r[k] = itemsb[(size_t)p.x * 8 + t];
            vw[k] = __int_as_float(p.y);
        } else {
            r[k] = make_uint4(0u, 0u, 0u, 0u);
            vw[k] = 0.0f;
        }
    }
    // weighted mean (invalid slots contribute 0)
    h2v um0 = h2z(), um1 = h2z(), um2 = h2z(), um3 = h2z();
    #pragma unroll
    for (int k = 0; k < NS; ++k) {
        h2v v2 = pk(vw[k], vw[k]);
        um0 += v2 * u2h(r[k].x); um1 += v2 * u2h(r[k].y);
        um2 += v2 * u2h(r[k].z); um3 += v2 * u2h(r[k].w);
    }
    um0 = grpadd8(um0); um1 = grpadd8(um1); um2 = grpadd8(um2); um3 = grpadd8(um3);
    #pragma unroll
    for (int m = 16; m <= 32; m <<= 1) {
        um0 += u2h(__shfl_xor(h2u(um0), m, 64));
        um1 += u2h(__shfl_xor(h2u(um1), m, 64));
        um2 += u2h(__shfl_xor(h2u(um2), m, 64));
        um3 += u2h(__shfl_xor(h2u(um3), m, 64));
    }
    // scores (branchless: invalid -> -1e30 -> exp2 -> 0)
    float scv[NS];
    float mloc = -1e30f;
    #pragma unroll
    for (int k = 0; k < NS; ++k) {
        unsigned int slot = (unsigned int)grp + 8u * k;
        h2v d0 = u2h(r[k].x) - um0, d1 = u2h(r[k].y) - um1;
        h2v d2 = u2h(r[k].z) - um2, d3 = u2h(r[k].w) - um3;
        float sq = fdot2f(d3, d3, fdot2f(d2, d2, fdot2f(d1, d1, fdot2f(d0, d0, 0.0f))));
        sq = red8(sq);
        float sc = sqrtf(sq) * SC;
        scv[k] = (slot < deg) ? sc : -1e30f;
        mloc = fmaxf(mloc, scv[k]);
    }
    mloc = fmaxf(mloc, dpp_mov<0x128>(mloc));          // xor8
    float M = fmaxf(mloc, __shfl_xor(mloc, 16, 64));
    M = fmaxf(M, __shfl_xor(M, 32, 64));
    #pragma unroll
    for (int k = 0; k < NS; ++k) {
        float e = exp2f(scv[k] - M);
        l += e;
        h2v e2 = pk(e, e);
        ac0 += e2 * u2h(r[k].x); ac1 += e2 * u2h(r[k].y);
        ac2 += e2 * u2h(r[k].z); ac3 += e2 * u2h(r[k].w);
    }
}

// fused user pipeline: one wave per user, 8x8-lane groups.
// deg<=16: 2-slot reg path; deg<=32: 4-slot reg path; else LDS online fallback.
__device__ __forceinline__ void fused_user_row(int row, int lane, uint4 (*cw)[8],
        const uint4* __restrict__ itemsb, const unsigned int* __restrict__ u_row_start,
        const int2* __restrict__ up, const float* __restrict__ base_user,
        float* __restrict__ out_user) {
    int grp = lane >> 3;
    int t   = lane & 7;
    unsigned int s0 = u_row_start[row];
    unsigned int s1 = u_row_start[row + 1];
    unsigned int deg = s1 - s0;

    const float SC = 5.0f * 1.44269504f;
    float l = 0.0f;
    h2v ac0 = h2z(), ac1 = h2z(), ac2 = h2z(), ac3 = h2z();

    if (__builtin_expect(deg <= 16, 1)) {
        user_fast_path<2>(s0, deg, grp, t, itemsb, up, l, ac0, ac1, ac2, ac3);
    } else if (deg <= UCACHE) {
        user_fast_path<4>(s0, deg, grp, t, itemsb, up, l, ac0, ac1, ac2, ac3);
    } else {
        // ---- fallback (deg > 32, ~never): LDS cache + online softmax ----
        h2v um0 = h2z(), um1 = h2z(), um2 = h2z(), um3 = h2z();
        for (unsigned int j = s0 + grp; j < s1; j += 8) {
            int2 p = up[j];
            uint4 r = itemsb[(size_t)p.x * 8 + t];
            int slot = (int)(j - s0);
            if (slot < UCACHE) cw[slot][t] = r;
            float v = __int_as_float(p.y);
            h2v v2 = pk(v, v);
            um0 += v2 * u2h(r.x); um1 += v2 * u2h(r.y);
            um2 += v2 * u2h(r.z); um3 += v2 * u2h(r.w);
        }
        um0 = grpadd8(um0); um1 = grpadd8(um1); um2 = grpadd8(um2); um3 = grpadd8(um3);
        #pragma unroll
        for (int m = 16; m <= 32; m <<= 1) {
            um0 += u2h(__shfl_xor(h2u(um0), m, 64));
            um1 += u2h(__shfl_xor(h2u(um1), m, 64));
            um2 += u2h(__shfl_xor(h2u(um2), m, 64));
            um3 += u2h(__shfl_xor(h2u(um3), m, 64));
        }
        float m_run = -1e30f;
        for (unsigned int j = s0 + grp; j < s1; j += 8) {
            int slot = (int)(j - s0);
            uint4 r = (slot < UCACHE) ? cw[slot][t]
                                      : itemsb[(size_t)up[j].x * 8 + t];
            h2v d0 = u2h(r.x) - um0, d1 = u2h(r.y) - um1;
            h2v d2 = u2h(r.z) - um2, d3 = u2h(r.w) - um3;
            float sq = fdot2f(d3, d3, fdot2f(d2, d2, fdot2f(d1, d1, fdot2f(d0, d0, 0.0f))));
            sq = red8(sq);                       // uniform within 8-lane group
            float sc = sqrtf(sq) * SC;
            if (sc > m_run) {                    // group-uniform branch
                float s = exp2f(m_run - sc);
                l *= s;
                h2v s2 = pk(s, s);
                ac0 *= s2; ac1 *= s2; ac2 *= s2; ac3 *= s2;
                m_run = sc;
            }
            float e = exp2f(sc - m_run);
            l += e;
            h2v e2 = pk(e, e);
            ac0 += e2 * u2h(r.x); ac1 += e2 * u2h(r.y);
            ac2 += e2 * u2h(r.z); ac3 += e2 * u2h(r.w);
        }
        float mx = fmaxf(m_run, dpp_mov<0x128>(m_run));
        float M = fmaxf(mx, __shfl_xor(mx, 16, 64));
        M = fmaxf(M, __shfl_xor(M, 32, 64));
        float wgt = (l > 0.0f) ? exp2f(m_run - M) : 0.0f;
        l *= wgt;
        h2v w2 = pk(wgt, wgt);
        ac0 *= w2; ac1 *= w2; ac2 *= w2; ac3 *= w2;
    }

    // cross-group merge (fast paths share a common M; fallback pre-scaled)
    l = l + dpp_mov<0x128>(l);
    ac0 = grpadd8(ac0); ac1 = grpadd8(ac1); ac2 = grpadd8(ac2); ac3 = grpadd8(ac3);
    #pragma unroll
    for (int m = 16; m <= 32; m <<= 1) {
        l   += __shfl_xor(l, m, 64);
        ac0 += u2h(__shfl_xor(h2u(ac0), m, 64));
        ac1 += u2h(__shfl_xor(h2u(ac1), m, 64));
        ac2 += u2h(__shfl_xor(h2u(ac2), m, 64));
        ac3 += u2h(__shfl_xor(h2u(ac3), m, 64));
    }
    float invl = (l > 0.0f) ? (1.0f / l) : 0.0f;
    float u0 = (float)ac0[0] * invl, u1 = (float)ac0[1] * invl;
    float u2 = (float)ac1[0] * invl, u3 = (float)ac1[1] * invl;
    float u4 = (float)ac2[0] * invl, u5 = (float)ac2[1] * invl;
    float u6 = (float)ac3[0] * invl, u7 = (float)ac3[1] * invl;

    float sq2 = u0*u0 + u1*u1 + u2*u2 + u3*u3 + u4*u4 + u5*u5 + u6*u6 + u7*u7;
    sq2 = red8(sq2);
    float inv = 1.0f / fmaxf(sqrtf(sq2), 1e-12f);
    if (grp == 0) {
        size_t fo = (size_t)row * 16 + 2 * t;
        float4 c0 = ((const float4*)base_user)[fo];
        float4 c1 = ((const float4*)base_user)[fo + 1];
        ((float4*)out_user)[fo]     = make_float4(c0.x + u0*inv, c0.y + u1*inv,
                                                  c0.z + u2*inv, c0.w + u3*inv);
        ((float4*)out_user)[fo + 1] = make_float4(c1.x + u4*inv, c1.y + u5*inv,
                                                  c1.z + u6*inv, c1.w + u7*inv);
    }
}

// =================== hop kernel wrappers ===================

// hop-1 gather+finalize (row-per-group) co-scheduled with the user-side sort
__global__ void gf1_p4u_k(const uint4* __restrict__ E0,
                          const unsigned int* __restrict__ row_start,
                          const int* __restrict__ col,
                          uint4* __restrict__ E1, uint4* __restrict__ itemsA,
                          const unsigned int* __restrict__ baseU,
                          const unsigned int* __restrict__ binnedU,
                          const float* __restrict__ binnedUV,
                          int2* __restrict__ upair, unsigned int* __restrict__ u_row_start) {
    __shared__ unsigned int h[CB_SIZE];
    __shared__ unsigned int ex[CB_SIZE];
    __shared__ unsigned int pairs[256];
    int bid = blockIdx.x;
    if (bid < NB_U) {
        build_user_f(baseU, binnedU, binnedUV, upair, u_row_start, h, ex, pairs, bid);
    } else {
        int lane = threadIdx.x & 63;
        int row = (bid - NB_U) * 32 + (threadIdx.x >> 6) * 8 + (lane >> 3);
        gather_fin_row8(row, lane & 7, row < N_ENT, E0, row_start, col, E1, itemsA,
                        nullptr, nullptr, nullptr, 0);
    }
}

// combined: hop-2 gather+finalize (out_ent = emb + v1 + v2) co-scheduled with
// hop-1 fused_user. Interleave 3 gather : 16 user per 19 blocks
// (4688 gather blocks vs 25000 user blocks ~ 3:16).
__global__ void g2_u1_k(const uint4* __restrict__ entb,           // E1
                        const unsigned int* __restrict__ row_start,
                        const int* __restrict__ col,
                        uint4* __restrict__ items_out,            // itemsB
                        const float* __restrict__ entity_emb,
                        float* __restrict__ out_ent,
                        const uint4* __restrict__ itemsb1,        // itemsA
                        const unsigned int* __restrict__ u_row_start,
                        const int2* __restrict__ up,
                        const float* __restrict__ base_user,      // user_emb
                        float* __restrict__ out_user) {
    __shared__ uint4 cache[4][UCACHE][8];   // 16 KB (fallback only)
    int bid = blockIdx.x;
    int g = bid / 19, r = bid - g * 19;
    int w    = threadIdx.x >> 6;
    int lane = threadIdx.x & 63;
    if (r < 3) {
        int gb = g * 3 + r;                  // < 4689; rows guarded below
        int row = gb * 32 + w * 8 + (lane >> 3);
        gather_fin_row8(row, lane & 7, row < N_ENT, entb, row_start, col,
                        nullptr, items_out, entity_emb, entb, out_ent, 1);
    } else {
        int idx = g * 16 + (r - 3);          // < 25008
        int row = idx * 4 + w;
        if (row < N_USERS)
            fused_user_row(row, lane, cache[w], itemsb1, u_row_start, up,
                           base_user, out_user);
    }
}

// hop-2 user pipeline
__global__ void fused_user_k(const uint4* __restrict__ itemsb,
                             const unsigned int* __restrict__ u_row_start,
                             const int2* __restrict__ up,
                             const float* __restrict__ base_user,
                             float* __restrict__ out_user) {
    __shared__ uint4 cache[4][UCACHE][8];
    int wave = (blockIdx.x * blockDim.x + threadIdx.x) >> 6;
    int w    = threadIdx.x >> 6;
    int lane = threadIdx.x & 63;
    if (wave >= N_USERS) return;
    fused_user_row(wave, lane, cache[w], itemsb, u_row_start, up, base_user, out_user);
}

extern "C" void kernel_launch(void* const* d_in, const int* in_sizes, int n_in,
                              void* d_out, int out_size, void* d_ws, size_t ws_size,
                              hipStream_t stream) {
    const float* user_emb   = (const float*)d_in[0];
    const float* entity_emb = (const float*)d_in[1];
    const int*   edge_index = (const int*)d_in[3];
    const int*   iu = (const int*)d_in[5];
    const int*   ii = (const int*)d_in[6];
    const float* iv = (const float*)d_in[7];

    float* out_user = (float*)d_out;
    float* out_ent  = out_user + (size_t)N_USERS * CH;

    // ---- workspace layout (~68.3 MB), uint4 view ----
    uint4* E0     = (uint4*)d_ws;                        // N_ENT*8   (19.2 MB)
    uint4* E1     = E0 + (size_t)N_ENT * 8;              // N_ENT*8   (19.2 MB)
    uint4* itemsA = E1 + (size_t)N_ENT * 8;              // N_ITEMS*8 (6.4 MB)
    uint4* itemsB = itemsA + (size_t)N_ITEMS * 8;        // N_ITEMS*8 (6.4 MB)
    int2*  upair  = (int2*)(itemsB + (size_t)N_ITEMS * 8);       // NNZ (8 MB)
    int*   col    = (int*)(upair + NNZ);                 // N_EDGES (8 MB)
    unsigned int* row_start   = (unsigned int*)(col + N_EDGES);  // N_ENT+1
    unsigned int* u_row_start = row_start + N_ENT + 1;           // N_USERS+1
    unsigned int* cntE  = u_row_start + N_USERS + 1;             // NB_E
    unsigned int* cntU  = cntE + NB_E;                           // NB_U
    unsigned int* baseE = cntU + NB_U;                           // NB_E+1
    unsigned int* curE  = baseE + NB_E + 1;                      // NB_E
    unsigned int* baseU = curE + NB_E;                           // NB_U+1
    unsigned int* curU  = baseU + NB_U + 1;                      // NB_U

    // build-time scratch:
    //  - binnedE aliased over E1: consumed by build_p3u_p4e, before gf1 writes E1.
    //  - binnedU/UV aliased over out_user: consumed by gf1's sort-U blocks;
    //    out_user first really written by g2_u1_k.
    unsigned int* binnedE  = (unsigned int*)E1;                  // N_EDGES
    unsigned int* binnedU  = (unsigned int*)out_user;            // NNZ
    float*        binnedUV = (float*)(binnedU + NNZ);            // NNZ

    const int* head = edge_index;
    const int* tail = edge_index + N_EDGES;

    // ---- CSR builds (structure constant across hops) ----
    (void)hipMemsetAsync(cntE, 0, (size_t)(NB_E + NB_U) * 4, stream);
    build_p1<<<2 * NBLK_CNT + NBLK_CONV, 256, 0, stream>>>(head, iu, entity_emb,
                                                           (uint2*)E0, cntE, cntU);
    build_p2<<<2, 512, 0, stream>>>(cntE, baseE, curE, cntU, baseU, curU);
    build_p3e<<<NBLK_BS_E, 256, 0, stream>>>(head, tail, curE, binnedE);
    build_p3u_p4e<<<NBLK_BS_U + NB_E, 256, 0, stream>>>(iu, ii, iv, curU, binnedU, binnedUV,
                                                        baseE, binnedE, col, row_start);

    // ---- hop-1 gather+finalize (E0 -> E1, itemsA) + user-side sort ----
    gf1_p4u_k<<<NB_U + GB_G8, 256, 0, stream>>>(E0, row_start, col, E1, itemsA,
                                                baseU, binnedU, binnedUV,
                                                upair, u_row_start);

    // ---- hop-2 gather+finalize (out_ent = emb + v1 + v2) + hop-1 user ----
    g2_u1_k<<<G2U1_NG * 19, 256, 0, stream>>>(E1, row_start, col, itemsB,
                                              entity_emb, out_ent,
                                              itemsA, u_row_start, upair,
                                              user_emb, out_user);

    // ---- hop 2 user pipeline: out_user += u2 ----
    fused_user_k<<<GB_USER, 256, 0, stream>>>(itemsB, u_row_start, upair,
                                              out_user, out_user);
}

// Round 9
// 399.527 us; speedup vs baseline: 1.5017x; 1.0883x over previous
//
#include <hip/hip_runtime.h>

#define N_USERS   100000
#define N_ITEMS   50000
#define N_ENT     150000
#define N_EDGES   2000000
#define NNZ       1000000
#define CH        64

#define CB_SHIFT  9
#define CB_SIZE   512
#define NB_E      ((N_ENT   + CB_SIZE - 1) >> CB_SHIFT)   // 293
#define NB_U      ((N_USERS + CB_SIZE - 1) >> CB_SHIFT)   // 196
#define A_CHUNK   4096
#define UCACHE    32     // register/LDS fast-path bound; fallback handles deg > UCACHE
#define ECAP      8192   // per-bucket capacity, E (Poisson mean 6826, +16 sigma)
#define UCAP      6144   // per-bucket capacity, U (Poisson mean 5102, +14 sigma)

#define NBLK_CONV  ((N_ENT * 16 + 255) / 256)             // 9375
#define NBLK_BS_E  ((N_EDGES + A_CHUNK - 1) / A_CHUNK)    // 489
#define NBLK_BS_U  ((NNZ + A_CHUNK - 1) / A_CHUNK)        // 245
#define GB_G8      ((N_ENT + 31) / 32)                    // 4688 gather blocks (32 rows/block)
#define GB_USER    (N_USERS / 4)                          // 25000 blocks (1 wave = 1 user)
#define G2U1_NG    1563                                   // ceil(4688/3) == ceil(25000/16)

// ---- packed fp16 helpers: tables are fp16; rows are 8 lanes x uint4 (16B) ----
typedef __fp16 h2v __attribute__((ext_vector_type(2)));

__device__ __forceinline__ h2v h2z() { h2v z = {(__fp16)0.f, (__fp16)0.f}; return z; }
__device__ __forceinline__ h2v pk(float a, float b) { return __builtin_amdgcn_cvt_pkrtz(a, b); }
__device__ __forceinline__ unsigned int h2u(h2v h) { return __builtin_bit_cast(unsigned int, h); }
__device__ __forceinline__ h2v u2h(unsigned int u) { return __builtin_bit_cast(h2v, u); }
__device__ __forceinline__ float fdot2f(h2v a, h2v b, float c) {
    return __builtin_amdgcn_fdot2(a, b, c, false);   // f32 accumulate of packed f16 dot
}

// ---- DPP helpers (VALU-only cross-lane; DPP row = 16 lanes) ----
template<int CTRL>
__device__ __forceinline__ float dpp_mov(float x) {
    return __builtin_bit_cast(float, __builtin_amdgcn_update_dpp(
        0, __builtin_bit_cast(int, x), CTRL, 0xF, 0xF, true));
}
template<int CTRL>
__device__ __forceinline__ unsigned dpp_mov_u(unsigned x) {
    return (unsigned)__builtin_amdgcn_update_dpp(0, (int)x, CTRL, 0xF, 0xF, true);
}
// 8-lane all-reduce sum (within each 8-lane group)
__device__ __forceinline__ float red8(float x) {
    x += dpp_mov<0xB1>(x);    // quad_perm [1,0,3,2]  (xor 1)
    x += dpp_mov<0x4E>(x);    // quad_perm [2,3,0,1]  (xor 2)
    x += dpp_mov<0x141>(x);   // row_half_mirror: i<->7-i within 8
    return x;
}
// lane^8 partner add for packed fp16 (row_ror:8 == xor8 within the 16-lane row)
__device__ __forceinline__ h2v grpadd8(h2v a) {
    return a + u2h(dpp_mov_u<0x128>(h2u(a)));
}

// =================== build phase (direct-bucket, no count/scan pass) ===================

// E-side bin scatter: chunk -> LDS histogram -> bucket reservation -> scatter
__device__ __forceinline__ void binscat_ent_f(const int* __restrict__ head,
                                              const int* __restrict__ tail,
                                              unsigned int* __restrict__ cur,
                                              unsigned int* __restrict__ binned,
                                              unsigned int* h, unsigned int* bb, int bid) {
    int lo = bid * A_CHUNK;
    int hi = min(lo + A_CHUNK, N_EDGES);
    for (int i = threadIdx.x; i < NB_E; i += blockDim.x) h[i] = 0;
    __syncthreads();
    for (int e = lo + threadIdx.x; e < hi; e += blockDim.x)
        atomicAdd(&h[head[e] >> CB_SHIFT], 1u);
    __syncthreads();
    for (int i = threadIdx.x; i < NB_E; i += blockDim.x) {
        unsigned int c = h[i];
        bb[i] = c ? ((unsigned int)i * ECAP + atomicAdd(&cur[i], c)) : 0u;
        h[i] = 0;
    }
    __syncthreads();
    for (int e = lo + threadIdx.x; e < hi; e += blockDim.x) {
        int hd = head[e];
        int b = hd >> CB_SHIFT;
        unsigned int r = atomicAdd(&h[b], 1u);
        unsigned int local = (unsigned int)hd & (CB_SIZE - 1);
        binned[bb[b] + r] = (local << 18) | (unsigned int)tail[e];   // tail < 2^18
    }
}

// U-side bin scatter
__device__ __forceinline__ void binscat_user_f(const int* __restrict__ iu,
                                               const int* __restrict__ ii,
                                               const float* __restrict__ iv,
                                               unsigned int* __restrict__ cur,
                                               unsigned int* __restrict__ binned,
                                               float* __restrict__ binnedv,
                                               unsigned int* h, unsigned int* bb, int bid) {
    int lo = bid * A_CHUNK;
    int hi = min(lo + A_CHUNK, NNZ);
    for (int i = threadIdx.x; i < NB_U; i += blockDim.x) h[i] = 0;
    __syncthreads();
    for (int e = lo + threadIdx.x; e < hi; e += blockDim.x)
        atomicAdd(&h[iu[e] >> CB_SHIFT], 1u);
    __syncthreads();
    for (int i = threadIdx.x; i < NB_U; i += blockDim.x) {
        unsigned int c = h[i];
        bb[i] = c ? ((unsigned int)i * UCAP + atomicAdd(&cur[i], c)) : 0u;
        h[i] = 0;
    }
    __syncthreads();
    for (int e = lo + threadIdx.x; e < hi; e += blockDim.x) {
        int u = iu[e];
        int b = u >> CB_SHIFT;
        unsigned int r = atomicAdd(&h[b], 1u);
        unsigned int slot = bb[b] + r;
        unsigned int local = (unsigned int)u & (CB_SIZE - 1);
        binned[slot] = (local << 16) | (unsigned int)ii[e];          // item < 2^16
        binnedv[slot] = iv[e];
    }
}

// D1: both bin scatters + fp32->fp16 convert, one dispatch (no dependencies)
__global__ void build_d1(const int* __restrict__ head, const int* __restrict__ tail,
                         const int* __restrict__ iu, const int* __restrict__ ii,
                         const float* __restrict__ iv,
                         const float* __restrict__ entity_emb, uint2* __restrict__ E0,
                         unsigned int* __restrict__ curE, unsigned int* __restrict__ binnedE,
                         unsigned int* __restrict__ curU, unsigned int* __restrict__ binnedU,
                         float* __restrict__ binnedUV) {
    __shared__ unsigned int h[NB_E];
    __shared__ unsigned int bb[NB_E];
    int bid = blockIdx.x;
    if (bid < NBLK_BS_E) {
        binscat_ent_f(head, tail, curE, binnedE, h, bb, bid);
    } else if (bid < NBLK_BS_E + NBLK_BS_U) {
        binscat_user_f(iu, ii, iv, curU, binnedU, binnedUV, h, bb, bid - NBLK_BS_E);
    } else {
        int i = (bid - NBLK_BS_E - NBLK_BS_U) * 256 + threadIdx.x;
        if (i < N_ENT * 16) {
            float4 a = ((const float4*)entity_emb)[i];
            E0[i] = make_uint2(h2u(pk(a.x, a.y)), h2u(pk(a.z, a.w)));
        }
    }
}

// E-side per-bucket counting sort -> col + erow{start,deg}
__device__ __forceinline__ void csort_ent_f(const unsigned int* __restrict__ cnt,
                                            const unsigned int* __restrict__ binned,
                                            int* __restrict__ col,
                                            uint2* __restrict__ erow,
                                            unsigned int* h, unsigned int* ex,
                                            unsigned int* pairs, int b) {
    unsigned int s0 = (unsigned int)b * ECAP;
    unsigned int n  = min(cnt[b], (unsigned int)ECAP);
    unsigned int s1 = s0 + n;
    int t = threadIdx.x;
    h[2 * t] = 0; h[2 * t + 1] = 0;
    __syncthreads();
    for (unsigned int j = s0 + t; j < s1; j += 256)
        atomicAdd(&h[binned[j] >> 18], 1u);
    __syncthreads();
    unsigned int a0 = h[2 * t], a1 = h[2 * t + 1];
    pairs[t] = a0 + a1;
    __syncthreads();
    for (int off = 1; off < 256; off <<= 1) {
        unsigned int u = 0;
        if (t >= off) u = pairs[t - off];
        __syncthreads();
        if (t >= off) pairs[t] += u;
        __syncthreads();
    }
    unsigned int pe = pairs[t] - (a0 + a1);
    ex[2 * t] = pe;
    ex[2 * t + 1] = pe + a0;
    __syncthreads();
    int keybase = b << CB_SHIFT;
    if (keybase + 2 * t < N_ENT)     erow[keybase + 2 * t]     = make_uint2(s0 + ex[2 * t], a0);
    if (keybase + 2 * t + 1 < N_ENT) erow[keybase + 2 * t + 1] = make_uint2(s0 + ex[2 * t + 1], a1);
    __syncthreads();
    h[2 * t] = 0; h[2 * t + 1] = 0;
    __syncthreads();
    for (unsigned int j = s0 + t; j < s1; j += 256) {
        unsigned int p = binned[j];
        unsigned int local = p >> 18;
        unsigned int r = atomicAdd(&h[local], 1u);
        col[s0 + ex[local] + r] = (int)(p & 0x3FFFFu);
    }
}

// U-side per-bucket counting sort -> upair + urow{start,deg}
__device__ __forceinline__ void csort_user_f(const unsigned int* __restrict__ cnt,
                                             const unsigned int* __restrict__ binned,
                                             const float* __restrict__ binnedv,
                                             int2* __restrict__ upair,
                                             uint2* __restrict__ urow,
                                             unsigned int* h, unsigned int* ex,
                                             unsigned int* pairs, int b) {
    unsigned int s0 = (unsigned int)b * UCAP;
    unsigned int n  = min(cnt[b], (unsigned int)UCAP);
    unsigned int s1 = s0 + n;
    int t = threadIdx.x;
    h[2 * t] = 0; h[2 * t + 1] = 0;
    __syncthreads();
    for (unsigned int j = s0 + t; j < s1; j += 256)
        atomicAdd(&h[binned[j] >> 16], 1u);
    __syncthreads();
    unsigned int a0 = h[2 * t], a1 = h[2 * t + 1];
    pairs[t] = a0 + a1;
    __syncthreads();
    for (int off = 1; off < 256; off <<= 1) {
        unsigned int u = 0;
        if (t >= off) u = pairs[t - off];
        __syncthreads();
        if (t >= off) pairs[t] += u;
        __syncthreads();
    }
    unsigned int pe = pairs[t] - (a0 + a1);
    ex[2 * t] = pe;
    ex[2 * t + 1] = pe + a0;
    __syncthreads();
    int keybase = b << CB_SHIFT;
    if (keybase + 2 * t < N_USERS)     urow[keybase + 2 * t]     = make_uint2(s0 + ex[2 * t], a0);
    if (keybase + 2 * t + 1 < N_USERS) urow[keybase + 2 * t + 1] = make_uint2(s0 + ex[2 * t + 1], a1);
    __syncthreads();
    h[2 * t] = 0; h[2 * t + 1] = 0;
    __syncthreads();
    for (unsigned int j = s0 + t; j < s1; j += 256) {
        unsigned int p = binned[j];
        float v = binnedv[j];
        unsigned int local = p >> 16;
        unsigned int r = atomicAdd(&h[local], 1u);
        upair[s0 + ex[local] + r] = make_int2((int)(p & 0xFFFFu), __float_as_int(v));
    }
}

// D2: E-side counting sort (U-side is folded into the hop-1 dispatch)
__global__ void build_d2(const unsigned int* __restrict__ curE,
                         const unsigned int* __restrict__ binnedE,
                         int* __restrict__ col, uint2* __restrict__ erow) {
    __shared__ unsigned int h[CB_SIZE];
    __shared__ unsigned int ex[CB_SIZE];
    __shared__ unsigned int pairs[256];
    csort_ent_f(curE, binnedE, col, erow, h, ex, pairs, blockIdx.x);
}

// =================== hop kernels, device bodies ===================

// CSR gather, row-per-group: one 8-lane group owns one entity row (8 rows/wave).
// 4 row loads in flight per group. No cross-group reduction.
// mode 0: ent_out = fp16(l2norm(mean)), items = fp16(mean).
// mode 1: items = fp16(mean), out_ent = emb + fp16(v1) + v2.
__device__ __forceinline__ void gather_fin_row8(int row, int t, bool valid,
        const uint4* __restrict__ entb, const uint2* __restrict__ erow,
        const int* __restrict__ col,
        uint4* __restrict__ ent_out, uint4* __restrict__ items_out,
        const float* __restrict__ base_ent, const uint4* __restrict__ v1tab,
        float* __restrict__ out_ent, int mode) {
    unsigned int s0 = 0, deg = 0;
    if (valid) { uint2 rs = erow[row]; s0 = rs.x; deg = rs.y; }
    unsigned int s1 = s0 + deg;

    h2v a0 = h2z(), a1 = h2z(), a2 = h2z(), a3 = h2z();
    unsigned int j = s0;
    for (; j + 3 < s1; j += 4) {               // 4 loads in flight per group
        int c0 = col[j], c1 = col[j + 1], c2 = col[j + 2], c3 = col[j + 3];
        uint4 x0 = entb[(size_t)c0 * 8 + t];
        uint4 x1 = entb[(size_t)c1 * 8 + t];
        uint4 x2 = entb[(size_t)c2 * 8 + t];
        uint4 x3 = entb[(size_t)c3 * 8 + t];
        a0 += (u2h(x0.x) + u2h(x1.x)) + (u2h(x2.x) + u2h(x3.x));
        a1 += (u2h(x0.y) + u2h(x1.y)) + (u2h(x2.y) + u2h(x3.y));
        a2 += (u2h(x0.z) + u2h(x1.z)) + (u2h(x2.z) + u2h(x3.z));
        a3 += (u2h(x0.w) + u2h(x1.w)) + (u2h(x2.w) + u2h(x3.w));
    }
    for (; j < s1; ++j) {
        uint4 x = entb[(size_t)col[j] * 8 + t];
        a0 += u2h(x.x); a1 += u2h(x.y); a2 += u2h(x.z); a3 += u2h(x.w);
    }
    float inv = 1.0f / fmaxf((float)deg, 1.0f);
    float m0 = (float)a0[0] * inv, m1 = (float)a0[1] * inv;
    float m2 = (float)a1[0] * inv, m3 = (float)a1[1] * inv;
    float m4 = (float)a2[0] * inv, m5 = (float)a2[1] * inv;
    float m6 = (float)a3[0] * inv, m7 = (float)a3[1] * inv;

    float sq = m0*m0 + m1*m1 + m2*m2 + m3*m3 + m4*m4 + m5*m5 + m6*m6 + m7*m7;
    sq = red8(sq);
    float invn = 1.0f / fmaxf(sqrtf(sq), 1e-12f);

    if (!valid) return;
    size_t o = (size_t)row * 8 + t;
    if (row < N_ITEMS)
        items_out[o] = make_uint4(h2u(pk(m0, m1)), h2u(pk(m2, m3)),
                                  h2u(pk(m4, m5)), h2u(pk(m6, m7)));
    if (mode == 0) {
        ent_out[o] = make_uint4(h2u(pk(m0*invn, m1*invn)), h2u(pk(m2*invn, m3*invn)),
                                h2u(pk(m4*invn, m5*invn)), h2u(pk(m6*invn, m7*invn)));
    } else {
        size_t fo = (size_t)row * 16 + 2 * t;          // float4 index
        float4 c0 = ((const float4*)base_ent)[fo];
        float4 c1 = ((const float4*)base_ent)[fo + 1];
        uint4 v1 = v1tab[o];
        h2v p0 = u2h(v1.x), p1 = u2h(v1.y), p2 = u2h(v1.z), p3 = u2h(v1.w);
        ((float4*)out_ent)[fo]     = make_float4(c0.x + (float)p0[0] + m0*invn,
                                                 c0.y + (float)p0[1] + m1*invn,
                                                 c0.z + (float)p1[0] + m2*invn,
                                                 c0.w + (float)p1[1] + m3*invn);
        ((float4*)out_ent)[fo + 1] = make_float4(c1.x + (float)p2[0] + m4*invn,
                                                 c1.y + (float)p2[1] + m5*invn,
                                                 c1.z + (float)p3[0] + m6*invn,
                                                 c1.w + (float)p3[1] + m7*invn);
    }
}

// register-resident user fast path: rows in r[NS] uint4 VGPRs, 8-lane groups.
template<int NS>
__device__ __forceinline__ void user_fast_path(
        unsigned int s0, unsigned int deg, int grp, int t,
        const uint4* __restrict__ itemsb, const int2* __restrict__ up,
        float& l, h2v& ac0, h2v& ac1, h2v& ac2, h2v& ac3) {
    const float SC = 5.0f * 1.44269504f;   // (1/TEMPERATURE) * log2(e)
    uint4 r[NS];
    float vw[NS];
    #pragma unroll
    for (int k = 0; k < NS; ++k) {
        unsigned int slot = (unsigned int)grp + 8u * k;
        if (slot < deg) {
            int2 p = up[s0 + slot];
            r[k] = itemsb[(size_t)p.x * 8 + t];
            vw[k] = __int_as_float(p.y);
        } else {
            r[k] = make_uint4(0u, 0u, 0u, 0u);
            vw[k] = 0.0f;
        }
    }
    // weighted mean (invalid slots contribute 0)
    h2v um0 = h2z(), um1 = h2z(), um2 = h2z(), um3 = h2z();
    #pragma unroll
    for (int k = 0; k < NS; ++k) {
        h2v v2 = pk(vw[k], vw[k]);
        um0 += v2 * u2h(r[k].x); um1 += v2 * u2h(r[k].y);
        um2 += v2 * u2h(r[k].z); um3 += v2 * u2h(r[k].w);
    }
    um0 = grpadd8(um0); um1 = grpadd8(um1); um2 = grpadd8(um2); um3 = grpadd8(um3);
    #pragma unroll
    for (int m = 16; m <= 32; m <<= 1) {
        um0 += u2h(__shfl_xor(h2u(um0), m, 64));
        um1 += u2h(__shfl_xor(h2u(um1), m, 64));
        um2 += u2h(__shfl_xor(h2u(um2), m, 64));
        um3 += u2h(__shfl_xor(h2u(um3), m, 64));
    }
    // scores (branchless: invalid -> -1e30 -> exp2 -> 0)
    float scv[NS];
    float mloc = -1e30f;
    #pragma unroll
    for (int k = 0; k < NS; ++k) {
        unsigned int slot = (unsigned int)grp + 8u * k;
        h2v d0 = u2h(r[k].x) - um0, d1 = u2h(r[k].y) - um1;
        h2v d2 = u2h(r[k].z) - um2, d3 = u2h(r[k].w) - um3;
        float sq = fdot2f(d3, d3, fdot2f(d2, d2, fdot2f(d1, d1, fdot2f(d0, d0, 0.0f))));
        sq = red8(sq);
        float sc = sqrtf(sq) * SC;
        scv[k] = (slot < deg) ? sc : -1e30f;
        mloc = fmaxf(mloc, scv[k]);
    }
    mloc = fmaxf(mloc, dpp_mov<0x128>(mloc));          // xor8
    float M = fmaxf(mloc, __shfl_xor(mloc, 16, 64));
    M = fmaxf(M, __shfl_xor(M, 32, 64));
    #pragma unroll
    for (int k = 0; k < NS; ++k) {
        float e = exp2f(scv[k] - M);
        l += e;
        h2v e2 = pk(e, e);
        ac0 += e2 * u2h(r[k].x); ac1 += e2 * u2h(r[k].y);
        ac2 += e2 * u2h(r[k].z); ac3 += e2 * u2h(r[k].w);
    }
}

// fused user pipeline: one wave per user, 8x8-lane groups.
// deg<=16: 2-slot reg path; deg<=32: 4-slot reg path; else LDS online fallback.
__device__ __forceinline__ void fused_user_row(int row, int lane, uint4 (*cw)[8],
        const uint4* __restrict__ itemsb, const uint2* __restrict__ urow,
        const int2* __restrict__ up, const float* __restrict__ base_user,
        float* __restrict__ out_user) {
    int grp = lane >> 3;
    int t   = lane & 7;
    uint2 rs = urow[row];
    unsigned int s0 = rs.x;
    unsigned int deg = rs.y;
    unsigned int s1 = s0 + deg;

    const float SC = 5.0f * 1.44269504f;
    float l = 0.0f;
    h2v ac0 = h2z(), ac1 = h2z(), ac2 = h2z(), ac3 = h2z();

    if (__builtin_expect(deg <= 16, 1)) {
        user_fast_path<2>(s0, deg, grp, t, itemsb, up, l, ac0, ac1, ac2, ac3);
    } else if (deg <= UCACHE) {
        user_fast_path<4>(s0, deg, grp, t, itemsb, up, l, ac0, ac1, ac2, ac3);
    } else {
        // ---- fallback (deg > 32, ~never): LDS cache + online softmax ----
        h2v um0 = h2z(), um1 = h2z(), um2 = h2z(), um3 = h2z();
        for (unsigned int j = s0 + grp; j < s1; j += 8) {
            int2 p = up[j];
            uint4 r = itemsb[(size_t)p.x * 8 + t];
            int slot = (int)(j - s0);
            if (slot < UCACHE) cw[slot][t] = r;
            float v = __int_as_float(p.y);
            h2v v2 = pk(v, v);
            um0 += v2 * u2h(r.x); um1 += v2 * u2h(r.y);
            um2 += v2 * u2h(r.z); um3 += v2 * u2h(r.w);
        }
        um0 = grpadd8(um0); um1 = grpadd8(um1); um2 = grpadd8(um2); um3 = grpadd8(um3);
        #pragma unroll
        for (int m = 16; m <= 32; m <<= 1) {
            um0 += u2h(__shfl_xor(h2u(um0), m, 64));
            um1 += u2h(__shfl_xor(h2u(um1), m, 64));
            um2 += u2h(__shfl_xor(h2u(um2), m, 64));
            um3 += u2h(__shfl_xor(h2u(um3), m, 64));
        }
        float m_run = -1e30f;
        for (unsigned int j = s0 + grp; j < s1; j += 8) {
            int slot = (int)(j - s0);
            uint4 r = (slot < UCACHE) ? cw[slot][t]
                                      : itemsb[(size_t)up[j].x * 8 + t];
            h2v d0 = u2h(r.x) - um0, d1 = u2h(r.y) - um1;
            h2v d2 = u2h(r.z) - um2, d3 = u2h(r.w) - um3;
            float sq = fdot2f(d3, d3, fdot2f(d2, d2, fdot2f(d1, d1, fdot2f(d0, d0, 0.0f))));
            sq = red8(sq);                       // uniform within 8-lane group
            float sc = sqrtf(sq) * SC;
            if (sc > m_run) {                    // group-uniform branch
                float s = exp2f(m_run - sc);
                l *= s;
                h2v s2 = pk(s, s);
                ac0 *= s2; ac1 *= s2; ac2 *= s2; ac3 *= s2;
                m_run = sc;
            }
            float e = exp2f(sc - m_run);
            l += e;
            h2v e2 = pk(e, e);
            ac0 += e2 * u2h(r.x); ac1 += e2 * u2h(r.y);
            ac2 += e2 * u2h(r.z); ac3 += e2 * u2h(r.w);
        }
        float mx = fmaxf(m_run, dpp_mov<0x128>(m_run));
        float M = fmaxf(mx, __shfl_xor(mx, 16, 64));
        M = fmaxf(M, __shfl_xor(M, 32, 64));
        float wgt = (l > 0.0f) ? exp2f(m_run - M) : 0.0f;
        l *= wgt;
        h2v w2 = pk(wgt, wgt);
        ac0 *= w2; ac1 *= w2; ac2 *= w2; ac3 *= w2;
    }

    // cross-group merge (fast paths share a common M; fallback pre-scaled)
    l = l + dpp_mov<0x128>(l);
    ac0 = grpadd8(ac0); ac1 = grpadd8(ac1); ac2 = grpadd8(ac2); ac3 = grpadd8(ac3);
    #pragma unroll
    for (int m = 16; m <= 32; m <<= 1) {
        l   += __shfl_xor(l, m, 64);
        ac0 += u2h(__shfl_xor(h2u(ac0), m, 64));
        ac1 += u2h(__shfl_xor(h2u(ac1), m, 64));
        ac2 += u2h(__shfl_xor(h2u(ac2), m, 64));
        ac3 += u2h(__shfl_xor(h2u(ac3), m, 64));
    }
    float invl = (l > 0.0f) ? (1.0f / l) : 0.0f;
    float u0 = (float)ac0[0] * invl, u1 = (float)ac0[1] * invl;
    float u2 = (float)ac1[0] * invl, u3 = (float)ac1[1] * invl;
    float u4 = (float)ac2[0] * invl, u5 = (float)ac2[1] * invl;
    float u6 = (float)ac3[0] * invl, u7 = (float)ac3[1] * invl;

    float sq2 = u0*u0 + u1*u1 + u2*u2 + u3*u3 + u4*u4 + u5*u5 + u6*u6 + u7*u7;
    sq2 = red8(sq2);
    float inv = 1.0f / fmaxf(sqrtf(sq2), 1e-12f);
    if (grp == 0) {
        size_t fo = (size_t)row * 16 + 2 * t;
        float4 c0 = ((const float4*)base_user)[fo];
        float4 c1 = ((const float4*)base_user)[fo + 1];
        ((float4*)out_user)[fo]     = make_float4(c0.x + u0*inv, c0.y + u1*inv,
                                                  c0.z + u2*inv, c0.w + u3*inv);
        ((float4*)out_user)[fo + 1] = make_float4(c1.x + u4*inv, c1.y + u5*inv,
                                                  c1.z + u6*inv, c1.w + u7*inv);
    }
}

// =================== hop kernel wrappers ===================

// D3: hop-1 gather+finalize (row-per-group) co-scheduled with the user-side sort
__global__ void gf1_p4u_k(const uint4* __restrict__ E0,
                          const uint2* __restrict__ erow,
                          const int* __restrict__ col,
                          uint4* __restrict__ E1, uint4* __restrict__ itemsA,
                          const unsigned int* __restrict__ curU,
                          const unsigned int* __restrict__ binnedU,
                          const float* __restrict__ binnedUV,
                          int2* __restrict__ upair, uint2* __restrict__ urow) {
    __shared__ unsigned int h[CB_SIZE];
    __shared__ unsigned int ex[CB_SIZE];
    __shared__ unsigned int pairs[256];
    int bid = blockIdx.x;
    if (bid < NB_U) {
        csort_user_f(curU, binnedU, binnedUV, upair, urow, h, ex, pairs, bid);
    } else {
        int lane = threadIdx.x & 63;
        int row = (bid - NB_U) * 32 + (threadIdx.x >> 6) * 8 + (lane >> 3);
        gather_fin_row8(row, lane & 7, row < N_ENT, E0, erow, col, E1, itemsA,
                        nullptr, nullptr, nullptr, 0);
    }
}

// D4: hop-2 gather+finalize (out_ent = emb + v1 + v2) co-scheduled with
// hop-1 fused_user. Interleave 3 gather : 16 user per 19 blocks.
__global__ void g2_u1_k(const uint4* __restrict__ entb,           // E1
                        const uint2* __restrict__ erow,
                        const int* __restrict__ col,
                        uint4* __restrict__ items_out,            // itemsB
                        const float* __restrict__ entity_emb,
                        float* __restrict__ out_ent,
                        const uint4* __restrict__ itemsb1,        // itemsA
                        const uint2* __restrict__ urow,
                        const int2* __restrict__ up,
                        const float* __restrict__ base_user,      // user_emb
                        float* __restrict__ out_user) {
    __shared__ uint4 cache[4][UCACHE][8];   // 16 KB (fallback only)
    int bid = blockIdx.x;
    int g = bid / 19, r = bid - g * 19;
    int w    = threadIdx.x >> 6;
    int lane = threadIdx.x & 63;
    if (r < 3) {
        int gb = g * 3 + r;                  // < 4689; rows guarded below
        int row = gb * 32 + w * 8 + (lane >> 3);
        gather_fin_row8(row, lane & 7, row < N_ENT, entb, erow, col,
                        nullptr, items_out, entity_emb, entb, out_ent, 1);
    } else {
        int idx = g * 16 + (r - 3);          // < 25008
        int row = idx * 4 + w;
        if (row < N_USERS)
            fused_user_row(row, lane, cache[w], itemsb1, urow, up,
                           base_user, out_user);
    }
}

// D5: hop-2 user pipeline
__global__ void fused_user_k(const uint4* __restrict__ itemsb,
                             const uint2* __restrict__ urow,
                             const int2* __restrict__ up,
                             const float* __restrict__ base_user,
                             float* __restrict__ out_user) {
    __shared__ uint4 cache[4][UCACHE][8];
    int wave = (blockIdx.x * blockDim.x + threadIdx.x) >> 6;
    int w    = threadIdx.x >> 6;
    int lane = threadIdx.x & 63;
    if (wave >= N_USERS) return;
    fused_user_row(wave, lane, cache[w], itemsb, urow, up, base_user, out_user);
}

extern "C" void kernel_launch(void* const* d_in, const int* in_sizes, int n_in,
                              void* d_out, int out_size, void* d_ws, size_t ws_size,
                              hipStream_t stream) {
    const float* user_emb   = (const float*)d_in[0];
    const float* entity_emb = (const float*)d_in[1];
    const int*   edge_index = (const int*)d_in[3];
    const int*   iu = (const int*)d_in[5];
    const int*   ii = (const int*)d_in[6];
    const float* iv = (const float*)d_in[7];

    float* out_user = (float*)d_out;
    float* out_ent  = out_user + (size_t)N_USERS * CH;

    // ---- workspace layout (~72.5 MB) ----
    uint4* E0     = (uint4*)d_ws;                        // N_ENT*8   (19.2 MB)
    uint4* E1     = E0 + (size_t)N_ENT * 8;              // N_ENT*8   (19.2 MB)
    uint4* itemsA = E1 + (size_t)N_ENT * 8;              // N_ITEMS*8 (6.4 MB)
    uint4* itemsB = itemsA + (size_t)N_ITEMS * 8;        // N_ITEMS*8 (6.4 MB)
    int2*  upair  = (int2*)(itemsB + (size_t)N_ITEMS * 8);       // NB_U*UCAP (9.63 MB)
    int*   col    = (int*)(upair + (size_t)NB_U * UCAP);         // NB_E*ECAP (9.6 MB)
    uint2* erow   = (uint2*)(col + (size_t)NB_E * ECAP);         // N_ENT   (1.2 MB)
    uint2* urow   = erow + N_ENT;                                 // N_USERS (0.8 MB)
    unsigned int* curE = (unsigned int*)(urow + N_USERS);        // NB_E
    unsigned int* curU = curE + NB_E;                             // NB_U

    // build-time scratch:
    //  - binnedE aliased over E1 (9.6 < 19.2 MB): consumed by build_d2, which
    //    completes before gf1_p4u_k writes E1.
    //  - binnedU/UV aliased over out_user (9.6 < 25.6 MB): consumed by the
    //    sort-U blocks of gf1_p4u_k; out_user first really written by g2_u1_k.
    unsigned int* binnedE  = (unsigned int*)E1;                  // NB_E*ECAP
    unsigned int* binnedU  = (unsigned int*)out_user;            // NB_U*UCAP
    float*        binnedUV = (float*)(binnedU + (size_t)NB_U * UCAP);

    const int* head = edge_index;
    const int* tail = edge_index + N_EDGES;

    // ---- direct-bucket CSR build: 2 dispatches ----
    (void)hipMemsetAsync(curE, 0, (size_t)(NB_E + NB_U) * 4, stream);
    build_d1<<<NBLK_BS_E + NBLK_BS_U + NBLK_CONV, 256, 0, stream>>>(
        head, tail, iu, ii, iv, entity_emb, (uint2*)E0,
        curE, binnedE, curU, binnedU, binnedUV);
    build_d2<<<NB_E, 256, 0, stream>>>(curE, binnedE, col, erow);

    // ---- hop-1 gather+finalize (E0 -> E1, itemsA) + user-side sort ----
    gf1_p4u_k<<<NB_U + GB_G8, 256, 0, stream>>>(E0, erow, col, E1, itemsA,
                                                curU, binnedU, binnedUV,
                                                upair, urow);

    // ---- hop-2 gather+finalize (out_ent = emb + v1 + v2) + hop-1 user ----
    g2_u1_k<<<G2U1_NG * 19, 256, 0, stream>>>(E1, erow, col, itemsB,
                                              entity_emb, out_ent,
                                              itemsA, urow, upair,
                                              user_emb, out_user);

    // ---- hop 2 user pipeline: out_user += u2 ----
    fused_user_k<<<GB_USER, 256, 0, stream>>>(itemsB, urow, upair,
                                              out_user, out_user);
}

// Round 10
// 371.247 us; speedup vs baseline: 1.6161x; 1.0762x over previous
//
#include <hip/hip_runtime.h>

#define N_USERS   100000
#define N_ITEMS   50000
#define N_ENT     150000
#define N_EDGES   2000000
#define NNZ       1000000
#define CH        64

#define CB_SHIFT  9
#define CB_SIZE   512
#define NB_E      ((N_ENT   + CB_SIZE - 1) >> CB_SHIFT)   // 293
#define NB_U      ((N_USERS + CB_SIZE - 1) >> CB_SHIFT)   // 196
#define A_CHUNK   4096
#define UCACHE    32     // register/LDS fast-path bound; fallback handles deg > UCACHE
#define ECAP      8192   // per-bucket capacity, E (Poisson mean 6826, +16 sigma)
#define UCAP      6144   // per-bucket capacity, U (Poisson mean 5102, +14 sigma)

#define NBLK_CONV  ((N_ENT * 16 + 255) / 256)             // 9375
#define NBLK_BS_E  ((N_EDGES + A_CHUNK - 1) / A_CHUNK)    // 489
#define NBLK_BS_U  ((NNZ + A_CHUNK - 1) / A_CHUNK)        // 245
#define GB_G8      ((N_ENT + 31) / 32)                    // 4688 gather blocks (32 rows/block)
#define GB_GI      ((N_ITEMS + 31) / 32)                  // 1563 item-row gather blocks
#define GB_GN      ((N_ENT - N_ITEMS) / 32)               // 3125 non-item gather blocks (exact)
#define D4A_NG     1563                                   // 1:16 interleave; 1563*16=25008>=25000
#define D4B_NG     3125                                   // 1:8  interleave; 3125*8=25000 exact

// ---- packed fp16 helpers: tables are fp16; rows are 8 lanes x uint4 (16B) ----
typedef __fp16 h2v __attribute__((ext_vector_type(2)));

__device__ __forceinline__ h2v h2z() { h2v z = {(__fp16)0.f, (__fp16)0.f}; return z; }
__device__ __forceinline__ h2v pk(float a, float b) { return __builtin_amdgcn_cvt_pkrtz(a, b); }
__device__ __forceinline__ unsigned int h2u(h2v h) { return __builtin_bit_cast(unsigned int, h); }
__device__ __forceinline__ h2v u2h(unsigned int u) { return __builtin_bit_cast(h2v, u); }
__device__ __forceinline__ float fdot2f(h2v a, h2v b, float c) {
    return __builtin_amdgcn_fdot2(a, b, c, false);   // f32 accumulate of packed f16 dot
}

// ---- DPP helpers (VALU-only cross-lane; DPP row = 16 lanes) ----
template<int CTRL>
__device__ __forceinline__ float dpp_mov(float x) {
    return __builtin_bit_cast(float, __builtin_amdgcn_update_dpp(
        0, __builtin_bit_cast(int, x), CTRL, 0xF, 0xF, true));
}
template<int CTRL>
__device__ __forceinline__ unsigned dpp_mov_u(unsigned x) {
    return (unsigned)__builtin_amdgcn_update_dpp(0, (int)x, CTRL, 0xF, 0xF, true);
}
// 8-lane all-reduce sum (within each 8-lane group)
__device__ __forceinline__ float red8(float x) {
    x += dpp_mov<0xB1>(x);    // quad_perm [1,0,3,2]  (xor 1)
    x += dpp_mov<0x4E>(x);    // quad_perm [2,3,0,1]  (xor 2)
    x += dpp_mov<0x141>(x);   // row_half_mirror: i<->7-i within 8
    return x;
}
// lane^8 partner add for packed fp16 (row_ror:8 == xor8 within the 16-lane row)
__device__ __forceinline__ h2v grpadd8(h2v a) {
    return a + u2h(dpp_mov_u<0x128>(h2u(a)));
}

// =================== build phase (direct-bucket, no count/scan pass) ===================

// E-side bin scatter (int4 edge loads; all chunk bounds divisible by 4)
__device__ __forceinline__ void binscat_ent_f(const int* __restrict__ head,
                                              const int* __restrict__ tail,
                                              unsigned int* __restrict__ cur,
                                              unsigned int* __restrict__ binned,
                                              unsigned int* h, unsigned int* bb, int bid) {
    int lo = bid * A_CHUNK;
    int hi = min(lo + A_CHUNK, N_EDGES);
    const int4* head4 = (const int4*)head;
    const int4* tail4 = (const int4*)tail;
    int lo4 = lo >> 2, hi4 = hi >> 2;
    for (int i = threadIdx.x; i < NB_E; i += blockDim.x) h[i] = 0;
    __syncthreads();
    for (int e4 = lo4 + threadIdx.x; e4 < hi4; e4 += blockDim.x) {
        int4 hd = head4[e4];
        atomicAdd(&h[hd.x >> CB_SHIFT], 1u);
        atomicAdd(&h[hd.y >> CB_SHIFT], 1u);
        atomicAdd(&h[hd.z >> CB_SHIFT], 1u);
        atomicAdd(&h[hd.w >> CB_SHIFT], 1u);
    }
    __syncthreads();
    for (int i = threadIdx.x; i < NB_E; i += blockDim.x) {
        unsigned int c = h[i];
        bb[i] = c ? ((unsigned int)i * ECAP + atomicAdd(&cur[i], c)) : 0u;
        h[i] = 0;
    }
    __syncthreads();
    for (int e4 = lo4 + threadIdx.x; e4 < hi4; e4 += blockDim.x) {
        int4 hd = head4[e4];
        int4 tl = tail4[e4];
        int hds[4] = {hd.x, hd.y, hd.z, hd.w};
        int tls[4] = {tl.x, tl.y, tl.z, tl.w};
        #pragma unroll
        for (int k = 0; k < 4; ++k) {
            int b = hds[k] >> CB_SHIFT;
            unsigned int r = atomicAdd(&h[b], 1u);
            unsigned int local = (unsigned int)hds[k] & (CB_SIZE - 1);
            binned[bb[b] + r] = (local << 18) | (unsigned int)tls[k];   // tail < 2^18
        }
    }
}

// U-side bin scatter (int4/float4 loads)
__device__ __forceinline__ void binscat_user_f(const int* __restrict__ iu,
                                               const int* __restrict__ ii,
                                               const float* __restrict__ iv,
                                               unsigned int* __restrict__ cur,
                                               unsigned int* __restrict__ binned,
                                               float* __restrict__ binnedv,
                                               unsigned int* h, unsigned int* bb, int bid) {
    int lo = bid * A_CHUNK;
    int hi = min(lo + A_CHUNK, NNZ);
    const int4*   iu4 = (const int4*)iu;
    const int4*   ii4 = (const int4*)ii;
    const float4* iv4 = (const float4*)iv;
    int lo4 = lo >> 2, hi4 = hi >> 2;
    for (int i = threadIdx.x; i < NB_U; i += blockDim.x) h[i] = 0;
    __syncthreads();
    for (int e4 = lo4 + threadIdx.x; e4 < hi4; e4 += blockDim.x) {
        int4 u = iu4[e4];
        atomicAdd(&h[u.x >> CB_SHIFT], 1u);
        atomicAdd(&h[u.y >> CB_SHIFT], 1u);
        atomicAdd(&h[u.z >> CB_SHIFT], 1u);
        atomicAdd(&h[u.w >> CB_SHIFT], 1u);
    }
    __syncthreads();
    for (int i = threadIdx.x; i < NB_U; i += blockDim.x) {
        unsigned int c = h[i];
        bb[i] = c ? ((unsigned int)i * UCAP + atomicAdd(&cur[i], c)) : 0u;
        h[i] = 0;
    }
    __syncthreads();
    for (int e4 = lo4 + threadIdx.x; e4 < hi4; e4 += blockDim.x) {
        int4   u = iu4[e4];
        int4   it = ii4[e4];
        float4 v = iv4[e4];
        int us[4] = {u.x, u.y, u.z, u.w};
        int is[4] = {it.x, it.y, it.z, it.w};
        float vs[4] = {v.x, v.y, v.z, v.w};
        #pragma unroll
        for (int k = 0; k < 4; ++k) {
            int b = us[k] >> CB_SHIFT;
            unsigned int r = atomicAdd(&h[b], 1u);
            unsigned int slot = bb[b] + r;
            unsigned int local = (unsigned int)us[k] & (CB_SIZE - 1);
            binned[slot] = (local << 16) | (unsigned int)is[k];          // item < 2^16
            binnedv[slot] = vs[k];
        }
    }
}

// D1: both bin scatters + fp32->fp16 convert, one dispatch (no dependencies)
__global__ void build_d1(const int* __restrict__ head, const int* __restrict__ tail,
                         const int* __restrict__ iu, const int* __restrict__ ii,
                         const float* __restrict__ iv,
                         const float* __restrict__ entity_emb, uint2* __restrict__ E0,
                         unsigned int* __restrict__ curE, unsigned int* __restrict__ binnedE,
                         unsigned int* __restrict__ curU, unsigned int* __restrict__ binnedU,
                         float* __restrict__ binnedUV) {
    __shared__ unsigned int h[NB_E];
    __shared__ unsigned int bb[NB_E];
    int bid = blockIdx.x;
    if (bid < NBLK_BS_E) {
        binscat_ent_f(head, tail, curE, binnedE, h, bb, bid);
    } else if (bid < NBLK_BS_E + NBLK_BS_U) {
        binscat_user_f(iu, ii, iv, curU, binnedU, binnedUV, h, bb, bid - NBLK_BS_E);
    } else {
        int i = (bid - NBLK_BS_E - NBLK_BS_U) * 256 + threadIdx.x;
        if (i < N_ENT * 16) {
            float4 a = ((const float4*)entity_emb)[i];
            E0[i] = make_uint2(h2u(pk(a.x, a.y)), h2u(pk(a.z, a.w)));
        }
    }
}

// D2: E-side per-bucket counting sort @512 threads, bin-per-thread direct
__global__ __launch_bounds__(512) void build_d2(const unsigned int* __restrict__ curE,
                                                const unsigned int* __restrict__ binnedE,
                                                int* __restrict__ col, uint2* __restrict__ erow) {
    __shared__ unsigned int s[CB_SIZE];
    __shared__ unsigned int hh[CB_SIZE];
    int b = blockIdx.x;
    int t = threadIdx.x;                 // 0..511, owns bin t
    unsigned int s0 = (unsigned int)b * ECAP;
    unsigned int n  = min(curE[b], (unsigned int)ECAP);
    unsigned int s1 = s0 + n;
    hh[t] = 0;
    __syncthreads();
    for (unsigned int j = s0 + t; j < s1; j += 512)
        atomicAdd(&hh[binnedE[j] >> 18], 1u);
    __syncthreads();
    unsigned int cnt = hh[t];
    s[t] = cnt;
    __syncthreads();
    for (int off = 1; off < 512; off <<= 1) {
        unsigned int u = 0;
        if (t >= off) u = s[t - off];
        __syncthreads();
        if (t >= off) s[t] += u;
        __syncthreads();
    }
    unsigned int ex = s[t] - cnt;        // exclusive offset of bin t
    int key = (b << CB_SHIFT) + t;
    if (key < N_ENT) erow[key] = make_uint2(s0 + ex, cnt);
    s[t] = ex;                           // own slot only; published by barrier below
    hh[t] = 0;
    __syncthreads();
    for (unsigned int j = s0 + t; j < s1; j += 512) {
        unsigned int p = binnedE[j];
        unsigned int local = p >> 18;
        unsigned int r = atomicAdd(&hh[local], 1u);
        col[s0 + s[local] + r] = (int)(p & 0x3FFFFu);
    }
}

// U-side per-bucket counting sort (256 threads; runs inside gf1 dispatch)
__device__ __forceinline__ void csort_user_f(const unsigned int* __restrict__ cnt,
                                             const unsigned int* __restrict__ binned,
                                             const float* __restrict__ binnedv,
                                             int2* __restrict__ upair,
                                             uint2* __restrict__ urow,
                                             unsigned int* h, unsigned int* ex,
                                             unsigned int* pairs, int b) {
    unsigned int s0 = (unsigned int)b * UCAP;
    unsigned int n  = min(cnt[b], (unsigned int)UCAP);
    unsigned int s1 = s0 + n;
    int t = threadIdx.x;
    h[2 * t] = 0; h[2 * t + 1] = 0;
    __syncthreads();
    for (unsigned int j = s0 + t; j < s1; j += 256)
        atomicAdd(&h[binned[j] >> 16], 1u);
    __syncthreads();
    unsigned int a0 = h[2 * t], a1 = h[2 * t + 1];
    pairs[t] = a0 + a1;
    __syncthreads();
    for (int off = 1; off < 256; off <<= 1) {
        unsigned int u = 0;
        if (t >= off) u = pairs[t - off];
        __syncthreads();
        if (t >= off) pairs[t] += u;
        __syncthreads();
    }
    unsigned int pe = pairs[t] - (a0 + a1);
    ex[2 * t] = pe;
    ex[2 * t + 1] = pe + a0;
    __syncthreads();
    int keybase = b << CB_SHIFT;
    if (keybase + 2 * t < N_USERS)     urow[keybase + 2 * t]     = make_uint2(s0 + ex[2 * t], a0);
    if (keybase + 2 * t + 1 < N_USERS) urow[keybase + 2 * t + 1] = make_uint2(s0 + ex[2 * t + 1], a1);
    __syncthreads();
    h[2 * t] = 0; h[2 * t + 1] = 0;
    __syncthreads();
    for (unsigned int j = s0 + t; j < s1; j += 256) {
        unsigned int p = binned[j];
        float v = binnedv[j];
        unsigned int local = p >> 16;
        unsigned int r = atomicAdd(&h[local], 1u);
        upair[s0 + ex[local] + r] = make_int2((int)(p & 0xFFFFu), __float_as_int(v));
    }
}

// =================== hop kernels, device bodies ===================

// CSR gather, row-per-group: one 8-lane group owns one entity row (8 rows/wave).
// 4 row loads in flight per group. No cross-group reduction.
// mode 0: ent_out = fp16(l2norm(mean)), items = fp16(mean).
// mode 1: items = fp16(mean), out_ent = emb + fp16(v1) + v2.
__device__ __forceinline__ void gather_fin_row8(int row, int t, bool valid,
        const uint4* __restrict__ entb, const uint2* __restrict__ erow,
        const int* __restrict__ col,
        uint4* __restrict__ ent_out, uint4* __restrict__ items_out,
        const float* __restrict__ base_ent, const uint4* __restrict__ v1tab,
        float* __restrict__ out_ent, int mode) {
    unsigned int s0 = 0, deg = 0;
    if (valid) { uint2 rs = erow[row]; s0 = rs.x; deg = rs.y; }
    unsigned int s1 = s0 + deg;

    h2v a0 = h2z(), a1 = h2z(), a2 = h2z(), a3 = h2z();
    unsigned int j = s0;
    for (; j + 3 < s1; j += 4) {               // 4 loads in flight per group
        int c0 = col[j], c1 = col[j + 1], c2 = col[j + 2], c3 = col[j + 3];
        uint4 x0 = entb[(size_t)c0 * 8 + t];
        uint4 x1 = entb[(size_t)c1 * 8 + t];
        uint4 x2 = entb[(size_t)c2 * 8 + t];
        uint4 x3 = entb[(size_t)c3 * 8 + t];
        a0 += (u2h(x0.x) + u2h(x1.x)) + (u2h(x2.x) + u2h(x3.x));
        a1 += (u2h(x0.y) + u2h(x1.y)) + (u2h(x2.y) + u2h(x3.y));
        a2 += (u2h(x0.z) + u2h(x1.z)) + (u2h(x2.z) + u2h(x3.z));
        a3 += (u2h(x0.w) + u2h(x1.w)) + (u2h(x2.w) + u2h(x3.w));
    }
    for (; j < s1; ++j) {
        uint4 x = entb[(size_t)col[j] * 8 + t];
        a0 += u2h(x.x); a1 += u2h(x.y); a2 += u2h(x.z); a3 += u2h(x.w);
    }
    float inv = 1.0f / fmaxf((float)deg, 1.0f);
    float m0 = (float)a0[0] * inv, m1 = (float)a0[1] * inv;
    float m2 = (float)a1[0] * inv, m3 = (float)a1[1] * inv;
    float m4 = (float)a2[0] * inv, m5 = (float)a2[1] * inv;
    float m6 = (float)a3[0] * inv, m7 = (float)a3[1] * inv;

    float sq = m0*m0 + m1*m1 + m2*m2 + m3*m3 + m4*m4 + m5*m5 + m6*m6 + m7*m7;
    sq = red8(sq);
    float invn = 1.0f / fmaxf(sqrtf(sq), 1e-12f);

    if (!valid) return;
    size_t o = (size_t)row * 8 + t;
    if (row < N_ITEMS)
        items_out[o] = make_uint4(h2u(pk(m0, m1)), h2u(pk(m2, m3)),
                                  h2u(pk(m4, m5)), h2u(pk(m6, m7)));
    if (mode == 0) {
        ent_out[o] = make_uint4(h2u(pk(m0*invn, m1*invn)), h2u(pk(m2*invn, m3*invn)),
                                h2u(pk(m4*invn, m5*invn)), h2u(pk(m6*invn, m7*invn)));
    } else {
        size_t fo = (size_t)row * 16 + 2 * t;          // float4 index
        float4 c0 = ((const float4*)base_ent)[fo];
        float4 c1 = ((const float4*)base_ent)[fo + 1];
        uint4 v1 = v1tab[o];
        h2v p0 = u2h(v1.x), p1 = u2h(v1.y), p2 = u2h(v1.z), p3 = u2h(v1.w);
        ((float4*)out_ent)[fo]     = make_float4(c0.x + (float)p0[0] + m0*invn,
                                                 c0.y + (float)p0[1] + m1*invn,
                                                 c0.z + (float)p1[0] + m2*invn,
                                                 c0.w + (float)p1[1] + m3*invn);
        ((float4*)out_ent)[fo + 1] = make_float4(c1.x + (float)p2[0] + m4*invn,
                                                 c1.y + (float)p2[1] + m5*invn,
                                                 c1.z + (float)p3[0] + m6*invn,
                                                 c1.w + (float)p3[1] + m7*invn);
    }
}

// register-resident user fast path: rows in r[NS] uint4 VGPRs, 8-lane groups.
template<int NS>
__device__ __forceinline__ void user_fast_path(
        unsigned int s0, unsigned int deg, int grp, int t,
        const uint4* __restrict__ itemsb, const int2* __restrict__ up,
        float& l, h2v& ac0, h2v& ac1, h2v& ac2, h2v& ac3) {
    const float SC = 5.0f * 1.44269504f;   // (1/TEMPERATURE) * log2(e)
    uint4 r[NS];
    float vw[NS];
    #pragma unroll
    for (int k = 0; k < NS; ++k) {
        unsigned int slot = (unsigned int)grp + 8u * k;
        if (slot < deg) {
            int2 p = up[s0 + slot];
            r[k] = itemsb[(size_t)p.x * 8 + t];
            vw[k] = __int_as_float(p.y);
        } else {
            r[k] = make_uint4(0u, 0u, 0u, 0u);
            vw[k] = 0.0f;
        }
    }
    // weighted mean (invalid slots contribute 0)
    h2v um0 = h2z(), um1 = h2z(), um2 = h2z(), um3 = h2z();
    #pragma unroll
    for (int k = 0; k < NS; ++k) {
        h2v v2 = pk(vw[k], vw[k]);
        um0 += v2 * u2h(r[k].x); um1 += v2 * u2h(r[k].y);
        um2 += v2 * u2h(r[k].z); um3 += v2 * u2h(r[k].w);
    }
    um0 = grpadd8(um0); um1 = grpadd8(um1); um2 = grpadd8(um2); um3 = grpadd8(um3);
    #pragma unroll
    for (int m = 16; m <= 32; m <<= 1) {
        um0 += u2h(__shfl_xor(h2u(um0), m, 64));
        um1 += u2h(__shfl_xor(h2u(um1), m, 64));
        um2 += u2h(__shfl_xor(h2u(um2), m, 64));
        um3 += u2h(__shfl_xor(h2u(um3), m, 64));
    }
    // scores (branchless: invalid -> -1e30 -> exp2 -> 0)
    float scv[NS];
    float mloc = -1e30f;
    #pragma unroll
    for (int k = 0; k < NS; ++k) {
        unsigned int slot = (unsigned int)grp + 8u * k;
        h2v d0 = u2h(r[k].x) - um0, d1 = u2h(r[k].y) - um1;
        h2v d2 = u2h(r[k].z) - um2, d3 = u2h(r[k].w) - um3;
        float sq = fdot2f(d3, d3, fdot2f(d2, d2, fdot2f(d1, d1, fdot2f(d0, d0, 0.0f))));
        sq = red8(sq);
        float sc = sqrtf(sq) * SC;
        scv[k] = (slot < deg) ? sc : -1e30f;
        mloc = fmaxf(mloc, scv[k]);
    }
    mloc = fmaxf(mloc, dpp_mov<0x128>(mloc));          // xor8
    float M = fmaxf(mloc, __shfl_xor(mloc, 16, 64));
    M = fmaxf(M, __shfl_xor(M, 32, 64));
    #pragma unroll
    for (int k = 0; k < NS; ++k) {
        float e = exp2f(scv[k] - M);
        l += e;
        h2v e2 = pk(e, e);
        ac0 += e2 * u2h(r[k].x); ac1 += e2 * u2h(r[k].y);
        ac2 += e2 * u2h(r[k].z); ac3 += e2 * u2h(r[k].w);
    }
}

// fused user pipeline: one wave per user, 8x8-lane groups.
// deg<=16: 2-slot reg path; deg<=32: 4-slot reg path; else LDS online fallback.
__device__ __forceinline__ void fused_user_row(int row, int lane, uint4 (*cw)[8],
        const uint4* __restrict__ itemsb, const uint2* __restrict__ urow,
        const int2* __restrict__ up, const float* __restrict__ base_user,
        float* __restrict__ out_user) {
    int grp = lane >> 3;
    int t   = lane & 7;
    uint2 rs = urow[row];
    unsigned int s0 = rs.x;
    unsigned int deg = rs.y;
    unsigned int s1 = s0 + deg;

    const float SC = 5.0f * 1.44269504f;
    float l = 0.0f;
    h2v ac0 = h2z(), ac1 = h2z(), ac2 = h2z(), ac3 = h2z();

    if (__builtin_expect(deg <= 16, 1)) {
        user_fast_path<2>(s0, deg, grp, t, itemsb, up, l, ac0, ac1, ac2, ac3);
    } else if (deg <= UCACHE) {
        user_fast_path<4>(s0, deg, grp, t, itemsb, up, l, ac0, ac1, ac2, ac3);
    } else {
        // ---- fallback (deg > 32, ~never): LDS cache + online softmax ----
        h2v um0 = h2z(), um1 = h2z(), um2 = h2z(), um3 = h2z();
        for (unsigned int j = s0 + grp; j < s1; j += 8) {
            int2 p = up[j];
            uint4 r = itemsb[(size_t)p.x * 8 + t];
            int slot = (int)(j - s0);
            if (slot < UCACHE) cw[slot][t] = r;
            float v = __int_as_float(p.y);
            h2v v2 = pk(v, v);
            um0 += v2 * u2h(r.x); um1 += v2 * u2h(r.y);
            um2 += v2 * u2h(r.z); um3 += v2 * u2h(r.w);
        }
        um0 = grpadd8(um0); um1 = grpadd8(um1); um2 = grpadd8(um2); um3 = grpadd8(um3);
        #pragma unroll
        for (int m = 16; m <= 32; m <<= 1) {
            um0 += u2h(__shfl_xor(h2u(um0), m, 64));
            um1 += u2h(__shfl_xor(h2u(um1), m, 64));
            um2 += u2h(__shfl_xor(h2u(um2), m, 64));
            um3 += u2h(__shfl_xor(h2u(um3), m, 64));
        }
        float m_run = -1e30f;
        for (unsigned int j = s0 + grp; j < s1; j += 8) {
            int slot = (int)(j - s0);
            uint4 r = (slot < UCACHE) ? cw[slot][t]
                                      : itemsb[(size_t)up[j].x * 8 + t];
            h2v d0 = u2h(r.x) - um0, d1 = u2h(r.y) - um1;
            h2v d2 = u2h(r.z) - um2, d3 = u2h(r.w) - um3;
            float sq = fdot2f(d3, d3, fdot2f(d2, d2, fdot2f(d1, d1, fdot2f(d0, d0, 0.0f))));
            sq = red8(sq);                       // uniform within 8-lane group
            float sc = sqrtf(sq) * SC;
            if (sc > m_run) {                    // group-uniform branch
                float s = exp2f(m_run - sc);
                l *= s;
                h2v s2 = pk(s, s);
                ac0 *= s2; ac1 *= s2; ac2 *= s2; ac3 *= s2;
                m_run = sc;
            }
            float e = exp2f(sc - m_run);
            l += e;
            h2v e2 = pk(e, e);
            ac0 += e2 * u2h(r.x); ac1 += e2 * u2h(r.y);
            ac2 += e2 * u2h(r.z); ac3 += e2 * u2h(r.w);
        }
        float mx = fmaxf(m_run, dpp_mov<0x128>(m_run));
        float M = fmaxf(mx, __shfl_xor(mx, 16, 64));
        M = fmaxf(M, __shfl_xor(M, 32, 64));
        float wgt = (l > 0.0f) ? exp2f(m_run - M) : 0.0f;
        l *= wgt;
        h2v w2 = pk(wgt, wgt);
        ac0 *= w2; ac1 *= w2; ac2 *= w2; ac3 *= w2;
    }

    // cross-group merge (fast paths share a common M; fallback pre-scaled)
    l = l + dpp_mov<0x128>(l);
    ac0 = grpadd8(ac0); ac1 = grpadd8(ac1); ac2 = grpadd8(ac2); ac3 = grpadd8(ac3);
    #pragma unroll
    for (int m = 16; m <= 32; m <<= 1) {
        l   += __shfl_xor(l, m, 64);
        ac0 += u2h(__shfl_xor(h2u(ac0), m, 64));
        ac1 += u2h(__shfl_xor(h2u(ac1), m, 64));
        ac2 += u2h(__shfl_xor(h2u(ac2), m, 64));
        ac3 += u2h(__shfl_xor(h2u(ac3), m, 64));
    }
    float invl = (l > 0.0f) ? (1.0f / l) : 0.0f;
    float u0 = (float)ac0[0] * invl, u1 = (float)ac0[1] * invl;
    float u2 = (float)ac1[0] * invl, u3 = (float)ac1[1] * invl;
    float u4 = (float)ac2[0] * invl, u5 = (float)ac2[1] * invl;
    float u6 = (float)ac3[0] * invl, u7 = (float)ac3[1] * invl;

    float sq2 = u0*u0 + u1*u1 + u2*u2 + u3*u3 + u4*u4 + u5*u5 + u6*u6 + u7*u7;
    sq2 = red8(sq2);
    float inv = 1.0f / fmaxf(sqrtf(sq2), 1e-12f);
    if (grp == 0) {
        size_t fo = (size_t)row * 16 + 2 * t;
        float4 c0 = ((const float4*)base_user)[fo];
        float4 c1 = ((const float4*)base_user)[fo + 1];
        ((float4*)out_user)[fo]     = make_float4(c0.x + u0*inv, c0.y + u1*inv,
                                                  c0.z + u2*inv, c0.w + u3*inv);
        ((float4*)out_user)[fo + 1] = make_float4(c1.x + u4*inv, c1.y + u5*inv,
                                                  c1.z + u6*inv, c1.w + u7*inv);
    }
}

// =================== hop kernel wrappers ===================

// D3: hop-1 gather+finalize (row-per-group) co-scheduled with the user-side sort
__global__ void gf1_p4u_k(const uint4* __restrict__ E0,
                          const uint2* __restrict__ erow,
                          const int* __restrict__ col,
                          uint4* __restrict__ E1, uint4* __restrict__ itemsA,
                          const unsigned int* __restrict__ curU,
                          const unsigned int* __restrict__ binnedU,
                          const float* __restrict__ binnedUV,
                          int2* __restrict__ upair, uint2* __restrict__ urow) {
    __shared__ unsigned int h[CB_SIZE];
    __shared__ unsigned int ex[CB_SIZE];
    __shared__ unsigned int pairs[256];
    int bid = blockIdx.x;
    if (bid < NB_U) {
        csort_user_f(curU, binnedU, binnedUV, upair, urow, h, ex, pairs, bid);
    } else {
        int lane = threadIdx.x & 63;
        int row = (bid - NB_U) * 32 + (threadIdx.x >> 6) * 8 + (lane >> 3);
        gather_fin_row8(row, lane & 7, row < N_ENT, E0, erow, col, E1, itemsA,
                        nullptr, nullptr, nullptr, 0);
    }
}

// D4a: hop-2 gather of ITEM rows (itemsB + out_ent) co-scheduled with hop-1 user.
// Interleave 1 gather : 16 user per 17 blocks.
__global__ void g2i_u1_k(const uint4* __restrict__ entb,          // E1
                         const uint2* __restrict__ erow,
                         const int* __restrict__ col,
                         uint4* __restrict__ items_out,           // itemsB
                         const float* __restrict__ entity_emb,
                         float* __restrict__ out_ent,
                         const uint4* __restrict__ itemsb1,       // itemsA
                         const uint2* __restrict__ urow,
                         const int2* __restrict__ up,
                         const float* __restrict__ base_user,     // user_emb
                         float* __restrict__ out_user) {
    __shared__ uint4 cache[4][UCACHE][8];   // fallback only
    int bid = blockIdx.x;
    int g = bid / 17, r = bid - g * 17;
    int w    = threadIdx.x >> 6;
    int lane = threadIdx.x & 63;
    if (r == 0) {
        int row = g * 32 + w * 8 + (lane >> 3);          // g < 1563; rows < 50016
        gather_fin_row8(row, lane & 7, row < N_ITEMS, entb, erow, col,
                        nullptr, items_out, entity_emb, entb, out_ent, 1);
    } else {
        int idx = g * 16 + (r - 1);                      // < 25008
        int row = idx * 4 + w;
        if (row < N_USERS)
            fused_user_row(row, lane, cache[w], itemsb1, urow, up,
                           base_user, out_user);
    }
}

// D4b: hop-2 gather of NON-ITEM rows (out_ent only) co-scheduled with hop-2 user.
// Interleave 1 gather : 8 user per 9 blocks.
__global__ void g2n_u2_k(const uint4* __restrict__ entb,          // E1
                         const uint2* __restrict__ erow,
                         const int* __restrict__ col,
                         const float* __restrict__ entity_emb,
                         float* __restrict__ out_ent,
                         const uint4* __restrict__ itemsb2,       // itemsB
                         const uint2* __restrict__ urow,
                         const int2* __restrict__ up,
                         float* __restrict__ out_user) {          // base AND out
    __shared__ uint4 cache[4][UCACHE][8];   // fallback only
    int bid = blockIdx.x;
    int g = bid / 9, r = bid - g * 9;
    int w    = threadIdx.x >> 6;
    int lane = threadIdx.x & 63;
    if (r == 0) {
        int row = N_ITEMS + g * 32 + w * 8 + (lane >> 3);   // g < 3125; rows < 150000
        gather_fin_row8(row, lane & 7, row < N_ENT, entb, erow, col,
                        nullptr, nullptr, entity_emb, entb, out_ent, 1);
    } else {
        int idx = g * 8 + (r - 1);                       // < 25000 exact
        int row = idx * 4 + w;
        fused_user_row(row, lane, cache[w], itemsb2, urow, up,
                       out_user, out_user);
    }
}

extern "C" void kernel_launch(void* const* d_in, const int* in_sizes, int n_in,
                              void* d_out, int out_size, void* d_ws, size_t ws_size,
                              hipStream_t stream) {
    const float* user_emb   = (const float*)d_in[0];
    const float* entity_emb = (const float*)d_in[1];
    const int*   edge_index = (const int*)d_in[3];
    const int*   iu = (const int*)d_in[5];
    const int*   ii = (const int*)d_in[6];
    const float* iv = (const float*)d_in[7];

    float* out_user = (float*)d_out;
    float* out_ent  = out_user + (size_t)N_USERS * CH;

    // ---- workspace layout (~72.5 MB) ----
    uint4* E0     = (uint4*)d_ws;                        // N_ENT*8   (19.2 MB)
    uint4* E1     = E0 + (size_t)N_ENT * 8;              // N_ENT*8   (19.2 MB)
    uint4* itemsA = E1 + (size_t)N_ENT * 8;              // N_ITEMS*8 (6.4 MB)
    uint4* itemsB = itemsA + (size_t)N_ITEMS * 8;        // N_ITEMS*8 (6.4 MB)
    int2*  upair  = (int2*)(itemsB + (size_t)N_ITEMS * 8);       // NB_U*UCAP (9.63 MB)
    int*   col    = (int*)(upair + (size_t)NB_U * UCAP);         // NB_E*ECAP (9.6 MB)
    uint2* erow   = (uint2*)(col + (size_t)NB_E * ECAP);         // N_ENT   (1.2 MB)
    uint2* urow   = erow + N_ENT;                                 // N_USERS (0.8 MB)
    unsigned int* curE = (unsigned int*)(urow + N_USERS);        // NB_E
    unsigned int* curU = curE + NB_E;                             // NB_U

    // build-time scratch:
    //  - binnedE aliased over E1 (9.6 < 19.2 MB): consumed by build_d2, which
    //    completes before gf1_p4u_k writes E1.
    //  - binnedU/UV aliased over out_user (9.6 < 25.6 MB): consumed by the
    //    sort-U blocks of gf1_p4u_k; out_user first really written by g2i_u1_k.
    unsigned int* binnedE  = (unsigned int*)E1;                  // NB_E*ECAP
    unsigned int* binnedU  = (unsigned int*)out_user;            // NB_U*UCAP
    float*        binnedUV = (float*)(binnedU + (size_t)NB_U * UCAP);

    const int* head = edge_index;
    const int* tail = edge_index + N_EDGES;

    // ---- direct-bucket CSR build: 2 dispatches ----
    (void)hipMemsetAsync(curE, 0, (size_t)(NB_E + NB_U) * 4, stream);
    build_d1<<<NBLK_BS_E + NBLK_BS_U + NBLK_CONV, 256, 0, stream>>>(
        head, tail, iu, ii, iv, entity_emb, (uint2*)E0,
        curE, binnedE, curU, binnedU, binnedUV);
    build_d2<<<NB_E, 512, 0, stream>>>(curE, binnedE, col, erow);

    // ---- hop-1 gather+finalize (E0 -> E1, itemsA) + user-side sort ----
    gf1_p4u_k<<<NB_U + GB_G8, 256, 0, stream>>>(E0, erow, col, E1, itemsA,
                                                curU, binnedU, binnedUV,
                                                upair, urow);

    // ---- D4a: hop-2 item gather (itemsB, out_ent[0..50k)) + hop-1 user ----
    g2i_u1_k<<<D4A_NG * 17, 256, 0, stream>>>(E1, erow, col, itemsB,
                                              entity_emb, out_ent,
                                              itemsA, urow, upair,
                                              user_emb, out_user);

    // ---- D4b: hop-2 non-item gather (out_ent[50k..150k)) + hop-2 user ----
    g2n_u2_k<<<D4B_NG * 9, 256, 0, stream>>>(E1, erow, col,
                                             entity_emb, out_ent,
                                             itemsB, urow, upair,
                                             out_user);
}